// Round 7
// baseline (389.050 us; speedup 1.0000x reference)
//
#include <hip/hip_runtime.h>
#include <hip/hip_fp16.h>
#include <cmath>

#define HEADS 4
#define CH 64
#define HC 256
#define NEG 0.2f
#define SCAN_TILE 2048

typedef __attribute__((ext_vector_type(8))) short short8;
typedef __attribute__((ext_vector_type(4))) float f32x4;
typedef __fp16 half2_t __attribute__((ext_vector_type(2)));

__device__ __forceinline__ float leaky(float v){ return v > 0.f ? v : NEG * v; }

__device__ __forceinline__ short bf16_rne(float f){
    unsigned u = __float_as_uint(f);
    unsigned r = u + 0x7fffu + ((u >> 16) & 1u);
    return (short)(r >> 16);
}
__device__ __forceinline__ float bf16_to_f(short s){
    return __uint_as_float(((unsigned)(unsigned short)s) << 16);
}
__device__ __forceinline__ half2_t bc16(unsigned u){ return __builtin_bit_cast(half2_t, u); }
__device__ __forceinline__ unsigned packh2(float a, float b){
    __half ha = __float2half(a), hb = __float2half(b);   // RNE
    return (unsigned)__builtin_bit_cast(unsigned short, ha)
         | ((unsigned)__builtin_bit_cast(unsigned short, hb) << 16);
}

// ---------------- prep: zero deg + one-time bf16-split of weights + d1 ----------------

__global__ __launch_bounds__(256) void prep_kernel(
    const float* __restrict__ W1, const float* __restrict__ W2,
    const float* __restrict__ Ws1, const float* __restrict__ bs1,
    const float* __restrict__ donor,
    int* __restrict__ deg, short* __restrict__ w1hi, short* __restrict__ w1lo,
    short* __restrict__ w2hi, short* __restrict__ w2lo,
    float* __restrict__ d1p, int N)
{
    int t = blockIdx.x * 256 + threadIdx.x;
    int T = gridDim.x * 256;
    for (int i = t; i < N; i += T) deg[i] = 0;
    for (int i = t; i < 256 * 40; i += T){                  // W1: [n=256][k pitch 40], K=27
        int n = i / 40, k = i % 40;
        float v = (k < 27) ? W1[(size_t)k * HC + n] : 0.f;
        short hi = bf16_rne(v);
        w1hi[i] = hi; w1lo[i] = bf16_rne(v - bf16_to_f(hi));
    }
    for (int i = t; i < 256 * 72; i += T){                  // W2: [n=256][k pitch 72], K=64
        int n = i / 72, k = i % 72;
        float v = (k < 64) ? W2[(size_t)k * HC + n] : 0.f;
        short hi = bf16_rne(v);
        w2hi[i] = hi; w2lo[i] = bf16_rne(v - bf16_to_f(hi));
    }
    if (t < 64){                                            // d1 = bs1 + donor @ Ws1[64:96]
        float s = bs1[t];
        for (int k = 0; k < 32; ++k) s = fmaf(donor[k], Ws1[(size_t)(64 + k) * 64 + t], s);
        d1p[t] = s;
    }
}

// ---------------- CSR build ----------------

__global__ void blocksum_kernel(const int* __restrict__ deg, int N, int* __restrict__ bsum){
    __shared__ int wsum[4];
    int tid = threadIdx.x;
    int base = blockIdx.x * SCAN_TILE;
    int s = 0;
    for (int i = tid; i < SCAN_TILE; i += 256){
        int idx = base + i;
        s += (idx < N) ? deg[idx] : 0;
    }
    #pragma unroll
    for (int off = 32; off > 0; off >>= 1) s += __shfl_down(s, off);
    if ((tid & 63) == 0) wsum[tid >> 6] = s;
    __syncthreads();
    if (tid == 0) bsum[blockIdx.x] = wsum[0] + wsum[1] + wsum[2] + wsum[3];
}

__global__ void scan_write_kernel(const int* __restrict__ deg, const int* __restrict__ bsum,
                                  int N, int ET, int* __restrict__ rowptr, int* __restrict__ cursor){
    __shared__ int wsum[4];
    __shared__ int bpre;
    int tid = threadIdx.x;
    if (tid < 64){
        int v = (tid < blockIdx.x) ? bsum[tid] : 0;
        #pragma unroll
        for (int off = 32; off > 0; off >>= 1) v += __shfl_down(v, off);
        if (tid == 0) bpre = v;
    }
    if (blockIdx.x == 0 && tid == 0) rowptr[N] = ET;
    int base = blockIdx.x * SCAN_TILE + tid * 8;
    int v[8]; int s = 0;
    #pragma unroll
    for (int j = 0; j < 8; ++j){
        int idx = base + j;
        v[j] = (idx < N) ? deg[idx] : 0;
        s += v[j];
    }
    int lane = tid & 63, wv = tid >> 6;
    int incl = s;
    #pragma unroll
    for (int off = 1; off < 64; off <<= 1){
        int tt = __shfl_up(incl, off);
        if (lane >= off) incl += tt;
    }
    if (lane == 63) wsum[wv] = incl;
    __syncthreads();
    int excl = incl - s + bpre;
    for (int w = 0; w < wv; ++w) excl += wsum[w];
    #pragma unroll
    for (int j = 0; j < 8; ++j){
        int idx = base + j;
        if (idx < N){ rowptr[idx] = excl; cursor[idx] = excl; excl += v[j]; }
    }
}

__global__ void scatter_kernel(const int* __restrict__ ei, int E, int N,
                               int* __restrict__ cursor, int* __restrict__ colsrc){
    int e = blockIdx.x * 256 + threadIdx.x;
    int ET = E + N;
    if (e >= ET) return;
    int s, d;
    if (e < E){ s = ei[e]; d = ei[E + e]; } else { s = d = e - E; }
    int pos = atomicAdd(&cursor[d], 1);
    colsrc[pos] = s;
}

// ---------------- MFMA node transform (device body) ----------------

template<int FIN, int KSTEPS, int NT>
__device__ __forceinline__ void transform_body(
    int bx, int by,
    const float* __restrict__ xin, const short* __restrict__ whi, const short* __restrict__ wlo,
    const float* __restrict__ a_src, const float* __restrict__ a_dst,
    __half* __restrict__ h, float* __restrict__ asrc, float* __restrict__ adst, int N)
{
    constexpr int KP = KSTEPS * 32;
    constexpr int XP = KP + 4;
    constexpr int WP = KP + 8;
    constexpr int NCOL = NT * 16;
    __shared__ float xl[64 * XP];
    __shared__ short wt_hi[NCOL * WP];
    __shared__ short wt_lo[NCOL * WP];

    const int tid = threadIdx.x;
    const int n0 = bx * 64;
    const int c0 = by * NCOL;

    if (FIN == 64) {
        for (int t = tid; t < 64 * 16; t += 256) {
            int row = t >> 4, c4 = (t & 15) * 4;
            int n = n0 + row;
            float4 v = make_float4(0.f, 0.f, 0.f, 0.f);
            if (n < N) v = *(const float4*)(xin + (size_t)n * 64 + c4);
            *(float4*)(xl + row * XP + c4) = v;
        }
    } else {
        for (int t = tid; t < 64 * KP; t += 256) {
            int row = t / KP, k = t % KP;
            int n = n0 + row;
            float v = 0.f;
            if (n < N && k < FIN) v = xin[(size_t)n * FIN + k];
            xl[row * XP + k] = v;
        }
    }
    {
        const short8* ghi = (const short8*)(whi + (size_t)c0 * WP);
        const short8* glo = (const short8*)(wlo + (size_t)c0 * WP);
        short8* lhi = (short8*)wt_hi;
        short8* llo = (short8*)wt_lo;
        for (int t = tid; t < NCOL * WP / 8; t += 256){
            lhi[t] = ghi[t];
            llo[t] = glo[t];
        }
    }
    __syncthreads();

    const int wv = tid >> 6, lane = tid & 63;
    const int quad = lane >> 4, ln = lane & 15;
    const int myrow = wv * 16 + ln;

    f32x4 acc[NT];
    #pragma unroll
    for (int i = 0; i < NT; ++i) acc[i] = (f32x4){0.f, 0.f, 0.f, 0.f};

    #pragma unroll
    for (int ks = 0; ks < KSTEPS; ++ks) {
        const int k0 = ks * 32 + quad * 8;
        const float* ap = xl + myrow * XP + k0;
        float4 f0 = *(const float4*)ap;
        float4 f1 = *(const float4*)(ap + 4);
        float fa[8] = {f0.x, f0.y, f0.z, f0.w, f1.x, f1.y, f1.z, f1.w};
        short8 ahi, alo;
        #pragma unroll
        for (int e = 0; e < 8; ++e) {
            short hi = bf16_rne(fa[e]);
            ahi[e] = hi;
            alo[e] = bf16_rne(fa[e] - bf16_to_f(hi));
        }
        #pragma unroll
        for (int nt = 0; nt < NT; ++nt) {
            short8 bhi = *(const short8*)(wt_hi + (nt * 16 + ln) * WP + k0);
            short8 blo = *(const short8*)(wt_lo + (nt * 16 + ln) * WP + k0);
            acc[nt] = __builtin_amdgcn_mfma_f32_16x16x32_bf16(ahi, bhi, acc[nt], 0, 0, 0);
            acc[nt] = __builtin_amdgcn_mfma_f32_16x16x32_bf16(alo, bhi, acc[nt], 0, 0, 0);
            acc[nt] = __builtin_amdgcn_mfma_f32_16x16x32_bf16(ahi, blo, acc[nt], 0, 0, 0);
        }
    }

    #pragma unroll
    for (int r = 0; r < 4; ++r) {
        int n = n0 + wv * 16 + quad * 4 + r;
        if (n < N) {
            if (NT == 16) {
                #pragma unroll
                for (int q = 0; q < 4; ++q) {
                    uint2 u;
                    u.x = packh2(acc[q][r],     acc[q + 4][r]);
                    u.y = packh2(acc[q + 8][r], acc[q + 12][r]);
                    *(uint2*)((char*)h + (size_t)n * 512 + (q * 16 + ln) * 8) = u;
                }
            } else {
                #pragma unroll
                for (int q = 0; q < 4; ++q) {
                    unsigned u = packh2(acc[q][r], acc[q + 4][r]);
                    *(unsigned*)((char*)h + (size_t)n * 512 + (q * 16 + ln) * 8 + ((c0 >> 6) << 1)) = u;
                }
            }
        }
    }

    float aS[NT], aD[NT];
    #pragma unroll
    for (int nt = 0; nt < NT; ++nt) {
        aS[nt] = a_src[c0 + nt * 16 + ln];
        aD[nt] = a_dst[c0 + nt * 16 + ln];
    }
    #pragma unroll
    for (int hl = 0; hl < NT / 4; ++hl) {
        #pragma unroll
        for (int r = 0; r < 4; ++r) {
            float ps = 0.f, pd = 0.f;
            #pragma unroll
            for (int i = 0; i < 4; ++i) {
                ps = fmaf(acc[hl * 4 + i][r], aS[hl * 4 + i], ps);
                pd = fmaf(acc[hl * 4 + i][r], aD[hl * 4 + i], pd);
            }
            #pragma unroll
            for (int off = 1; off < 16; off <<= 1) {
                ps += __shfl_xor(ps, off);
                pd += __shfl_xor(pd, off);
            }
            if (ln == 0) {
                int n = n0 + wv * 16 + quad * 4 + r;
                if (n < N) {
                    int hg = c0 / 64 + hl;
                    asrc[n * 4 + hg] = ps;
                    adst[n * 4 + hg] = pd;
                }
            }
        }
    }
}

__global__ __launch_bounds__(256) void transform1_count_kernel(
    const float* __restrict__ xin, const short* __restrict__ whi, const short* __restrict__ wlo,
    const float* __restrict__ a_src, const float* __restrict__ a_dst,
    __half* __restrict__ h, float* __restrict__ asrc, float* __restrict__ adst, int N,
    int nblk, const int* __restrict__ ei, int E, int* __restrict__ deg)
{
    if ((int)blockIdx.x < nblk) {
        transform_body<27, 1, 16>(blockIdx.x, 0, xin, whi, wlo, a_src, a_dst, h, asrc, adst, N);
    } else {
        int e = (blockIdx.x - nblk) * 256 + threadIdx.x;
        int ET = E + N;
        if (e < ET){
            int d = (e < E) ? ei[E + e] : (e - E);
            atomicAdd(&deg[d], 1);
        }
    }
}

__global__ __launch_bounds__(256) void transform2_kernel(
    const float* __restrict__ xin, const short* __restrict__ whi, const short* __restrict__ wlo,
    const float* __restrict__ a_src, const float* __restrict__ a_dst,
    __half* __restrict__ h, float* __restrict__ asrc, float* __restrict__ adst, int N)
{
    transform_body<64, 2, 8>(blockIdx.x, blockIdx.y, xin, whi, wlo, a_src, a_dst, h, asrc, adst, N);
}

// ---------------- per-dst aggregation ----------------
// Fast path (deg<=64, ~always): plain max-butterfly -> ONE exp/lane/head ->
// sum-butterfly; p reused as unnormalized weight (4 exps/node vs 52).
// Slow path (deg>64): online-softmax butterfly as before.
// do_score: fused scorer epilogue (hidden = relu(o@Ws1 + d1), logit = hidden@Ws2+bs2).

__device__ __forceinline__ void edge_sweep(
    const int* __restrict__ soff, const uint2* __restrict__ sw,
    const __half* __restrict__ h, int boff, int cnt, float& accA, float& accB)
{
    int cnt2 = (cnt + 1) & ~1;
    for (int j = 0; j < cnt2; j += 2){
        int offA = __builtin_amdgcn_readfirstlane(soff[j]);
        int offB = __builtin_amdgcn_readfirstlane(soff[j + 1]);
        uint4 w4 = *(const uint4*)(sw + j);
        uint2 ha = *(const uint2*)((const char*)h + offA + boff);
        uint2 hb = *(const uint2*)((const char*)h + offB + boff);
        accA = __builtin_amdgcn_fdot2(bc16(ha.x), bc16(w4.x), accA, false);
        accA = __builtin_amdgcn_fdot2(bc16(ha.y), bc16(w4.y), accA, false);
        accB = __builtin_amdgcn_fdot2(bc16(hb.x), bc16(w4.z), accB, false);
        accB = __builtin_amdgcn_fdot2(bc16(hb.y), bc16(w4.w), accB, false);
    }
}

__global__ __launch_bounds__(256) void aggregate_kernel(
    const int* __restrict__ rowptr, const int* __restrict__ colsrc,
    const __half* __restrict__ h, const float* __restrict__ asrc,
    const float* __restrict__ adst, const float* __restrict__ bias,
    float* __restrict__ hout, int N,
    const float* __restrict__ Ws1g, const float* __restrict__ d1p,
    const float* __restrict__ Ws2, const float* __restrict__ bs2,
    float* __restrict__ logits, int do_score)
{
    __shared__ float Wl[64 * 64];
    __shared__ float sh_o[4][64];
    __shared__ int   s_off[4][64];
    __shared__ uint2 s_w[4][64];
    int tid = threadIdx.x;
    int wv = tid >> 6, lane = tid & 63;
    if (do_score){
        for (int i = tid; i < 64 * 64; i += 256) Wl[i] = Ws1g[i];
    }
    __syncthreads();

    int n = blockIdx.x * 4 + wv;
    if (n >= N) return;
    int start = rowptr[n], end = rowptr[n + 1];
    int deg = end - start;
    const float4 ad = *(const float4*)(adst + (size_t)n * 4);

    int src0 = 0;
    float e0 = -1e30f, e1 = -1e30f, e2 = -1e30f, e3 = -1e30f;
    bool v0 = lane < deg;
    if (v0){
        src0 = colsrc[start + lane];
        float4 as = *(const float4*)(asrc + (size_t)src0 * 4);
        e0 = leaky(as.x + ad.x); e1 = leaky(as.y + ad.y);
        e2 = leaky(as.z + ad.z); e3 = leaky(as.w + ad.w);
    }

    float m0, m1, m2, m3, i0, i1, i2, i3, p0, p1, p2, p3;
    if (deg <= 64){
        // ---- fast path: max butterfly, single exp, sum butterfly
        m0 = e0; m1 = e1; m2 = e2; m3 = e3;
        #pragma unroll
        for (int off = 1; off < 64; off <<= 1){
            m0 = fmaxf(m0, __shfl_xor(m0, off));
            m1 = fmaxf(m1, __shfl_xor(m1, off));
            m2 = fmaxf(m2, __shfl_xor(m2, off));
            m3 = fmaxf(m3, __shfl_xor(m3, off));
        }
        p0 = __expf(e0 - m0);   // 0 for invalid lanes (underflow)
        p1 = __expf(e1 - m1);
        p2 = __expf(e2 - m2);
        p3 = __expf(e3 - m3);
        float t0 = p0, t1 = p1, t2 = p2, t3 = p3;
        #pragma unroll
        for (int off = 1; off < 64; off <<= 1){
            t0 += __shfl_xor(t0, off);
            t1 += __shfl_xor(t1, off);
            t2 += __shfl_xor(t2, off);
            t3 += __shfl_xor(t3, off);
        }
        i0 = 1.f / t0; i1 = 1.f / t1; i2 = 1.f / t2; i3 = 1.f / t3;
    } else {
        // ---- slow path (deg>64, ~never): online merge
        m0 = e0; m1 = e1; m2 = e2; m3 = e3;
        float t0 = v0 ? 1.f : 0.f, t1 = t0, t2 = t0, t3 = t0;
        for (int i = start + 64 + lane; i < end; i += 64){
            int s = colsrc[i];
            float4 as = *(const float4*)(asrc + (size_t)s * 4);
            float e, nm;
            e = leaky(as.x + ad.x); nm = fmaxf(m0, e); t0 = t0 * __expf(m0 - nm) + __expf(e - nm); m0 = nm;
            e = leaky(as.y + ad.y); nm = fmaxf(m1, e); t1 = t1 * __expf(m1 - nm) + __expf(e - nm); m1 = nm;
            e = leaky(as.z + ad.z); nm = fmaxf(m2, e); t2 = t2 * __expf(m2 - nm) + __expf(e - nm); m2 = nm;
            e = leaky(as.w + ad.w); nm = fmaxf(m3, e); t3 = t3 * __expf(m3 - nm) + __expf(e - nm); m3 = nm;
        }
        #pragma unroll
        for (int off = 1; off < 64; off <<= 1){
            float om, os, nm;
            om = __shfl_xor(m0, off); os = __shfl_xor(t0, off);
            nm = fmaxf(m0, om); t0 = t0 * __expf(m0 - nm) + os * __expf(om - nm); m0 = nm;
            om = __shfl_xor(m1, off); os = __shfl_xor(t1, off);
            nm = fmaxf(m1, om); t1 = t1 * __expf(m1 - nm) + os * __expf(om - nm); m1 = nm;
            om = __shfl_xor(m2, off); os = __shfl_xor(t2, off);
            nm = fmaxf(m2, om); t2 = t2 * __expf(m2 - nm) + os * __expf(om - nm); m2 = nm;
            om = __shfl_xor(m3, off); os = __shfl_xor(t3, off);
            nm = fmaxf(m3, om); t3 = t3 * __expf(m3 - nm) + os * __expf(om - nm); m3 = nm;
        }
        i0 = 1.f / t0; i1 = 1.f / t1; i2 = 1.f / t2; i3 = 1.f / t3;
        p0 = __expf(e0 - m0); p1 = __expf(e1 - m1);
        p2 = __expf(e2 - m2); p3 = __expf(e3 - m3);
    }

    // ---- pass B
    float accA = 0.f, accB = 0.f;
    const int boff = lane * 8;
    {
        int off = v0 ? src0 * (HC * 2) : 0;
        s_off[wv][lane] = off;
        half2_t p01 = __builtin_amdgcn_cvt_pkrtz(p0 * i0, p1 * i1);
        half2_t p23 = __builtin_amdgcn_cvt_pkrtz(p2 * i2, p3 * i3);
        s_w[wv][lane] = (uint2){ __builtin_bit_cast(unsigned, p01),
                                 __builtin_bit_cast(unsigned, p23) };
        int cnt = deg < 64 ? deg : 64;
        edge_sweep(&s_off[wv][0], &s_w[wv][0], h, boff, cnt, accA, accB);
    }
    for (int base = start + 64; base < end; base += 64){
        int cnt = end - base; if (cnt > 64) cnt = 64;
        float w0 = 0.f, w1 = 0.f, w2 = 0.f, w3 = 0.f; int off = 0;
        if (lane < cnt){
            int s = colsrc[base + lane];
            float4 as = *(const float4*)(asrc + (size_t)s * 4);
            w0 = __expf(leaky(as.x + ad.x) - m0) * i0;
            w1 = __expf(leaky(as.y + ad.y) - m1) * i1;
            w2 = __expf(leaky(as.z + ad.z) - m2) * i2;
            w3 = __expf(leaky(as.w + ad.w) - m3) * i3;
            off = s * (HC * 2);
        }
        s_off[wv][lane] = off;
        half2_t p01 = __builtin_amdgcn_cvt_pkrtz(w0, w1);
        half2_t p23 = __builtin_amdgcn_cvt_pkrtz(w2, w3);
        s_w[wv][lane] = (uint2){ __builtin_bit_cast(unsigned, p01),
                                 __builtin_bit_cast(unsigned, p23) };
        edge_sweep(&s_off[wv][0], &s_w[wv][0], h, boff, cnt, accA, accB);
    }

    float o = (accA + accB) * 0.25f + bias[lane];
    o = (o > 0.f) ? o : expm1f(o);   // ELU

    if (!do_score){
        hout[(size_t)n * CH + lane] = o;
    } else {
        // fused scorer: lane j computes hidden[j] from wave-local o[] broadcast
        sh_o[wv][lane] = o;
        float s = d1p[lane];
        #pragma unroll
        for (int k = 0; k < 64; ++k)
            s = fmaf(sh_o[wv][k], Wl[k * 64 + lane], s);
        s = fmaxf(s, 0.f) * Ws2[lane];
        #pragma unroll
        for (int off = 1; off < 64; off <<= 1) s += __shfl_xor(s, off);
        if (lane == 0) logits[n] = s + bs2[0];
    }
}

// ---------------- launch ----------------

extern "C" void kernel_launch(void* const* d_in, const int* in_sizes, int n_in,
                              void* d_out, int out_size, void* d_ws, size_t ws_size,
                              hipStream_t stream)
{
    const float* x    = (const float*)d_in[0];
    const int*   ei   = (const int*)  d_in[1];
    const float* donor= (const float*)d_in[2];
    const float* W1   = (const float*)d_in[3];
    const float* as1  = (const float*)d_in[4];
    const float* ad1  = (const float*)d_in[5];
    const float* b1   = (const float*)d_in[6];
    const float* W2   = (const float*)d_in[7];
    const float* as2  = (const float*)d_in[8];
    const float* ad2  = (const float*)d_in[9];
    const float* b2   = (const float*)d_in[10];
    const float* Ws1  = (const float*)d_in[11];
    const float* bs1  = (const float*)d_in[12];
    const float* Ws2  = (const float*)d_in[13];
    const float* bs2  = (const float*)d_in[14];

    const int N  = in_sizes[0] / 27;
    const int E  = in_sizes[1] / 2;
    const int ET = E + N;

    char* ws = (char*)d_ws;
    auto alloc = [&](size_t bytes) -> void* {
        void* p = (void*)ws;
        ws += (bytes + 255) / 256 * 256;
        return p;
    };
    int*    rowptr = (int*)   alloc((size_t)(N + 1) * 4);
    int*    deg    = (int*)   alloc((size_t)N * 4);
    int*    cursor = (int*)   alloc((size_t)N * 4);
    int*    colsrc = (int*)   alloc((size_t)ET * 4);
    __half* hbig   = (__half*)alloc((size_t)N * HC * 2);
    float*  asrc   = (float*) alloc((size_t)N * 4 * 4);
    float*  adst   = (float*) alloc((size_t)N * 4 * 4);
    float*  hmid   = (float*) alloc((size_t)N * CH * 4);
    const int SB = (N + SCAN_TILE - 1) / SCAN_TILE;
    int*    bsum   = (int*)   alloc((size_t)SB * 4);
    short*  w1hi   = (short*) alloc(256 * 40 * 2);
    short*  w1lo   = (short*) alloc(256 * 40 * 2);
    short*  w2hi   = (short*) alloc(256 * 72 * 2);
    short*  w2lo   = (short*) alloc(256 * 72 * 2);
    float*  d1p    = (float*) alloc(64 * 4);

    const int nblk = (N + 63) / 64;
    const int cblk = (ET + 255) / 256;

    // 1. prep
    prep_kernel<<<256, 256, 0, stream>>>(W1, W2, Ws1, bs1, donor,
        deg, w1hi, w1lo, w2hi, w2lo, d1p, N);
    // 2. layer1 transform + edge count
    transform1_count_kernel<<<nblk + cblk, 256, 0, stream>>>(
        x, w1hi, w1lo, as1, ad1, hbig, asrc, adst, N, nblk, ei, E, deg);
    // 3-4. scan
    blocksum_kernel<<<SB, 256, 0, stream>>>(deg, N, bsum);
    scan_write_kernel<<<SB, 256, 0, stream>>>(deg, bsum, N, ET, rowptr, cursor);
    // 5. scatter
    scatter_kernel<<<cblk, 256, 0, stream>>>(ei, E, N, cursor, colsrc);
    // 6. aggregate layer1
    aggregate_kernel<<<(N + 3) / 4, 256, 0, stream>>>(
        rowptr, colsrc, hbig, asrc, adst, b1, hmid, N,
        Ws1, d1p, Ws2, bs2, (float*)d_out, 0);
    // 7. layer2 transform
    transform2_kernel<<<dim3(nblk, 2), 256, 0, stream>>>(
        hmid, w2hi, w2lo, as2, ad2, hbig, asrc, adst, N);
    // 8. aggregate layer2 + fused scorer
    aggregate_kernel<<<(N + 3) / 4, 256, 0, stream>>>(
        rowptr, colsrc, hbig, asrc, adst, b2, hmid, N,
        Ws1, d1p, Ws2, bs2, (float*)d_out, 1);
}

// Round 8
// 370.025 us; speedup vs baseline: 1.0514x; 1.0514x over previous
//
#include <hip/hip_runtime.h>
#include <hip/hip_fp16.h>
#include <cmath>

#define HEADS 4
#define CH 64
#define HC 256
#define NEG 0.2f
#define SCAN_TILE 2048

typedef __attribute__((ext_vector_type(8))) short short8;
typedef __attribute__((ext_vector_type(4))) float f32x4;
typedef __fp16 half2_t __attribute__((ext_vector_type(2)));

__device__ __forceinline__ float leaky(float v){ return v > 0.f ? v : NEG * v; }

__device__ __forceinline__ short bf16_rne(float f){
    unsigned u = __float_as_uint(f);
    unsigned r = u + 0x7fffu + ((u >> 16) & 1u);
    return (short)(r >> 16);
}
__device__ __forceinline__ float bf16_to_f(short s){
    return __uint_as_float(((unsigned)(unsigned short)s) << 16);
}
__device__ __forceinline__ half2_t bc16(unsigned u){ return __builtin_bit_cast(half2_t, u); }
__device__ __forceinline__ unsigned packh2(float a, float b){
    __half ha = __float2half(a), hb = __float2half(b);   // RNE
    return (unsigned)__builtin_bit_cast(unsigned short, ha)
         | ((unsigned)__builtin_bit_cast(unsigned short, hb) << 16);
}

// ---------------- prep: zero deg + one-time bf16-split of weights + d1 ----------------

__global__ __launch_bounds__(256) void prep_kernel(
    const float* __restrict__ W1, const float* __restrict__ W2,
    const float* __restrict__ Ws1, const float* __restrict__ bs1,
    const float* __restrict__ donor,
    int* __restrict__ deg, short* __restrict__ w1hi, short* __restrict__ w1lo,
    short* __restrict__ w2hi, short* __restrict__ w2lo,
    short* __restrict__ s1hi, short* __restrict__ s1lo,
    float* __restrict__ d1p, int N)
{
    int t = blockIdx.x * 256 + threadIdx.x;
    int T = gridDim.x * 256;
    for (int i = t; i < N; i += T) deg[i] = 0;
    for (int i = t; i < 256 * 40; i += T){                  // W1: [n=256][k pitch 40], K=27
        int n = i / 40, k = i % 40;
        float v = (k < 27) ? W1[(size_t)k * HC + n] : 0.f;
        short hi = bf16_rne(v);
        w1hi[i] = hi; w1lo[i] = bf16_rne(v - bf16_to_f(hi));
    }
    for (int i = t; i < 256 * 72; i += T){                  // W2: [n=256][k pitch 72], K=64
        int n = i / 72, k = i % 72;
        float v = (k < 64) ? W2[(size_t)k * HC + n] : 0.f;
        short hi = bf16_rne(v);
        w2hi[i] = hi; w2lo[i] = bf16_rne(v - bf16_to_f(hi));
    }
    for (int i = t; i < 64 * 72; i += T){                   // Ws1 h-part: [j=64][k pitch 72], K=64
        int n = i / 72, k = i % 72;
        float v = (k < 64) ? Ws1[(size_t)k * 64 + n] : 0.f;
        short hi = bf16_rne(v);
        s1hi[i] = hi; s1lo[i] = bf16_rne(v - bf16_to_f(hi));
    }
    if (t < 64){                                            // d1 = bs1 + donor @ Ws1[64:96]
        float s = bs1[t];
        for (int k = 0; k < 32; ++k) s = fmaf(donor[k], Ws1[(size_t)(64 + k) * 64 + t], s);
        d1p[t] = s;
    }
}

// ---------------- CSR build ----------------

__global__ void blocksum_kernel(const int* __restrict__ deg, int N, int* __restrict__ bsum){
    __shared__ int wsum[4];
    int tid = threadIdx.x;
    int base = blockIdx.x * SCAN_TILE;
    int s = 0;
    for (int i = tid; i < SCAN_TILE; i += 256){
        int idx = base + i;
        s += (idx < N) ? deg[idx] : 0;
    }
    #pragma unroll
    for (int off = 32; off > 0; off >>= 1) s += __shfl_down(s, off);
    if ((tid & 63) == 0) wsum[tid >> 6] = s;
    __syncthreads();
    if (tid == 0) bsum[blockIdx.x] = wsum[0] + wsum[1] + wsum[2] + wsum[3];
}

__global__ void scan_write_kernel(const int* __restrict__ deg, const int* __restrict__ bsum,
                                  int N, int ET, int* __restrict__ rowptr, int* __restrict__ cursor){
    __shared__ int wsum[4];
    __shared__ int bpre;
    int tid = threadIdx.x;
    if (tid < 64){
        int v = (tid < blockIdx.x) ? bsum[tid] : 0;
        #pragma unroll
        for (int off = 32; off > 0; off >>= 1) v += __shfl_down(v, off);
        if (tid == 0) bpre = v;
    }
    if (blockIdx.x == 0 && tid == 0) rowptr[N] = ET;
    int base = blockIdx.x * SCAN_TILE + tid * 8;
    int v[8]; int s = 0;
    #pragma unroll
    for (int j = 0; j < 8; ++j){
        int idx = base + j;
        v[j] = (idx < N) ? deg[idx] : 0;
        s += v[j];
    }
    int lane = tid & 63, wv = tid >> 6;
    int incl = s;
    #pragma unroll
    for (int off = 1; off < 64; off <<= 1){
        int tt = __shfl_up(incl, off);
        if (lane >= off) incl += tt;
    }
    if (lane == 63) wsum[wv] = incl;
    __syncthreads();
    int excl = incl - s + bpre;
    for (int w = 0; w < wv; ++w) excl += wsum[w];
    #pragma unroll
    for (int j = 0; j < 8; ++j){
        int idx = base + j;
        if (idx < N){ rowptr[idx] = excl; cursor[idx] = excl; excl += v[j]; }
    }
}

__global__ void scatter_kernel(const int* __restrict__ ei, int E, int N,
                               int* __restrict__ cursor, int* __restrict__ colsrc){
    int e = blockIdx.x * 256 + threadIdx.x;
    int ET = E + N;
    if (e >= ET) return;
    int s, d;
    if (e < E){ s = ei[e]; d = ei[E + e]; } else { s = d = e - E; }
    int pos = atomicAdd(&cursor[d], 1);
    colsrc[pos] = s;
}

// ---------------- MFMA node transform (device body) ----------------

template<int FIN, int KSTEPS, int NT>
__device__ __forceinline__ void transform_body(
    int bx, int by,
    const float* __restrict__ xin, const short* __restrict__ whi, const short* __restrict__ wlo,
    const float* __restrict__ a_src, const float* __restrict__ a_dst,
    __half* __restrict__ h, float* __restrict__ asrc, float* __restrict__ adst, int N)
{
    constexpr int KP = KSTEPS * 32;
    constexpr int XP = KP + 4;
    constexpr int WP = KP + 8;
    constexpr int NCOL = NT * 16;
    __shared__ float xl[64 * XP];
    __shared__ short wt_hi[NCOL * WP];
    __shared__ short wt_lo[NCOL * WP];

    const int tid = threadIdx.x;
    const int n0 = bx * 64;
    const int c0 = by * NCOL;

    if (FIN == 64) {
        for (int t = tid; t < 64 * 16; t += 256) {
            int row = t >> 4, c4 = (t & 15) * 4;
            int n = n0 + row;
            float4 v = make_float4(0.f, 0.f, 0.f, 0.f);
            if (n < N) v = *(const float4*)(xin + (size_t)n * 64 + c4);
            *(float4*)(xl + row * XP + c4) = v;
        }
    } else {
        for (int t = tid; t < 64 * KP; t += 256) {
            int row = t / KP, k = t % KP;
            int n = n0 + row;
            float v = 0.f;
            if (n < N && k < FIN) v = xin[(size_t)n * FIN + k];
            xl[row * XP + k] = v;
        }
    }
    {
        const short8* ghi = (const short8*)(whi + (size_t)c0 * WP);
        const short8* glo = (const short8*)(wlo + (size_t)c0 * WP);
        short8* lhi = (short8*)wt_hi;
        short8* llo = (short8*)wt_lo;
        for (int t = tid; t < NCOL * WP / 8; t += 256){
            lhi[t] = ghi[t];
            llo[t] = glo[t];
        }
    }
    __syncthreads();

    const int wv = tid >> 6, lane = tid & 63;
    const int quad = lane >> 4, ln = lane & 15;
    const int myrow = wv * 16 + ln;

    f32x4 acc[NT];
    #pragma unroll
    for (int i = 0; i < NT; ++i) acc[i] = (f32x4){0.f, 0.f, 0.f, 0.f};

    #pragma unroll
    for (int ks = 0; ks < KSTEPS; ++ks) {
        const int k0 = ks * 32 + quad * 8;
        const float* ap = xl + myrow * XP + k0;
        float4 f0 = *(const float4*)ap;
        float4 f1 = *(const float4*)(ap + 4);
        float fa[8] = {f0.x, f0.y, f0.z, f0.w, f1.x, f1.y, f1.z, f1.w};
        short8 ahi, alo;
        #pragma unroll
        for (int e = 0; e < 8; ++e) {
            short hi = bf16_rne(fa[e]);
            ahi[e] = hi;
            alo[e] = bf16_rne(fa[e] - bf16_to_f(hi));
        }
        #pragma unroll
        for (int nt = 0; nt < NT; ++nt) {
            short8 bhi = *(const short8*)(wt_hi + (nt * 16 + ln) * WP + k0);
            short8 blo = *(const short8*)(wt_lo + (nt * 16 + ln) * WP + k0);
            acc[nt] = __builtin_amdgcn_mfma_f32_16x16x32_bf16(ahi, bhi, acc[nt], 0, 0, 0);
            acc[nt] = __builtin_amdgcn_mfma_f32_16x16x32_bf16(alo, bhi, acc[nt], 0, 0, 0);
            acc[nt] = __builtin_amdgcn_mfma_f32_16x16x32_bf16(ahi, blo, acc[nt], 0, 0, 0);
        }
    }

    #pragma unroll
    for (int r = 0; r < 4; ++r) {
        int n = n0 + wv * 16 + quad * 4 + r;
        if (n < N) {
            if (NT == 16) {
                #pragma unroll
                for (int q = 0; q < 4; ++q) {
                    uint2 u;
                    u.x = packh2(acc[q][r],     acc[q + 4][r]);
                    u.y = packh2(acc[q + 8][r], acc[q + 12][r]);
                    *(uint2*)((char*)h + (size_t)n * 512 + (q * 16 + ln) * 8) = u;
                }
            } else {
                #pragma unroll
                for (int q = 0; q < 4; ++q) {
                    unsigned u = packh2(acc[q][r], acc[q + 4][r]);
                    *(unsigned*)((char*)h + (size_t)n * 512 + (q * 16 + ln) * 8 + ((c0 >> 6) << 1)) = u;
                }
            }
        }
    }

    float aS[NT], aD[NT];
    #pragma unroll
    for (int nt = 0; nt < NT; ++nt) {
        aS[nt] = a_src[c0 + nt * 16 + ln];
        aD[nt] = a_dst[c0 + nt * 16 + ln];
    }
    #pragma unroll
    for (int hl = 0; hl < NT / 4; ++hl) {
        #pragma unroll
        for (int r = 0; r < 4; ++r) {
            float ps = 0.f, pd = 0.f;
            #pragma unroll
            for (int i = 0; i < 4; ++i) {
                ps = fmaf(acc[hl * 4 + i][r], aS[hl * 4 + i], ps);
                pd = fmaf(acc[hl * 4 + i][r], aD[hl * 4 + i], pd);
            }
            #pragma unroll
            for (int off = 1; off < 16; off <<= 1) {
                ps += __shfl_xor(ps, off);
                pd += __shfl_xor(pd, off);
            }
            if (ln == 0) {
                int n = n0 + wv * 16 + quad * 4 + r;
                if (n < N) {
                    int hg = c0 / 64 + hl;
                    asrc[n * 4 + hg] = ps;
                    adst[n * 4 + hg] = pd;
                }
            }
        }
    }
}

__global__ __launch_bounds__(256) void transform1_count_kernel(
    const float* __restrict__ xin, const short* __restrict__ whi, const short* __restrict__ wlo,
    const float* __restrict__ a_src, const float* __restrict__ a_dst,
    __half* __restrict__ h, float* __restrict__ asrc, float* __restrict__ adst, int N,
    int nblk, const int* __restrict__ ei, int E, int* __restrict__ deg)
{
    if ((int)blockIdx.x < nblk) {
        transform_body<27, 1, 16>(blockIdx.x, 0, xin, whi, wlo, a_src, a_dst, h, asrc, adst, N);
    } else {
        int e = (blockIdx.x - nblk) * 256 + threadIdx.x;
        int ET = E + N;
        if (e < ET){
            int d = (e < E) ? ei[E + e] : (e - E);
            atomicAdd(&deg[d], 1);
        }
    }
}

__global__ __launch_bounds__(256) void transform2_kernel(
    const float* __restrict__ xin, const short* __restrict__ whi, const short* __restrict__ wlo,
    const float* __restrict__ a_src, const float* __restrict__ a_dst,
    __half* __restrict__ h, float* __restrict__ asrc, float* __restrict__ adst, int N)
{
    transform_body<64, 2, 8>(blockIdx.x, blockIdx.y, xin, whi, wlo, a_src, a_dst, h, asrc, adst, N);
}

// ---------------- per-dst aggregation ----------------
// Fast path (deg<=64, ~always): max butterfly -> ONE exp/lane/head -> sum
// butterfly; p reused as unnormalized weight. Slow path: online softmax.

__device__ __forceinline__ void edge_sweep(
    const int* __restrict__ soff, const uint2* __restrict__ sw,
    const __half* __restrict__ h, int boff, int cnt, float& accA, float& accB)
{
    int cnt2 = (cnt + 1) & ~1;
    for (int j = 0; j < cnt2; j += 2){
        int offA = __builtin_amdgcn_readfirstlane(soff[j]);
        int offB = __builtin_amdgcn_readfirstlane(soff[j + 1]);
        uint4 w4 = *(const uint4*)(sw + j);
        uint2 ha = *(const uint2*)((const char*)h + offA + boff);
        uint2 hb = *(const uint2*)((const char*)h + offB + boff);
        accA = __builtin_amdgcn_fdot2(bc16(ha.x), bc16(w4.x), accA, false);
        accA = __builtin_amdgcn_fdot2(bc16(ha.y), bc16(w4.y), accA, false);
        accB = __builtin_amdgcn_fdot2(bc16(hb.x), bc16(w4.z), accB, false);
        accB = __builtin_amdgcn_fdot2(bc16(hb.y), bc16(w4.w), accB, false);
    }
}

__global__ __launch_bounds__(256) void aggregate_kernel(
    const int* __restrict__ rowptr, const int* __restrict__ colsrc,
    const __half* __restrict__ h, const float* __restrict__ asrc,
    const float* __restrict__ adst, const float* __restrict__ bias,
    float* __restrict__ hout, int N)
{
    __shared__ int   s_off[4][64];
    __shared__ uint2 s_w[4][64];
    int tid = threadIdx.x;
    int wv = tid >> 6, lane = tid & 63;
    int n = blockIdx.x * 4 + wv;
    if (n >= N) return;
    int start = rowptr[n], end = rowptr[n + 1];
    int deg = end - start;
    const float4 ad = *(const float4*)(adst + (size_t)n * 4);

    int src0 = 0;
    float e0 = -1e30f, e1 = -1e30f, e2 = -1e30f, e3 = -1e30f;
    bool v0 = lane < deg;
    if (v0){
        src0 = colsrc[start + lane];
        float4 as = *(const float4*)(asrc + (size_t)src0 * 4);
        e0 = leaky(as.x + ad.x); e1 = leaky(as.y + ad.y);
        e2 = leaky(as.z + ad.z); e3 = leaky(as.w + ad.w);
    }

    float m0, m1, m2, m3, i0, i1, i2, i3, p0, p1, p2, p3;
    if (deg <= 64){
        m0 = e0; m1 = e1; m2 = e2; m3 = e3;
        #pragma unroll
        for (int off = 1; off < 64; off <<= 1){
            m0 = fmaxf(m0, __shfl_xor(m0, off));
            m1 = fmaxf(m1, __shfl_xor(m1, off));
            m2 = fmaxf(m2, __shfl_xor(m2, off));
            m3 = fmaxf(m3, __shfl_xor(m3, off));
        }
        p0 = __expf(e0 - m0);   // 0 for invalid lanes (underflow)
        p1 = __expf(e1 - m1);
        p2 = __expf(e2 - m2);
        p3 = __expf(e3 - m3);
        float t0 = p0, t1 = p1, t2 = p2, t3 = p3;
        #pragma unroll
        for (int off = 1; off < 64; off <<= 1){
            t0 += __shfl_xor(t0, off);
            t1 += __shfl_xor(t1, off);
            t2 += __shfl_xor(t2, off);
            t3 += __shfl_xor(t3, off);
        }
        i0 = 1.f / t0; i1 = 1.f / t1; i2 = 1.f / t2; i3 = 1.f / t3;
    } else {
        m0 = e0; m1 = e1; m2 = e2; m3 = e3;
        float t0 = v0 ? 1.f : 0.f, t1 = t0, t2 = t0, t3 = t0;
        for (int i = start + 64 + lane; i < end; i += 64){
            int s = colsrc[i];
            float4 as = *(const float4*)(asrc + (size_t)s * 4);
            float e, nm;
            e = leaky(as.x + ad.x); nm = fmaxf(m0, e); t0 = t0 * __expf(m0 - nm) + __expf(e - nm); m0 = nm;
            e = leaky(as.y + ad.y); nm = fmaxf(m1, e); t1 = t1 * __expf(m1 - nm) + __expf(e - nm); m1 = nm;
            e = leaky(as.z + ad.z); nm = fmaxf(m2, e); t2 = t2 * __expf(m2 - nm) + __expf(e - nm); m2 = nm;
            e = leaky(as.w + ad.w); nm = fmaxf(m3, e); t3 = t3 * __expf(m3 - nm) + __expf(e - nm); m3 = nm;
        }
        #pragma unroll
        for (int off = 1; off < 64; off <<= 1){
            float om, os, nm;
            om = __shfl_xor(m0, off); os = __shfl_xor(t0, off);
            nm = fmaxf(m0, om); t0 = t0 * __expf(m0 - nm) + os * __expf(om - nm); m0 = nm;
            om = __shfl_xor(m1, off); os = __shfl_xor(t1, off);
            nm = fmaxf(m1, om); t1 = t1 * __expf(m1 - nm) + os * __expf(om - nm); m1 = nm;
            om = __shfl_xor(m2, off); os = __shfl_xor(t2, off);
            nm = fmaxf(m2, om); t2 = t2 * __expf(m2 - nm) + os * __expf(om - nm); m2 = nm;
            om = __shfl_xor(m3, off); os = __shfl_xor(t3, off);
            nm = fmaxf(m3, om); t3 = t3 * __expf(m3 - nm) + os * __expf(om - nm); m3 = nm;
        }
        i0 = 1.f / t0; i1 = 1.f / t1; i2 = 1.f / t2; i3 = 1.f / t3;
        p0 = __expf(e0 - m0); p1 = __expf(e1 - m1);
        p2 = __expf(e2 - m2); p3 = __expf(e3 - m3);
    }

    float accA = 0.f, accB = 0.f;
    const int boff = lane * 8;
    {
        int off = v0 ? src0 * (HC * 2) : 0;
        s_off[wv][lane] = off;
        half2_t p01 = __builtin_amdgcn_cvt_pkrtz(p0 * i0, p1 * i1);
        half2_t p23 = __builtin_amdgcn_cvt_pkrtz(p2 * i2, p3 * i3);
        s_w[wv][lane] = (uint2){ __builtin_bit_cast(unsigned, p01),
                                 __builtin_bit_cast(unsigned, p23) };
        int cnt = deg < 64 ? deg : 64;
        edge_sweep(&s_off[wv][0], &s_w[wv][0], h, boff, cnt, accA, accB);
    }
    for (int base = start + 64; base < end; base += 64){
        int cnt = end - base; if (cnt > 64) cnt = 64;
        float w0 = 0.f, w1 = 0.f, w2 = 0.f, w3 = 0.f; int off = 0;
        if (lane < cnt){
            int s = colsrc[base + lane];
            float4 as = *(const float4*)(asrc + (size_t)s * 4);
            w0 = __expf(leaky(as.x + ad.x) - m0) * i0;
            w1 = __expf(leaky(as.y + ad.y) - m1) * i1;
            w2 = __expf(leaky(as.z + ad.z) - m2) * i2;
            w3 = __expf(leaky(as.w + ad.w) - m3) * i3;
            off = s * (HC * 2);
        }
        s_off[wv][lane] = off;
        half2_t p01 = __builtin_amdgcn_cvt_pkrtz(w0, w1);
        half2_t p23 = __builtin_amdgcn_cvt_pkrtz(w2, w3);
        s_w[wv][lane] = (uint2){ __builtin_bit_cast(unsigned, p01),
                                 __builtin_bit_cast(unsigned, p23) };
        edge_sweep(&s_off[wv][0], &s_w[wv][0], h, boff, cnt, accA, accB);
    }

    float o = (accA + accB) * 0.25f + bias[lane];
    hout[(size_t)n * CH + lane] = (o > 0.f) ? o : expm1f(o);
}

// ---------------- scorer: MFMA (bf16x3) for hmid@Ws1, fp32 epilogue ----------------

__global__ __launch_bounds__(256) void scorer_mfma_kernel(
    const float* __restrict__ h2, const short* __restrict__ s1hi, const short* __restrict__ s1lo,
    const float* __restrict__ d1p, const float* __restrict__ Ws2, const float* __restrict__ bs2,
    float* __restrict__ out, int N)
{
    constexpr int XP = 68, WP = 72;
    __shared__ float xl[64 * XP];
    __shared__ short whi[64 * WP];
    __shared__ short wlo[64 * WP];
    const int tid = threadIdx.x;
    const int n0 = blockIdx.x * 64;

    for (int t = tid; t < 64 * 16; t += 256) {
        int row = t >> 4, c4 = (t & 15) * 4;
        int n = n0 + row;
        float4 v = make_float4(0.f, 0.f, 0.f, 0.f);
        if (n < N) v = *(const float4*)(h2 + (size_t)n * 64 + c4);
        *(float4*)(xl + row * XP + c4) = v;
    }
    {
        const short8* ghi = (const short8*)s1hi;
        const short8* glo = (const short8*)s1lo;
        short8* lhi = (short8*)whi;
        short8* llo = (short8*)wlo;
        for (int t = tid; t < 64 * WP / 8; t += 256){ lhi[t] = ghi[t]; llo[t] = glo[t]; }
    }
    __syncthreads();

    const int wv = tid >> 6, lane = tid & 63;
    const int quad = lane >> 4, ln = lane & 15;
    const int myrow = wv * 16 + ln;

    f32x4 acc[4];
    #pragma unroll
    for (int i = 0; i < 4; ++i) acc[i] = (f32x4){0.f, 0.f, 0.f, 0.f};

    #pragma unroll
    for (int ks = 0; ks < 2; ++ks) {
        const int k0 = ks * 32 + quad * 8;
        const float* ap = xl + myrow * XP + k0;
        float4 f0 = *(const float4*)ap;
        float4 f1 = *(const float4*)(ap + 4);
        float fa[8] = {f0.x, f0.y, f0.z, f0.w, f1.x, f1.y, f1.z, f1.w};
        short8 ahi, alo;
        #pragma unroll
        for (int e = 0; e < 8; ++e) {
            short hi = bf16_rne(fa[e]);
            ahi[e] = hi;
            alo[e] = bf16_rne(fa[e] - bf16_to_f(hi));
        }
        #pragma unroll
        for (int nt = 0; nt < 4; ++nt) {
            short8 bhi = *(const short8*)(whi + (nt * 16 + ln) * WP + k0);
            short8 blo = *(const short8*)(wlo + (nt * 16 + ln) * WP + k0);
            acc[nt] = __builtin_amdgcn_mfma_f32_16x16x32_bf16(ahi, bhi, acc[nt], 0, 0, 0);
            acc[nt] = __builtin_amdgcn_mfma_f32_16x16x32_bf16(alo, bhi, acc[nt], 0, 0, 0);
            acc[nt] = __builtin_amdgcn_mfma_f32_16x16x32_bf16(ahi, blo, acc[nt], 0, 0, 0);
        }
    }

    float d1v[4], w2v[4];
    #pragma unroll
    for (int nt = 0; nt < 4; ++nt){
        d1v[nt] = d1p[nt * 16 + ln];
        w2v[nt] = Ws2[nt * 16 + ln];
    }
    float b2 = bs2[0];
    #pragma unroll
    for (int r = 0; r < 4; ++r){
        float t = 0.f;
        #pragma unroll
        for (int nt = 0; nt < 4; ++nt)
            t = fmaf(fmaxf(acc[nt][r] + d1v[nt], 0.f), w2v[nt], t);
        #pragma unroll
        for (int off = 1; off < 16; off <<= 1) t += __shfl_xor(t, off);
        if (ln == 0){
            int n = n0 + wv * 16 + quad * 4 + r;
            if (n < N) out[n] = t + b2;
        }
    }
}

// ---------------- launch ----------------

extern "C" void kernel_launch(void* const* d_in, const int* in_sizes, int n_in,
                              void* d_out, int out_size, void* d_ws, size_t ws_size,
                              hipStream_t stream)
{
    const float* x    = (const float*)d_in[0];
    const int*   ei   = (const int*)  d_in[1];
    const float* donor= (const float*)d_in[2];
    const float* W1   = (const float*)d_in[3];
    const float* as1  = (const float*)d_in[4];
    const float* ad1  = (const float*)d_in[5];
    const float* b1   = (const float*)d_in[6];
    const float* W2   = (const float*)d_in[7];
    const float* as2  = (const float*)d_in[8];
    const float* ad2  = (const float*)d_in[9];
    const float* b2   = (const float*)d_in[10];
    const float* Ws1  = (const float*)d_in[11];
    const float* bs1  = (const float*)d_in[12];
    const float* Ws2  = (const float*)d_in[13];
    const float* bs2  = (const float*)d_in[14];

    const int N  = in_sizes[0] / 27;
    const int E  = in_sizes[1] / 2;
    const int ET = E + N;

    char* ws = (char*)d_ws;
    auto alloc = [&](size_t bytes) -> void* {
        void* p = (void*)ws;
        ws += (bytes + 255) / 256 * 256;
        return p;
    };
    int*    rowptr = (int*)   alloc((size_t)(N + 1) * 4);
    int*    deg    = (int*)   alloc((size_t)N * 4);
    int*    cursor = (int*)   alloc((size_t)N * 4);
    int*    colsrc = (int*)   alloc((size_t)ET * 4);
    __half* hbig   = (__half*)alloc((size_t)N * HC * 2);
    float*  asrc   = (float*) alloc((size_t)N * 4 * 4);
    float*  adst   = (float*) alloc((size_t)N * 4 * 4);
    float*  hmid   = (float*) alloc((size_t)N * CH * 4);
    const int SB = (N + SCAN_TILE - 1) / SCAN_TILE;
    int*    bsum   = (int*)   alloc((size_t)SB * 4);
    short*  w1hi   = (short*) alloc(256 * 40 * 2);
    short*  w1lo   = (short*) alloc(256 * 40 * 2);
    short*  w2hi   = (short*) alloc(256 * 72 * 2);
    short*  w2lo   = (short*) alloc(256 * 72 * 2);
    short*  s1hi   = (short*) alloc(64 * 72 * 2);
    short*  s1lo   = (short*) alloc(64 * 72 * 2);
    float*  d1p    = (float*) alloc(64 * 4);

    const int nblk = (N + 63) / 64;
    const int cblk = (ET + 255) / 256;

    // 1. prep
    prep_kernel<<<256, 256, 0, stream>>>(W1, W2, Ws1, bs1, donor,
        deg, w1hi, w1lo, w2hi, w2lo, s1hi, s1lo, d1p, N);
    // 2. layer1 transform + edge count
    transform1_count_kernel<<<nblk + cblk, 256, 0, stream>>>(
        x, w1hi, w1lo, as1, ad1, hbig, asrc, adst, N, nblk, ei, E, deg);
    // 3-4. scan
    blocksum_kernel<<<SB, 256, 0, stream>>>(deg, N, bsum);
    scan_write_kernel<<<SB, 256, 0, stream>>>(deg, bsum, N, ET, rowptr, cursor);
    // 5. scatter
    scatter_kernel<<<cblk, 256, 0, stream>>>(ei, E, N, cursor, colsrc);
    // 6. aggregate layer1
    aggregate_kernel<<<(N + 3) / 4, 256, 0, stream>>>(
        rowptr, colsrc, hbig, asrc, adst, b1, hmid, N);
    // 7. layer2 transform
    transform2_kernel<<<dim3(nblk, 2), 256, 0, stream>>>(
        hmid, w2hi, w2lo, as2, ad2, hbig, asrc, adst, N);
    // 8. aggregate layer2
    aggregate_kernel<<<(N + 3) / 4, 256, 0, stream>>>(
        rowptr, colsrc, hbig, asrc, adst, b2, hmid, N);
    // 9. scorer
    scorer_mfma_kernel<<<nblk, 256, 0, stream>>>(
        hmid, s1hi, s1lo, d1p, Ws2, bs2, (float*)d_out, N);
}

// Round 9
// 368.131 us; speedup vs baseline: 1.0568x; 1.0051x over previous
//
#include <hip/hip_runtime.h>
#include <hip/hip_fp16.h>
#include <cmath>

#define HEADS 4
#define CH 64
#define HC 256
#define NEG 0.2f
#define SCAN_TILE 2048

typedef __attribute__((ext_vector_type(8))) short short8;
typedef __attribute__((ext_vector_type(4))) float f32x4;
typedef __fp16 half2_t __attribute__((ext_vector_type(2)));

__device__ __forceinline__ float leaky(float v){ return v > 0.f ? v : NEG * v; }

__device__ __forceinline__ short bf16_rne(float f){
    unsigned u = __float_as_uint(f);
    unsigned r = u + 0x7fffu + ((u >> 16) & 1u);
    return (short)(r >> 16);
}
__device__ __forceinline__ float bf16_to_f(short s){
    return __uint_as_float(((unsigned)(unsigned short)s) << 16);
}
__device__ __forceinline__ half2_t bc16(unsigned u){ return __builtin_bit_cast(half2_t, u); }
__device__ __forceinline__ unsigned packh2(float a, float b){
    __half ha = __float2half(a), hb = __float2half(b);   // RNE
    return (unsigned)__builtin_bit_cast(unsigned short, ha)
         | ((unsigned)__builtin_bit_cast(unsigned short, hb) << 16);
}

// ---------------- prep: weight splits + d1 + edge count (deg zeroed by memset) ----------------

__global__ __launch_bounds__(256) void prep_count_kernel(
    const float* __restrict__ W1, const float* __restrict__ W2,
    const float* __restrict__ Ws1, const float* __restrict__ bs1,
    const float* __restrict__ donor,
    int* __restrict__ deg, short* __restrict__ w1hi, short* __restrict__ w1lo,
    short* __restrict__ w2hi, short* __restrict__ w2lo,
    short* __restrict__ s1hi, short* __restrict__ s1lo,
    float* __restrict__ d1p, int N, const int* __restrict__ ei, int E)
{
    int t = blockIdx.x * 256 + threadIdx.x;
    int T = gridDim.x * 256;
    for (int i = t; i < 256 * 40; i += T){                  // W1: [n=256][k pitch 40], K=27
        int n = i / 40, k = i % 40;
        float v = (k < 27) ? W1[(size_t)k * HC + n] : 0.f;
        short hi = bf16_rne(v);
        w1hi[i] = hi; w1lo[i] = bf16_rne(v - bf16_to_f(hi));
    }
    for (int i = t; i < 256 * 72; i += T){                  // W2: [n=256][k pitch 72], K=64
        int n = i / 72, k = i % 72;
        float v = (k < 64) ? W2[(size_t)k * HC + n] : 0.f;
        short hi = bf16_rne(v);
        w2hi[i] = hi; w2lo[i] = bf16_rne(v - bf16_to_f(hi));
    }
    for (int i = t; i < 64 * 72; i += T){                   // Ws1 h-part: [j=64][k pitch 72], K=64
        int n = i / 72, k = i % 72;
        float v = (k < 64) ? Ws1[(size_t)k * 64 + n] : 0.f;
        short hi = bf16_rne(v);
        s1hi[i] = hi; s1lo[i] = bf16_rne(v - bf16_to_f(hi));
    }
    if (t < 64){                                            // d1 = bs1 + donor @ Ws1[64:96]
        float s = bs1[t];
        for (int k = 0; k < 32; ++k) s = fmaf(donor[k], Ws1[(size_t)(64 + k) * 64 + t], s);
        d1p[t] = s;
    }
    int ET = E + N;
    for (int e = t; e < ET; e += T){
        int d = (e < E) ? ei[E + e] : (e - E);
        atomicAdd(&deg[d], 1);
    }
}

// ---------------- CSR scan ----------------

__global__ void blocksum_kernel(const int* __restrict__ deg, int N, int* __restrict__ bsum){
    __shared__ int wsum[4];
    int tid = threadIdx.x;
    int base = blockIdx.x * SCAN_TILE;
    int s = 0;
    for (int i = tid; i < SCAN_TILE; i += 256){
        int idx = base + i;
        s += (idx < N) ? deg[idx] : 0;
    }
    #pragma unroll
    for (int off = 32; off > 0; off >>= 1) s += __shfl_down(s, off);
    if ((tid & 63) == 0) wsum[tid >> 6] = s;
    __syncthreads();
    if (tid == 0) bsum[blockIdx.x] = wsum[0] + wsum[1] + wsum[2] + wsum[3];
}

__global__ void scan_write_kernel(const int* __restrict__ deg, const int* __restrict__ bsum,
                                  int N, int ET, int* __restrict__ rowptr, int* __restrict__ cursor){
    __shared__ int wsum[4];
    __shared__ int bpre;
    int tid = threadIdx.x;
    if (tid < 64){
        int v = (tid < blockIdx.x) ? bsum[tid] : 0;
        #pragma unroll
        for (int off = 32; off > 0; off >>= 1) v += __shfl_down(v, off);
        if (tid == 0) bpre = v;
    }
    if (blockIdx.x == 0 && tid == 0) rowptr[N] = ET;
    int base = blockIdx.x * SCAN_TILE + tid * 8;
    int v[8]; int s = 0;
    #pragma unroll
    for (int j = 0; j < 8; ++j){
        int idx = base + j;
        v[j] = (idx < N) ? deg[idx] : 0;
        s += v[j];
    }
    int lane = tid & 63, wv = tid >> 6;
    int incl = s;
    #pragma unroll
    for (int off = 1; off < 64; off <<= 1){
        int tt = __shfl_up(incl, off);
        if (lane >= off) incl += tt;
    }
    if (lane == 63) wsum[wv] = incl;
    __syncthreads();
    int excl = incl - s + bpre;
    for (int w = 0; w < wv; ++w) excl += wsum[w];
    #pragma unroll
    for (int j = 0; j < 8; ++j){
        int idx = base + j;
        if (idx < N){ rowptr[idx] = excl; cursor[idx] = excl; excl += v[j]; }
    }
}

// ---------------- MFMA node transform (device body) ----------------

template<int FIN, int KSTEPS, int NT>
__device__ __forceinline__ void transform_body(
    int bx, int by,
    const float* __restrict__ xin, const short* __restrict__ whi, const short* __restrict__ wlo,
    const float* __restrict__ a_src, const float* __restrict__ a_dst,
    __half* __restrict__ h, float* __restrict__ asrc, float* __restrict__ adst, int N)
{
    constexpr int KP = KSTEPS * 32;
    constexpr int XP = KP + 4;
    constexpr int WP = KP + 8;
    constexpr int NCOL = NT * 16;
    __shared__ float xl[64 * XP];
    __shared__ short wt_hi[NCOL * WP];
    __shared__ short wt_lo[NCOL * WP];

    const int tid = threadIdx.x;
    const int n0 = bx * 64;
    const int c0 = by * NCOL;

    if (FIN == 64) {
        for (int t = tid; t < 64 * 16; t += 256) {
            int row = t >> 4, c4 = (t & 15) * 4;
            int n = n0 + row;
            float4 v = make_float4(0.f, 0.f, 0.f, 0.f);
            if (n < N) v = *(const float4*)(xin + (size_t)n * 64 + c4);
            *(float4*)(xl + row * XP + c4) = v;
        }
    } else {
        for (int t = tid; t < 64 * KP; t += 256) {
            int row = t / KP, k = t % KP;
            int n = n0 + row;
            float v = 0.f;
            if (n < N && k < FIN) v = xin[(size_t)n * FIN + k];
            xl[row * XP + k] = v;
        }
    }
    {
        const short8* ghi = (const short8*)(whi + (size_t)c0 * WP);
        const short8* glo = (const short8*)(wlo + (size_t)c0 * WP);
        short8* lhi = (short8*)wt_hi;
        short8* llo = (short8*)wt_lo;
        for (int t = tid; t < NCOL * WP / 8; t += 256){
            lhi[t] = ghi[t];
            llo[t] = glo[t];
        }
    }
    __syncthreads();

    const int wv = tid >> 6, lane = tid & 63;
    const int quad = lane >> 4, ln = lane & 15;
    const int myrow = wv * 16 + ln;

    f32x4 acc[NT];
    #pragma unroll
    for (int i = 0; i < NT; ++i) acc[i] = (f32x4){0.f, 0.f, 0.f, 0.f};

    #pragma unroll
    for (int ks = 0; ks < KSTEPS; ++ks) {
        const int k0 = ks * 32 + quad * 8;
        const float* ap = xl + myrow * XP + k0;
        float4 f0 = *(const float4*)ap;
        float4 f1 = *(const float4*)(ap + 4);
        float fa[8] = {f0.x, f0.y, f0.z, f0.w, f1.x, f1.y, f1.z, f1.w};
        short8 ahi, alo;
        #pragma unroll
        for (int e = 0; e < 8; ++e) {
            short hi = bf16_rne(fa[e]);
            ahi[e] = hi;
            alo[e] = bf16_rne(fa[e] - bf16_to_f(hi));
        }
        #pragma unroll
        for (int nt = 0; nt < NT; ++nt) {
            short8 bhi = *(const short8*)(wt_hi + (nt * 16 + ln) * WP + k0);
            short8 blo = *(const short8*)(wt_lo + (nt * 16 + ln) * WP + k0);
            acc[nt] = __builtin_amdgcn_mfma_f32_16x16x32_bf16(ahi, bhi, acc[nt], 0, 0, 0);
            acc[nt] = __builtin_amdgcn_mfma_f32_16x16x32_bf16(alo, bhi, acc[nt], 0, 0, 0);
            acc[nt] = __builtin_amdgcn_mfma_f32_16x16x32_bf16(ahi, blo, acc[nt], 0, 0, 0);
        }
    }

    #pragma unroll
    for (int r = 0; r < 4; ++r) {
        int n = n0 + wv * 16 + quad * 4 + r;
        if (n < N) {
            if (NT == 16) {
                #pragma unroll
                for (int q = 0; q < 4; ++q) {
                    uint2 u;
                    u.x = packh2(acc[q][r],     acc[q + 4][r]);
                    u.y = packh2(acc[q + 8][r], acc[q + 12][r]);
                    *(uint2*)((char*)h + (size_t)n * 512 + (q * 16 + ln) * 8) = u;
                }
            } else {
                // NT==8: two heads per block; c0 selects byte-pair slot
                #pragma unroll
                for (int q = 0; q < 4; ++q) {
                    unsigned u = packh2(acc[q][r], acc[q + 4][r]);
                    *(unsigned*)((char*)h + (size_t)n * 512 + (q * 16 + ln) * 8 + ((c0 >> 6) << 1)) = u;
                }
            }
        }
    }

    float aS[NT], aD[NT];
    #pragma unroll
    for (int nt = 0; nt < NT; ++nt) {
        aS[nt] = a_src[c0 + nt * 16 + ln];
        aD[nt] = a_dst[c0 + nt * 16 + ln];
    }
    #pragma unroll
    for (int hl = 0; hl < NT / 4; ++hl) {
        #pragma unroll
        for (int r = 0; r < 4; ++r) {
            float ps = 0.f, pd = 0.f;
            #pragma unroll
            for (int i = 0; i < 4; ++i) {
                ps = fmaf(acc[hl * 4 + i][r], aS[hl * 4 + i], ps);
                pd = fmaf(acc[hl * 4 + i][r], aD[hl * 4 + i], pd);
            }
            #pragma unroll
            for (int off = 1; off < 16; off <<= 1) {
                ps += __shfl_xor(ps, off);
                pd += __shfl_xor(pd, off);
            }
            if (ln == 0) {
                int n = n0 + wv * 16 + quad * 4 + r;
                if (n < N) {
                    int hg = c0 / 64 + hl;
                    asrc[n * 4 + hg] = ps;
                    adst[n * 4 + hg] = pd;
                }
            }
        }
    }
}

// layer1 transform (NT=8, halved LDS) fused with edge scatter — independent work,
// scatter's write-path stalls overlap transform's MFMA/LDS work.
__global__ __launch_bounds__(256) void transform1_scatter_kernel(
    const float* __restrict__ xin, const short* __restrict__ whi, const short* __restrict__ wlo,
    const float* __restrict__ a_src, const float* __restrict__ a_dst,
    __half* __restrict__ h, float* __restrict__ asrc, float* __restrict__ adst, int N,
    int tblk, const int* __restrict__ ei, int E,
    int* __restrict__ cursor, int* __restrict__ colsrc)
{
    if ((int)blockIdx.x < tblk) {
        transform_body<27, 1, 8>(blockIdx.x >> 1, blockIdx.x & 1,
                                 xin, whi, wlo, a_src, a_dst, h, asrc, adst, N);
    } else {
        int e = (blockIdx.x - tblk) * 256 + threadIdx.x;
        int ET = E + N;
        if (e < ET){
            int s, d;
            if (e < E){ s = ei[e]; d = ei[E + e]; } else { s = d = e - E; }
            int pos = atomicAdd(&cursor[d], 1);
            colsrc[pos] = s;
        }
    }
}

__global__ __launch_bounds__(256) void transform2_kernel(
    const float* __restrict__ xin, const short* __restrict__ whi, const short* __restrict__ wlo,
    const float* __restrict__ a_src, const float* __restrict__ a_dst,
    __half* __restrict__ h, float* __restrict__ asrc, float* __restrict__ adst, int N)
{
    transform_body<64, 2, 8>(blockIdx.x, blockIdx.y, xin, whi, wlo, a_src, a_dst, h, asrc, adst, N);
}

// ---------------- per-dst aggregation ----------------
// Fast path (deg<=64, ~always): max butterfly -> ONE exp/lane/head -> sum
// butterfly; p reused as unnormalized weight. edge_sweep unrolled x4 for MLP.

__device__ __forceinline__ void edge_sweep(
    const int* __restrict__ soff, const uint2* __restrict__ sw,
    const __half* __restrict__ h, int boff, int cnt,
    float& accA, float& accB, float& accC, float& accD)
{
    int cnt4 = (cnt + 3) & ~3;
    for (int j = 0; j < cnt4; j += 4){
        int offA = __builtin_amdgcn_readfirstlane(soff[j]);
        int offB = __builtin_amdgcn_readfirstlane(soff[j + 1]);
        int offC = __builtin_amdgcn_readfirstlane(soff[j + 2]);
        int offD = __builtin_amdgcn_readfirstlane(soff[j + 3]);
        uint4 w01 = *(const uint4*)(sw + j);
        uint4 w23 = *(const uint4*)(sw + j + 2);
        uint2 ha = *(const uint2*)((const char*)h + offA + boff);
        uint2 hb = *(const uint2*)((const char*)h + offB + boff);
        uint2 hc = *(const uint2*)((const char*)h + offC + boff);
        uint2 hd = *(const uint2*)((const char*)h + offD + boff);
        accA = __builtin_amdgcn_fdot2(bc16(ha.x), bc16(w01.x), accA, false);
        accA = __builtin_amdgcn_fdot2(bc16(ha.y), bc16(w01.y), accA, false);
        accB = __builtin_amdgcn_fdot2(bc16(hb.x), bc16(w01.z), accB, false);
        accB = __builtin_amdgcn_fdot2(bc16(hb.y), bc16(w01.w), accB, false);
        accC = __builtin_amdgcn_fdot2(bc16(hc.x), bc16(w23.x), accC, false);
        accC = __builtin_amdgcn_fdot2(bc16(hc.y), bc16(w23.y), accC, false);
        accD = __builtin_amdgcn_fdot2(bc16(hd.x), bc16(w23.z), accD, false);
        accD = __builtin_amdgcn_fdot2(bc16(hd.y), bc16(w23.w), accD, false);
    }
}

__global__ __launch_bounds__(256) void aggregate_kernel(
    const int* __restrict__ rowptr, const int* __restrict__ colsrc,
    const __half* __restrict__ h, const float* __restrict__ asrc,
    const float* __restrict__ adst, const float* __restrict__ bias,
    float* __restrict__ hout, int N)
{
    __shared__ int   s_off[4][64];
    __shared__ uint2 s_w[4][64];
    int tid = threadIdx.x;
    int wv = tid >> 6, lane = tid & 63;
    int n = blockIdx.x * 4 + wv;
    if (n >= N) return;
    int start = rowptr[n], end = rowptr[n + 1];
    int deg = end - start;
    const float4 ad = *(const float4*)(adst + (size_t)n * 4);

    int src0 = 0;
    float e0 = -1e30f, e1 = -1e30f, e2 = -1e30f, e3 = -1e30f;
    bool v0 = lane < deg;
    if (v0){
        src0 = colsrc[start + lane];
        float4 as = *(const float4*)(asrc + (size_t)src0 * 4);
        e0 = leaky(as.x + ad.x); e1 = leaky(as.y + ad.y);
        e2 = leaky(as.z + ad.z); e3 = leaky(as.w + ad.w);
    }

    float m0, m1, m2, m3, i0, i1, i2, i3, p0, p1, p2, p3;
    if (deg <= 64){
        m0 = e0; m1 = e1; m2 = e2; m3 = e3;
        #pragma unroll
        for (int off = 1; off < 64; off <<= 1){
            m0 = fmaxf(m0, __shfl_xor(m0, off));
            m1 = fmaxf(m1, __shfl_xor(m1, off));
            m2 = fmaxf(m2, __shfl_xor(m2, off));
            m3 = fmaxf(m3, __shfl_xor(m3, off));
        }
        p0 = __expf(e0 - m0);   // 0 for invalid lanes (underflow)
        p1 = __expf(e1 - m1);
        p2 = __expf(e2 - m2);
        p3 = __expf(e3 - m3);
        float t0 = p0, t1 = p1, t2 = p2, t3 = p3;
        #pragma unroll
        for (int off = 1; off < 64; off <<= 1){
            t0 += __shfl_xor(t0, off);
            t1 += __shfl_xor(t1, off);
            t2 += __shfl_xor(t2, off);
            t3 += __shfl_xor(t3, off);
        }
        i0 = 1.f / t0; i1 = 1.f / t1; i2 = 1.f / t2; i3 = 1.f / t3;
    } else {
        m0 = e0; m1 = e1; m2 = e2; m3 = e3;
        float t0 = v0 ? 1.f : 0.f, t1 = t0, t2 = t0, t3 = t0;
        for (int i = start + 64 + lane; i < end; i += 64){
            int s = colsrc[i];
            float4 as = *(const float4*)(asrc + (size_t)s * 4);
            float e, nm;
            e = leaky(as.x + ad.x); nm = fmaxf(m0, e); t0 = t0 * __expf(m0 - nm) + __expf(e - nm); m0 = nm;
            e = leaky(as.y + ad.y); nm = fmaxf(m1, e); t1 = t1 * __expf(m1 - nm) + __expf(e - nm); m1 = nm;
            e = leaky(as.z + ad.z); nm = fmaxf(m2, e); t2 = t2 * __expf(m2 - nm) + __expf(e - nm); m2 = nm;
            e = leaky(as.w + ad.w); nm = fmaxf(m3, e); t3 = t3 * __expf(m3 - nm) + __expf(e - nm); m3 = nm;
        }
        #pragma unroll
        for (int off = 1; off < 64; off <<= 1){
            float om, os, nm;
            om = __shfl_xor(m0, off); os = __shfl_xor(t0, off);
            nm = fmaxf(m0, om); t0 = t0 * __expf(m0 - nm) + os * __expf(om - nm); m0 = nm;
            om = __shfl_xor(m1, off); os = __shfl_xor(t1, off);
            nm = fmaxf(m1, om); t1 = t1 * __expf(m1 - nm) + os * __expf(om - nm); m1 = nm;
            om = __shfl_xor(m2, off); os = __shfl_xor(t2, off);
            nm = fmaxf(m2, om); t2 = t2 * __expf(m2 - nm) + os * __expf(om - nm); m2 = nm;
            om = __shfl_xor(m3, off); os = __shfl_xor(t3, off);
            nm = fmaxf(m3, om); t3 = t3 * __expf(m3 - nm) + os * __expf(om - nm); m3 = nm;
        }
        i0 = 1.f / t0; i1 = 1.f / t1; i2 = 1.f / t2; i3 = 1.f / t3;
        p0 = __expf(e0 - m0); p1 = __expf(e1 - m1);
        p2 = __expf(e2 - m2); p3 = __expf(e3 - m3);
    }

    float accA = 0.f, accB = 0.f, accC = 0.f, accD = 0.f;
    const int boff = lane * 8;
    {
        int off = v0 ? src0 * (HC * 2) : 0;
        s_off[wv][lane] = off;
        half2_t p01 = __builtin_amdgcn_cvt_pkrtz(p0 * i0, p1 * i1);
        half2_t p23 = __builtin_amdgcn_cvt_pkrtz(p2 * i2, p3 * i3);
        s_w[wv][lane] = (uint2){ __builtin_bit_cast(unsigned, p01),
                                 __builtin_bit_cast(unsigned, p23) };
        int cnt = deg < 64 ? deg : 64;
        edge_sweep(&s_off[wv][0], &s_w[wv][0], h, boff, cnt, accA, accB, accC, accD);
    }
    for (int base = start + 64; base < end; base += 64){
        int cnt = end - base; if (cnt > 64) cnt = 64;
        float w0 = 0.f, w1 = 0.f, w2 = 0.f, w3 = 0.f; int off = 0;
        if (lane < cnt){
            int s = colsrc[base + lane];
            float4 as = *(const float4*)(asrc + (size_t)s * 4);
            w0 = __expf(leaky(as.x + ad.x) - m0) * i0;
            w1 = __expf(leaky(as.y + ad.y) - m1) * i1;
            w2 = __expf(leaky(as.z + ad.z) - m2) * i2;
            w3 = __expf(leaky(as.w + ad.w) - m3) * i3;
            off = s * (HC * 2);
        }
        s_off[wv][lane] = off;
        half2_t p01 = __builtin_amdgcn_cvt_pkrtz(w0, w1);
        half2_t p23 = __builtin_amdgcn_cvt_pkrtz(w2, w3);
        s_w[wv][lane] = (uint2){ __builtin_bit_cast(unsigned, p01),
                                 __builtin_bit_cast(unsigned, p23) };
        edge_sweep(&s_off[wv][0], &s_w[wv][0], h, boff, cnt, accA, accB, accC, accD);
    }

    float o = (accA + accB + accC + accD) * 0.25f + bias[lane];
    hout[(size_t)n * CH + lane] = (o > 0.f) ? o : expm1f(o);
}

// ---------------- scorer: MFMA (bf16x3) for hmid@Ws1, fp32 epilogue ----------------

__global__ __launch_bounds__(256) void scorer_mfma_kernel(
    const float* __restrict__ h2, const short* __restrict__ s1hi, const short* __restrict__ s1lo,
    const float* __restrict__ d1p, const float* __restrict__ Ws2, const float* __restrict__ bs2,
    float* __restrict__ out, int N)
{
    constexpr int XP = 68, WP = 72;
    __shared__ float xl[64 * XP];
    __shared__ short whi[64 * WP];
    __shared__ short wlo[64 * WP];
    const int tid = threadIdx.x;
    const int n0 = blockIdx.x * 64;

    for (int t = tid; t < 64 * 16; t += 256) {
        int row = t >> 4, c4 = (t & 15) * 4;
        int n = n0 + row;
        float4 v = make_float4(0.f, 0.f, 0.f, 0.f);
        if (n < N) v = *(const float4*)(h2 + (size_t)n * 64 + c4);
        *(float4*)(xl + row * XP + c4) = v;
    }
    {
        const short8* ghi = (const short8*)s1hi;
        const short8* glo = (const short8*)s1lo;
        short8* lhi = (short8*)whi;
        short8* llo = (short8*)wlo;
        for (int t = tid; t < 64 * WP / 8; t += 256){ lhi[t] = ghi[t]; llo[t] = glo[t]; }
    }
    __syncthreads();

    const int wv = tid >> 6, lane = tid & 63;
    const int quad = lane >> 4, ln = lane & 15;
    const int myrow = wv * 16 + ln;

    f32x4 acc[4];
    #pragma unroll
    for (int i = 0; i < 4; ++i) acc[i] = (f32x4){0.f, 0.f, 0.f, 0.f};

    #pragma unroll
    for (int ks = 0; ks < 2; ++ks) {
        const int k0 = ks * 32 + quad * 8;
        const float* ap = xl + myrow * XP + k0;
        float4 f0 = *(const float4*)ap;
        float4 f1 = *(const float4*)(ap + 4);
        float fa[8] = {f0.x, f0.y, f0.z, f0.w, f1.x, f1.y, f1.z, f1.w};
        short8 ahi, alo;
        #pragma unroll
        for (int e = 0; e < 8; ++e) {
            short hi = bf16_rne(fa[e]);
            ahi[e] = hi;
            alo[e] = bf16_rne(fa[e] - bf16_to_f(hi));
        }
        #pragma unroll
        for (int nt = 0; nt < 4; ++nt) {
            short8 bhi = *(const short8*)(whi + (nt * 16 + ln) * WP + k0);
            short8 blo = *(const short8*)(wlo + (nt * 16 + ln) * WP + k0);
            acc[nt] = __builtin_amdgcn_mfma_f32_16x16x32_bf16(ahi, bhi, acc[nt], 0, 0, 0);
            acc[nt] = __builtin_amdgcn_mfma_f32_16x16x32_bf16(alo, bhi, acc[nt], 0, 0, 0);
            acc[nt] = __builtin_amdgcn_mfma_f32_16x16x32_bf16(ahi, blo, acc[nt], 0, 0, 0);
        }
    }

    float d1v[4], w2v[4];
    #pragma unroll
    for (int nt = 0; nt < 4; ++nt){
        d1v[nt] = d1p[nt * 16 + ln];
        w2v[nt] = Ws2[nt * 16 + ln];
    }
    float b2 = bs2[0];
    #pragma unroll
    for (int r = 0; r < 4; ++r){
        float t = 0.f;
        #pragma unroll
        for (int nt = 0; nt < 4; ++nt)
            t = fmaf(fmaxf(acc[nt][r] + d1v[nt], 0.f), w2v[nt], t);
        #pragma unroll
        for (int off = 1; off < 16; off <<= 1) t += __shfl_xor(t, off);
        if (ln == 0){
            int n = n0 + wv * 16 + quad * 4 + r;
            if (n < N) out[n] = t + b2;
        }
    }
}

// ---------------- launch ----------------

extern "C" void kernel_launch(void* const* d_in, const int* in_sizes, int n_in,
                              void* d_out, int out_size, void* d_ws, size_t ws_size,
                              hipStream_t stream)
{
    const float* x    = (const float*)d_in[0];
    const int*   ei   = (const int*)  d_in[1];
    const float* donor= (const float*)d_in[2];
    const float* W1   = (const float*)d_in[3];
    const float* as1  = (const float*)d_in[4];
    const float* ad1  = (const float*)d_in[5];
    const float* b1   = (const float*)d_in[6];
    const float* W2   = (const float*)d_in[7];
    const float* as2  = (const float*)d_in[8];
    const float* ad2  = (const float*)d_in[9];
    const float* b2   = (const float*)d_in[10];
    const float* Ws1  = (const float*)d_in[11];
    const float* bs1  = (const float*)d_in[12];
    const float* Ws2  = (const float*)d_in[13];
    const float* bs2  = (const float*)d_in[14];

    const int N  = in_sizes[0] / 27;
    const int E  = in_sizes[1] / 2;
    const int ET = E + N;

    char* ws = (char*)d_ws;
    auto alloc = [&](size_t bytes) -> void* {
        void* p = (void*)ws;
        ws += (bytes + 255) / 256 * 256;
        return p;
    };
    int*    rowptr = (int*)   alloc((size_t)(N + 1) * 4);
    int*    deg    = (int*)   alloc((size_t)N * 4);
    int*    cursor = (int*)   alloc((size_t)N * 4);
    int*    colsrc = (int*)   alloc((size_t)ET * 4);
    __half* hbig   = (__half*)alloc((size_t)N * HC * 2);
    float*  asrc   = (float*) alloc((size_t)N * 4 * 4);
    float*  adst   = (float*) alloc((size_t)N * 4 * 4);
    float*  hmid   = (float*) alloc((size_t)N * CH * 4);
    const int SB = (N + SCAN_TILE - 1) / SCAN_TILE;
    int*    bsum   = (int*)   alloc((size_t)SB * 4);
    short*  w1hi   = (short*) alloc(256 * 40 * 2);
    short*  w1lo   = (short*) alloc(256 * 40 * 2);
    short*  w2hi   = (short*) alloc(256 * 72 * 2);
    short*  w2lo   = (short*) alloc(256 * 72 * 2);
    short*  s1hi   = (short*) alloc(64 * 72 * 2);
    short*  s1lo   = (short*) alloc(64 * 72 * 2);
    float*  d1p    = (float*) alloc(64 * 4);

    const int nblk = (N + 63) / 64;
    const int cblk = (ET + 255) / 256;
    const int tblk = nblk * 2;   // transform1 split into 2 column-halves

    // 1. zero deg + prep (weights, d1) + count
    (void)hipMemsetAsync(deg, 0, (size_t)N * 4, stream);
    prep_count_kernel<<<256, 256, 0, stream>>>(W1, W2, Ws1, bs1, donor,
        deg, w1hi, w1lo, w2hi, w2lo, s1hi, s1lo, d1p, N, ei, E);
    // 2-3. scan
    blocksum_kernel<<<SB, 256, 0, stream>>>(deg, N, bsum);
    scan_write_kernel<<<SB, 256, 0, stream>>>(deg, bsum, N, ET, rowptr, cursor);
    // 4. layer1 transform + edge scatter (overlapped)
    transform1_scatter_kernel<<<tblk + cblk, 256, 0, stream>>>(
        x, w1hi, w1lo, as1, ad1, hbig, asrc, adst, N, tblk, ei, E, cursor, colsrc);
    // 5. aggregate layer1
    aggregate_kernel<<<(N + 3) / 4, 256, 0, stream>>>(
        rowptr, colsrc, hbig, asrc, adst, b1, hmid, N);
    // 6. layer2 transform
    transform2_kernel<<<dim3(nblk, 2), 256, 0, stream>>>(
        hmid, w2hi, w2lo, as2, ad2, hbig, asrc, adst, N);
    // 7. aggregate layer2
    aggregate_kernel<<<(N + 3) / 4, 256, 0, stream>>>(
        rowptr, colsrc, hbig, asrc, adst, b2, hmid, N);
    // 8. scorer
    scorer_mfma_kernel<<<nblk, 256, 0, stream>>>(
        hmid, s1hi, s1lo, d1p, Ws2, bs2, (float*)d_out, N);
}

// Round 10
// 308.183 us; speedup vs baseline: 1.2624x; 1.1945x over previous
//
#include <hip/hip_runtime.h>
#include <hip/hip_fp16.h>
#include <cmath>

#define HEADS 4
#define CH 64
#define HC 256
#define NEG 0.2f

typedef __attribute__((ext_vector_type(8))) short short8;
typedef __attribute__((ext_vector_type(4))) float f32x4;
typedef __fp16 half2_t __attribute__((ext_vector_type(2)));

__device__ __forceinline__ float leaky(float v){ return v > 0.f ? v : NEG * v; }

__device__ __forceinline__ short bf16_rne(float f){
    unsigned u = __float_as_uint(f);
    unsigned r = u + 0x7fffu + ((u >> 16) & 1u);
    return (short)(r >> 16);
}
__device__ __forceinline__ float bf16_to_f(short s){
    return __uint_as_float(((unsigned)(unsigned short)s) << 16);
}
__device__ __forceinline__ half2_t bc16(unsigned u){ return __builtin_bit_cast(half2_t, u); }
__device__ __forceinline__ unsigned packh2(float a, float b){
    __half ha = __float2half(a), hb = __float2half(b);   // RNE
    return (unsigned)__builtin_bit_cast(unsigned short, ha)
         | ((unsigned)__builtin_bit_cast(unsigned short, hb) << 16);
}

// block-wide exclusive scan of one int per thread (256 threads)
__device__ __forceinline__ int block_excl_scan(int v, int* ws4){
    int tid = threadIdx.x, lane = tid & 63, wv = tid >> 6;
    int incl = v;
    #pragma unroll
    for (int off = 1; off < 64; off <<= 1){
        int t = __shfl_up(incl, off);
        if (lane >= off) incl += t;
    }
    if (lane == 63) ws4[wv] = incl;
    __syncthreads();
    int add = 0;
    for (int w = 0; w < wv; ++w) add += ws4[w];
    return incl - v + add;
}

// ---------------- prep: weight splits + d1 + zero bucket_cnt ----------------

__global__ __launch_bounds__(256) void prep_kernel(
    const float* __restrict__ W1, const float* __restrict__ W2,
    const float* __restrict__ Ws1, const float* __restrict__ bs1,
    const float* __restrict__ donor,
    short* __restrict__ w1hi, short* __restrict__ w1lo,
    short* __restrict__ w2hi, short* __restrict__ w2lo,
    short* __restrict__ s1hi, short* __restrict__ s1lo,
    float* __restrict__ d1p, int* __restrict__ bucket_cnt)
{
    int t = blockIdx.x * 256 + threadIdx.x;
    int T = gridDim.x * 256;
    if (blockIdx.x == 0) bucket_cnt[threadIdx.x] = 0;
    for (int i = t; i < 256 * 40; i += T){                  // W1: [n=256][k pitch 40], K=27
        int n = i / 40, k = i % 40;
        float v = (k < 27) ? W1[(size_t)k * HC + n] : 0.f;
        short hi = bf16_rne(v);
        w1hi[i] = hi; w1lo[i] = bf16_rne(v - bf16_to_f(hi));
    }
    for (int i = t; i < 256 * 72; i += T){                  // W2: [n=256][k pitch 72], K=64
        int n = i / 72, k = i % 72;
        float v = (k < 64) ? W2[(size_t)k * HC + n] : 0.f;
        short hi = bf16_rne(v);
        w2hi[i] = hi; w2lo[i] = bf16_rne(v - bf16_to_f(hi));
    }
    for (int i = t; i < 64 * 72; i += T){                   // Ws1 h-part
        int n = i / 72, k = i % 72;
        float v = (k < 64) ? Ws1[(size_t)k * 64 + n] : 0.f;
        short hi = bf16_rne(v);
        s1hi[i] = hi; s1lo[i] = bf16_rne(v - bf16_to_f(hi));
    }
    if (t < 64){                                            // d1 = bs1 + donor @ Ws1[64:96]
        float s = bs1[t];
        for (int k = 0; k < 32; ++k) s = fmaf(donor[k], Ws1[(size_t)(64 + k) * 64 + t], s);
        d1p[t] = s;
    }
}

// ---------------- CSR build: two-level counting sort ----------------

// K2: scan bucket counts -> base/cursor; rowptr[N]=ET
__global__ __launch_bounds__(256) void bucket_scan_kernel(
    const int* __restrict__ bucket_cnt, int NB, int ET,
    int* __restrict__ bucket_base, int* __restrict__ bucket_cursor,
    int* __restrict__ rowptr, int N)
{
    __shared__ int ws4[4];
    int tid = threadIdx.x;
    int v = (tid < NB) ? bucket_cnt[tid] : 0;
    int excl = block_excl_scan(v, ws4);
    if (tid <= NB) bucket_base[tid] = excl;      // base[NB] == ET
    if (tid < NB)  bucket_cursor[tid] = excl;
    if (tid == 0)  rowptr[N] = ET;
}

// K3: coarse scatter of (dst,src) pairs into bucket regions
__global__ __launch_bounds__(256) void coarse_scatter_kernel(
    const int* __restrict__ ei, int E, int N, int NB,
    int* __restrict__ bucket_cursor, uint2* __restrict__ pairs)
{
    __shared__ int lh[256];
    __shared__ int gb[256];
    int tid = threadIdx.x;
    int ET = E + N;
    int ebase = blockIdx.x * 2048;
    lh[tid] = 0;
    __syncthreads();
    int d[8], s[8], r[8];
    #pragma unroll
    for (int j = 0; j < 8; ++j){
        int e = ebase + j * 256 + tid;
        d[j] = -1;
        if (e < ET){
            if (e < E){ s[j] = ei[e]; d[j] = ei[E + e]; } else { s[j] = d[j] = e - E; }
            r[j] = atomicAdd(&lh[d[j] >> 8], 1);
        }
    }
    __syncthreads();
    if (tid < NB) gb[tid] = atomicAdd(&bucket_cursor[tid], lh[tid]);
    __syncthreads();
    #pragma unroll
    for (int j = 0; j < 8; ++j){
        if (d[j] >= 0)
            pairs[gb[d[j] >> 8] + r[j]] = make_uint2((unsigned)d[j], (unsigned)s[j]);
    }
}

// K4: per-bucket fine counting sort -> colsrc + rowptr (block owns contiguous region)
__global__ __launch_bounds__(256) void fine_sort_kernel(
    const uint2* __restrict__ pairs, const int* __restrict__ bucket_base,
    int* __restrict__ colsrc, int* __restrict__ rowptr, int N)
{
    __shared__ int hist[256];
    __shared__ int cur[256];
    __shared__ int ws4[4];
    int tid = threadIdx.x;
    int b = blockIdx.x;
    int base = bucket_base[b], endb = bucket_base[b + 1];
    int cnt = endb - base;
    int d0 = b << 8;
    hist[tid] = 0;
    __syncthreads();
    for (int i = tid; i < cnt; i += 256){
        uint2 p = pairs[base + i];
        atomicAdd(&hist[p.x - d0], 1);
    }
    __syncthreads();
    int v = hist[tid];
    int excl = block_excl_scan(v, ws4);
    cur[tid] = excl;
    if (d0 + tid < N) rowptr[d0 + tid] = base + excl;
    __syncthreads();
    for (int i = tid; i < cnt; i += 256){
        uint2 p = pairs[base + i];
        int r = atomicAdd(&cur[p.x - d0], 1);
        colsrc[base + r] = (int)p.y;      // region is block-local -> L2-local writes
    }
}

// ---------------- MFMA node transform (device body) ----------------

template<int FIN, int KSTEPS, int NT>
__device__ __forceinline__ void transform_body(
    int bx, int by,
    const float* __restrict__ xin, const short* __restrict__ whi, const short* __restrict__ wlo,
    const float* __restrict__ a_src, const float* __restrict__ a_dst,
    __half* __restrict__ h, float* __restrict__ asrc, float* __restrict__ adst, int N)
{
    constexpr int KP = KSTEPS * 32;
    constexpr int XP = KP + 4;
    constexpr int WP = KP + 8;
    constexpr int NCOL = NT * 16;
    __shared__ float xl[64 * XP];
    __shared__ short wt_hi[NCOL * WP];
    __shared__ short wt_lo[NCOL * WP];

    const int tid = threadIdx.x;
    const int n0 = bx * 64;
    const int c0 = by * NCOL;

    if (FIN == 64) {
        for (int t = tid; t < 64 * 16; t += 256) {
            int row = t >> 4, c4 = (t & 15) * 4;
            int n = n0 + row;
            float4 v = make_float4(0.f, 0.f, 0.f, 0.f);
            if (n < N) v = *(const float4*)(xin + (size_t)n * 64 + c4);
            *(float4*)(xl + row * XP + c4) = v;
        }
    } else {
        for (int t = tid; t < 64 * KP; t += 256) {
            int row = t / KP, k = t % KP;
            int n = n0 + row;
            float v = 0.f;
            if (n < N && k < FIN) v = xin[(size_t)n * FIN + k];
            xl[row * XP + k] = v;
        }
    }
    {
        const short8* ghi = (const short8*)(whi + (size_t)c0 * WP);
        const short8* glo = (const short8*)(wlo + (size_t)c0 * WP);
        short8* lhi = (short8*)wt_hi;
        short8* llo = (short8*)wt_lo;
        for (int t = tid; t < NCOL * WP / 8; t += 256){
            lhi[t] = ghi[t];
            llo[t] = glo[t];
        }
    }
    __syncthreads();

    const int wv = tid >> 6, lane = tid & 63;
    const int quad = lane >> 4, ln = lane & 15;
    const int myrow = wv * 16 + ln;

    f32x4 acc[NT];
    #pragma unroll
    for (int i = 0; i < NT; ++i) acc[i] = (f32x4){0.f, 0.f, 0.f, 0.f};

    #pragma unroll
    for (int ks = 0; ks < KSTEPS; ++ks) {
        const int k0 = ks * 32 + quad * 8;
        const float* ap = xl + myrow * XP + k0;
        float4 f0 = *(const float4*)ap;
        float4 f1 = *(const float4*)(ap + 4);
        float fa[8] = {f0.x, f0.y, f0.z, f0.w, f1.x, f1.y, f1.z, f1.w};
        short8 ahi, alo;
        #pragma unroll
        for (int e = 0; e < 8; ++e) {
            short hi = bf16_rne(fa[e]);
            ahi[e] = hi;
            alo[e] = bf16_rne(fa[e] - bf16_to_f(hi));
        }
        #pragma unroll
        for (int nt = 0; nt < NT; ++nt) {
            short8 bhi = *(const short8*)(wt_hi + (nt * 16 + ln) * WP + k0);
            short8 blo = *(const short8*)(wt_lo + (nt * 16 + ln) * WP + k0);
            acc[nt] = __builtin_amdgcn_mfma_f32_16x16x32_bf16(ahi, bhi, acc[nt], 0, 0, 0);
            acc[nt] = __builtin_amdgcn_mfma_f32_16x16x32_bf16(alo, bhi, acc[nt], 0, 0, 0);
            acc[nt] = __builtin_amdgcn_mfma_f32_16x16x32_bf16(ahi, blo, acc[nt], 0, 0, 0);
        }
    }

    #pragma unroll
    for (int r = 0; r < 4; ++r) {
        int n = n0 + wv * 16 + quad * 4 + r;
        if (n < N) {
            if (NT == 16) {
                #pragma unroll
                for (int q = 0; q < 4; ++q) {
                    uint2 u;
                    u.x = packh2(acc[q][r],     acc[q + 4][r]);
                    u.y = packh2(acc[q + 8][r], acc[q + 12][r]);
                    *(uint2*)((char*)h + (size_t)n * 512 + (q * 16 + ln) * 8) = u;
                }
            } else {
                #pragma unroll
                for (int q = 0; q < 4; ++q) {
                    unsigned u = packh2(acc[q][r], acc[q + 4][r]);
                    *(unsigned*)((char*)h + (size_t)n * 512 + (q * 16 + ln) * 8 + ((c0 >> 6) << 1)) = u;
                }
            }
        }
    }

    float aS[NT], aD[NT];
    #pragma unroll
    for (int nt = 0; nt < NT; ++nt) {
        aS[nt] = a_src[c0 + nt * 16 + ln];
        aD[nt] = a_dst[c0 + nt * 16 + ln];
    }
    #pragma unroll
    for (int hl = 0; hl < NT / 4; ++hl) {
        #pragma unroll
        for (int r = 0; r < 4; ++r) {
            float ps = 0.f, pd = 0.f;
            #pragma unroll
            for (int i = 0; i < 4; ++i) {
                ps = fmaf(acc[hl * 4 + i][r], aS[hl * 4 + i], ps);
                pd = fmaf(acc[hl * 4 + i][r], aD[hl * 4 + i], pd);
            }
            #pragma unroll
            for (int off = 1; off < 16; off <<= 1) {
                ps += __shfl_xor(ps, off);
                pd += __shfl_xor(pd, off);
            }
            if (ln == 0) {
                int n = n0 + wv * 16 + quad * 4 + r;
                if (n < N) {
                    int hg = c0 / 64 + hl;
                    asrc[n * 4 + hg] = ps;
                    adst[n * 4 + hg] = pd;
                }
            }
        }
    }
}

// layer1 transform (NT=16) + K1 coarse-hist tail (resource-light: 1 KB LDS, few atomics)
__global__ __launch_bounds__(256) void transform1_hist_kernel(
    const float* __restrict__ xin, const short* __restrict__ whi, const short* __restrict__ wlo,
    const float* __restrict__ a_src, const float* __restrict__ a_dst,
    __half* __restrict__ h, float* __restrict__ asrc, float* __restrict__ adst, int N,
    int nblk, const int* __restrict__ ei, int E, int NB, int* __restrict__ bucket_cnt)
{
    if ((int)blockIdx.x < nblk) {
        transform_body<27, 1, 16>(blockIdx.x, 0, xin, whi, wlo, a_src, a_dst, h, asrc, adst, N);
    } else {
        __shared__ int lh[256];
        int tid = threadIdx.x;
        int ET = E + N;
        int ebase = (blockIdx.x - nblk) * 2048;
        lh[tid] = 0;
        __syncthreads();
        #pragma unroll
        for (int j = 0; j < 8; ++j){
            int e = ebase + j * 256 + tid;
            if (e < ET){
                int d = (e < E) ? ei[E + e] : (e - E);
                atomicAdd(&lh[d >> 8], 1);
            }
        }
        __syncthreads();
        if (tid < NB) atomicAdd(&bucket_cnt[tid], lh[tid]);
    }
}

__global__ __launch_bounds__(256) void transform2_kernel(
    const float* __restrict__ xin, const short* __restrict__ whi, const short* __restrict__ wlo,
    const float* __restrict__ a_src, const float* __restrict__ a_dst,
    __half* __restrict__ h, float* __restrict__ asrc, float* __restrict__ adst, int N)
{
    transform_body<64, 2, 8>(blockIdx.x, blockIdx.y, xin, whi, wlo, a_src, a_dst, h, asrc, adst, N);
}

// ---------------- per-dst aggregation (unchanged from R9) ----------------

__device__ __forceinline__ void edge_sweep(
    const int* __restrict__ soff, const uint2* __restrict__ sw,
    const __half* __restrict__ h, int boff, int cnt,
    float& accA, float& accB, float& accC, float& accD)
{
    int cnt4 = (cnt + 3) & ~3;
    for (int j = 0; j < cnt4; j += 4){
        int offA = __builtin_amdgcn_readfirstlane(soff[j]);
        int offB = __builtin_amdgcn_readfirstlane(soff[j + 1]);
        int offC = __builtin_amdgcn_readfirstlane(soff[j + 2]);
        int offD = __builtin_amdgcn_readfirstlane(soff[j + 3]);
        uint4 w01 = *(const uint4*)(sw + j);
        uint4 w23 = *(const uint4*)(sw + j + 2);
        uint2 ha = *(const uint2*)((const char*)h + offA + boff);
        uint2 hb = *(const uint2*)((const char*)h + offB + boff);
        uint2 hc = *(const uint2*)((const char*)h + offC + boff);
        uint2 hd = *(const uint2*)((const char*)h + offD + boff);
        accA = __builtin_amdgcn_fdot2(bc16(ha.x), bc16(w01.x), accA, false);
        accA = __builtin_amdgcn_fdot2(bc16(ha.y), bc16(w01.y), accA, false);
        accB = __builtin_amdgcn_fdot2(bc16(hb.x), bc16(w01.z), accB, false);
        accB = __builtin_amdgcn_fdot2(bc16(hb.y), bc16(w01.w), accB, false);
        accC = __builtin_amdgcn_fdot2(bc16(hc.x), bc16(w23.x), accC, false);
        accC = __builtin_amdgcn_fdot2(bc16(hc.y), bc16(w23.y), accC, false);
        accD = __builtin_amdgcn_fdot2(bc16(hd.x), bc16(w23.z), accD, false);
        accD = __builtin_amdgcn_fdot2(bc16(hd.y), bc16(w23.w), accD, false);
    }
}

__global__ __launch_bounds__(256) void aggregate_kernel(
    const int* __restrict__ rowptr, const int* __restrict__ colsrc,
    const __half* __restrict__ h, const float* __restrict__ asrc,
    const float* __restrict__ adst, const float* __restrict__ bias,
    float* __restrict__ hout, int N)
{
    __shared__ int   s_off[4][64];
    __shared__ uint2 s_w[4][64];
    int tid = threadIdx.x;
    int wv = tid >> 6, lane = tid & 63;
    int n = blockIdx.x * 4 + wv;
    if (n >= N) return;
    int start = rowptr[n], end = rowptr[n + 1];
    int deg = end - start;
    const float4 ad = *(const float4*)(adst + (size_t)n * 4);

    int src0 = 0;
    float e0 = -1e30f, e1 = -1e30f, e2 = -1e30f, e3 = -1e30f;
    bool v0 = lane < deg;
    if (v0){
        src0 = colsrc[start + lane];
        float4 as = *(const float4*)(asrc + (size_t)src0 * 4);
        e0 = leaky(as.x + ad.x); e1 = leaky(as.y + ad.y);
        e2 = leaky(as.z + ad.z); e3 = leaky(as.w + ad.w);
    }

    float m0, m1, m2, m3, i0, i1, i2, i3, p0, p1, p2, p3;
    if (deg <= 64){
        m0 = e0; m1 = e1; m2 = e2; m3 = e3;
        #pragma unroll
        for (int off = 1; off < 64; off <<= 1){
            m0 = fmaxf(m0, __shfl_xor(m0, off));
            m1 = fmaxf(m1, __shfl_xor(m1, off));
            m2 = fmaxf(m2, __shfl_xor(m2, off));
            m3 = fmaxf(m3, __shfl_xor(m3, off));
        }
        p0 = __expf(e0 - m0);
        p1 = __expf(e1 - m1);
        p2 = __expf(e2 - m2);
        p3 = __expf(e3 - m3);
        float t0 = p0, t1 = p1, t2 = p2, t3 = p3;
        #pragma unroll
        for (int off = 1; off < 64; off <<= 1){
            t0 += __shfl_xor(t0, off);
            t1 += __shfl_xor(t1, off);
            t2 += __shfl_xor(t2, off);
            t3 += __shfl_xor(t3, off);
        }
        i0 = 1.f / t0; i1 = 1.f / t1; i2 = 1.f / t2; i3 = 1.f / t3;
    } else {
        m0 = e0; m1 = e1; m2 = e2; m3 = e3;
        float t0 = v0 ? 1.f : 0.f, t1 = t0, t2 = t0, t3 = t0;
        for (int i = start + 64 + lane; i < end; i += 64){
            int s = colsrc[i];
            float4 as = *(const float4*)(asrc + (size_t)s * 4);
            float e, nm;
            e = leaky(as.x + ad.x); nm = fmaxf(m0, e); t0 = t0 * __expf(m0 - nm) + __expf(e - nm); m0 = nm;
            e = leaky(as.y + ad.y); nm = fmaxf(m1, e); t1 = t1 * __expf(m1 - nm) + __expf(e - nm); m1 = nm;
            e = leaky(as.z + ad.z); nm = fmaxf(m2, e); t2 = t2 * __expf(m2 - nm) + __expf(e - nm); m2 = nm;
            e = leaky(as.w + ad.w); nm = fmaxf(m3, e); t3 = t3 * __expf(m3 - nm) + __expf(e - nm); m3 = nm;
        }
        #pragma unroll
        for (int off = 1; off < 64; off <<= 1){
            float om, os, nm;
            om = __shfl_xor(m0, off); os = __shfl_xor(t0, off);
            nm = fmaxf(m0, om); t0 = t0 * __expf(m0 - nm) + os * __expf(om - nm); m0 = nm;
            om = __shfl_xor(m1, off); os = __shfl_xor(t1, off);
            nm = fmaxf(m1, om); t1 = t1 * __expf(m1 - nm) + os * __expf(om - nm); m1 = nm;
            om = __shfl_xor(m2, off); os = __shfl_xor(t2, off);
            nm = fmaxf(m2, om); t2 = t2 * __expf(m2 - nm) + os * __expf(om - nm); m2 = nm;
            om = __shfl_xor(m3, off); os = __shfl_xor(t3, off);
            nm = fmaxf(m3, om); t3 = t3 * __expf(m3 - nm) + os * __expf(om - nm); m3 = nm;
        }
        i0 = 1.f / t0; i1 = 1.f / t1; i2 = 1.f / t2; i3 = 1.f / t3;
        p0 = __expf(e0 - m0); p1 = __expf(e1 - m1);
        p2 = __expf(e2 - m2); p3 = __expf(e3 - m3);
    }

    float accA = 0.f, accB = 0.f, accC = 0.f, accD = 0.f;
    const int boff = lane * 8;
    {
        int off = v0 ? src0 * (HC * 2) : 0;
        s_off[wv][lane] = off;
        half2_t p01 = __builtin_amdgcn_cvt_pkrtz(p0 * i0, p1 * i1);
        half2_t p23 = __builtin_amdgcn_cvt_pkrtz(p2 * i2, p3 * i3);
        s_w[wv][lane] = (uint2){ __builtin_bit_cast(unsigned, p01),
                                 __builtin_bit_cast(unsigned, p23) };
        int cnt = deg < 64 ? deg : 64;
        edge_sweep(&s_off[wv][0], &s_w[wv][0], h, boff, cnt, accA, accB, accC, accD);
    }
    for (int base = start + 64; base < end; base += 64){
        int cnt = end - base; if (cnt > 64) cnt = 64;
        float w0 = 0.f, w1 = 0.f, w2 = 0.f, w3 = 0.f; int off = 0;
        if (lane < cnt){
            int s = colsrc[base + lane];
            float4 as = *(const float4*)(asrc + (size_t)s * 4);
            w0 = __expf(leaky(as.x + ad.x) - m0) * i0;
            w1 = __expf(leaky(as.y + ad.y) - m1) * i1;
            w2 = __expf(leaky(as.z + ad.z) - m2) * i2;
            w3 = __expf(leaky(as.w + ad.w) - m3) * i3;
            off = s * (HC * 2);
        }
        s_off[wv][lane] = off;
        half2_t p01 = __builtin_amdgcn_cvt_pkrtz(w0, w1);
        half2_t p23 = __builtin_amdgcn_cvt_pkrtz(w2, w3);
        s_w[wv][lane] = (uint2){ __builtin_bit_cast(unsigned, p01),
                                 __builtin_bit_cast(unsigned, p23) };
        edge_sweep(&s_off[wv][0], &s_w[wv][0], h, boff, cnt, accA, accB, accC, accD);
    }

    float o = (accA + accB + accC + accD) * 0.25f + bias[lane];
    hout[(size_t)n * CH + lane] = (o > 0.f) ? o : expm1f(o);
}

// ---------------- scorer: MFMA (bf16x3) for hmid@Ws1, fp32 epilogue ----------------

__global__ __launch_bounds__(256) void scorer_mfma_kernel(
    const float* __restrict__ h2, const short* __restrict__ s1hi, const short* __restrict__ s1lo,
    const float* __restrict__ d1p, const float* __restrict__ Ws2, const float* __restrict__ bs2,
    float* __restrict__ out, int N)
{
    constexpr int XP = 68, WP = 72;
    __shared__ float xl[64 * XP];
    __shared__ short whi[64 * WP];
    __shared__ short wlo[64 * WP];
    const int tid = threadIdx.x;
    const int n0 = blockIdx.x * 64;

    for (int t = tid; t < 64 * 16; t += 256) {
        int row = t >> 4, c4 = (t & 15) * 4;
        int n = n0 + row;
        float4 v = make_float4(0.f, 0.f, 0.f, 0.f);
        if (n < N) v = *(const float4*)(h2 + (size_t)n * 64 + c4);
        *(float4*)(xl + row * XP + c4) = v;
    }
    {
        const short8* ghi = (const short8*)s1hi;
        const short8* glo = (const short8*)s1lo;
        short8* lhi = (short8*)whi;
        short8* llo = (short8*)wlo;
        for (int t = tid; t < 64 * WP / 8; t += 256){ lhi[t] = ghi[t]; llo[t] = glo[t]; }
    }
    __syncthreads();

    const int wv = tid >> 6, lane = tid & 63;
    const int quad = lane >> 4, ln = lane & 15;
    const int myrow = wv * 16 + ln;

    f32x4 acc[4];
    #pragma unroll
    for (int i = 0; i < 4; ++i) acc[i] = (f32x4){0.f, 0.f, 0.f, 0.f};

    #pragma unroll
    for (int ks = 0; ks < 2; ++ks) {
        const int k0 = ks * 32 + quad * 8;
        const float* ap = xl + myrow * XP + k0;
        float4 f0 = *(const float4*)ap;
        float4 f1 = *(const float4*)(ap + 4);
        float fa[8] = {f0.x, f0.y, f0.z, f0.w, f1.x, f1.y, f1.z, f1.w};
        short8 ahi, alo;
        #pragma unroll
        for (int e = 0; e < 8; ++e) {
            short hi = bf16_rne(fa[e]);
            ahi[e] = hi;
            alo[e] = bf16_rne(fa[e] - bf16_to_f(hi));
        }
        #pragma unroll
        for (int nt = 0; nt < 4; ++nt) {
            short8 bhi = *(const short8*)(whi + (nt * 16 + ln) * WP + k0);
            short8 blo = *(const short8*)(wlo + (nt * 16 + ln) * WP + k0);
            acc[nt] = __builtin_amdgcn_mfma_f32_16x16x32_bf16(ahi, bhi, acc[nt], 0, 0, 0);
            acc[nt] = __builtin_amdgcn_mfma_f32_16x16x32_bf16(alo, bhi, acc[nt], 0, 0, 0);
            acc[nt] = __builtin_amdgcn_mfma_f32_16x16x32_bf16(ahi, blo, acc[nt], 0, 0, 0);
        }
    }

    float d1v[4], w2v[4];
    #pragma unroll
    for (int nt = 0; nt < 4; ++nt){
        d1v[nt] = d1p[nt * 16 + ln];
        w2v[nt] = Ws2[nt * 16 + ln];
    }
    float b2 = bs2[0];
    #pragma unroll
    for (int r = 0; r < 4; ++r){
        float t = 0.f;
        #pragma unroll
        for (int nt = 0; nt < 4; ++nt)
            t = fmaf(fmaxf(acc[nt][r] + d1v[nt], 0.f), w2v[nt], t);
        #pragma unroll
        for (int off = 1; off < 16; off <<= 1) t += __shfl_xor(t, off);
        if (ln == 0){
            int n = n0 + wv * 16 + quad * 4 + r;
            if (n < N) out[n] = t + b2;
        }
    }
}

// ---------------- launch ----------------

extern "C" void kernel_launch(void* const* d_in, const int* in_sizes, int n_in,
                              void* d_out, int out_size, void* d_ws, size_t ws_size,
                              hipStream_t stream)
{
    const float* x    = (const float*)d_in[0];
    const int*   ei   = (const int*)  d_in[1];
    const float* donor= (const float*)d_in[2];
    const float* W1   = (const float*)d_in[3];
    const float* as1  = (const float*)d_in[4];
    const float* ad1  = (const float*)d_in[5];
    const float* b1   = (const float*)d_in[6];
    const float* W2   = (const float*)d_in[7];
    const float* as2  = (const float*)d_in[8];
    const float* ad2  = (const float*)d_in[9];
    const float* b2   = (const float*)d_in[10];
    const float* Ws1  = (const float*)d_in[11];
    const float* bs1  = (const float*)d_in[12];
    const float* Ws2  = (const float*)d_in[13];
    const float* bs2  = (const float*)d_in[14];

    const int N  = in_sizes[0] / 27;
    const int E  = in_sizes[1] / 2;
    const int ET = E + N;
    const int NB = (N + 255) / 256;            // coarse buckets (<=256)

    char* ws = (char*)d_ws;
    auto alloc = [&](size_t bytes) -> void* {
        void* p = (void*)ws;
        ws += (bytes + 255) / 256 * 256;
        return p;
    };
    int*    rowptr  = (int*)   alloc((size_t)(N + 1) * 4);
    int*    colsrc  = (int*)   alloc((size_t)ET * 4);
    uint2*  pairs   = (uint2*) alloc((size_t)ET * 8);
    __half* hbig    = (__half*)alloc((size_t)N * HC * 2);
    float*  asrc    = (float*) alloc((size_t)N * 4 * 4);
    float*  adst    = (float*) alloc((size_t)N * 4 * 4);
    float*  hmid    = (float*) alloc((size_t)N * CH * 4);
    int*    bucket_cnt    = (int*) alloc(256 * 4);
    int*    bucket_base   = (int*) alloc(257 * 4);
    int*    bucket_cursor = (int*) alloc(256 * 4);
    short*  w1hi    = (short*) alloc(256 * 40 * 2);
    short*  w1lo    = (short*) alloc(256 * 40 * 2);
    short*  w2hi    = (short*) alloc(256 * 72 * 2);
    short*  w2lo    = (short*) alloc(256 * 72 * 2);
    short*  s1hi    = (short*) alloc(64 * 72 * 2);
    short*  s1lo    = (short*) alloc(64 * 72 * 2);
    float*  d1p     = (float*) alloc(64 * 4);

    const int nblk = (N + 63) / 64;
    const int hblk = (ET + 2047) / 2048;       // hist/scatter chunks

    // 1. prep: weight splits, d1, zero bucket_cnt
    prep_kernel<<<256, 256, 0, stream>>>(W1, W2, Ws1, bs1, donor,
        w1hi, w1lo, w2hi, w2lo, s1hi, s1lo, d1p, bucket_cnt);
    // 2. layer1 transform + coarse histogram
    transform1_hist_kernel<<<nblk + hblk, 256, 0, stream>>>(
        x, w1hi, w1lo, as1, ad1, hbig, asrc, adst, N, nblk, ei, E, NB, bucket_cnt);
    // 3. bucket scan
    bucket_scan_kernel<<<1, 256, 0, stream>>>(bucket_cnt, NB, ET, bucket_base, bucket_cursor, rowptr, N);
    // 4. coarse scatter -> pairs
    coarse_scatter_kernel<<<hblk, 256, 0, stream>>>(ei, E, N, NB, bucket_cursor, pairs);
    // 5. fine sort -> colsrc + rowptr
    fine_sort_kernel<<<NB, 256, 0, stream>>>(pairs, bucket_base, colsrc, rowptr, N);
    // 6. aggregate layer1
    aggregate_kernel<<<(N + 3) / 4, 256, 0, stream>>>(
        rowptr, colsrc, hbig, asrc, adst, b1, hmid, N);
    // 7. layer2 transform
    transform2_kernel<<<dim3(nblk, 2), 256, 0, stream>>>(
        hmid, w2hi, w2lo, as2, ad2, hbig, asrc, adst, N);
    // 8. aggregate layer2
    aggregate_kernel<<<(N + 3) / 4, 256, 0, stream>>>(
        rowptr, colsrc, hbig, asrc, adst, b2, hmid, N);
    // 9. scorer
    scorer_mfma_kernel<<<nblk, 256, 0, stream>>>(
        hmid, s1hi, s1lo, d1p, Ws2, bs2, (float*)d_out, N);
}

// Round 11
// 307.191 us; speedup vs baseline: 1.2665x; 1.0032x over previous
//
#include <hip/hip_runtime.h>
#include <hip/hip_fp16.h>
#include <cmath>

#define HEADS 4
#define CH 64
#define HC 256
#define NEG 0.2f

typedef __attribute__((ext_vector_type(8))) short short8;
typedef __attribute__((ext_vector_type(4))) float f32x4;
typedef __fp16 half2_t __attribute__((ext_vector_type(2)));

__device__ __forceinline__ float leaky(float v){ return v > 0.f ? v : NEG * v; }

__device__ __forceinline__ short bf16_rne(float f){
    unsigned u = __float_as_uint(f);
    unsigned r = u + 0x7fffu + ((u >> 16) & 1u);
    return (short)(r >> 16);
}
__device__ __forceinline__ float bf16_to_f(short s){
    return __uint_as_float(((unsigned)(unsigned short)s) << 16);
}
__device__ __forceinline__ half2_t bc16(unsigned u){ return __builtin_bit_cast(half2_t, u); }
__device__ __forceinline__ unsigned packh2(float a, float b){
    __half ha = __float2half(a), hb = __float2half(b);   // RNE
    return (unsigned)__builtin_bit_cast(unsigned short, ha)
         | ((unsigned)__builtin_bit_cast(unsigned short, hb) << 16);
}

// block-wide exclusive scan of one int per thread (256 threads)
__device__ __forceinline__ int block_excl_scan(int v, int* ws4){
    int tid = threadIdx.x, lane = tid & 63, wv = tid >> 6;
    int incl = v;
    #pragma unroll
    for (int off = 1; off < 64; off <<= 1){
        int t = __shfl_up(incl, off);
        if (lane >= off) incl += t;
    }
    if (lane == 63) ws4[wv] = incl;
    __syncthreads();
    int add = 0;
    for (int w = 0; w < wv; ++w) add += ws4[w];
    return incl - v + add;
}

// ---------------- prep: weight splits + d1 + zero bucket_cnt ----------------

__global__ __launch_bounds__(256) void prep_kernel(
    const float* __restrict__ W1, const float* __restrict__ W2,
    const float* __restrict__ Ws1, const float* __restrict__ bs1,
    const float* __restrict__ donor,
    short* __restrict__ w1hi, short* __restrict__ w1lo,
    short* __restrict__ w2hi, short* __restrict__ w2lo,
    short* __restrict__ s1hi, short* __restrict__ s1lo,
    float* __restrict__ d1p, int* __restrict__ bucket_cnt)
{
    int t = blockIdx.x * 256 + threadIdx.x;
    int T = gridDim.x * 256;
    if (blockIdx.x == 0) bucket_cnt[threadIdx.x] = 0;
    for (int i = t; i < 256 * 40; i += T){
        int n = i / 40, k = i % 40;
        float v = (k < 27) ? W1[(size_t)k * HC + n] : 0.f;
        short hi = bf16_rne(v);
        w1hi[i] = hi; w1lo[i] = bf16_rne(v - bf16_to_f(hi));
    }
    for (int i = t; i < 256 * 72; i += T){
        int n = i / 72, k = i % 72;
        float v = (k < 64) ? W2[(size_t)k * HC + n] : 0.f;
        short hi = bf16_rne(v);
        w2hi[i] = hi; w2lo[i] = bf16_rne(v - bf16_to_f(hi));
    }
    for (int i = t; i < 64 * 72; i += T){
        int n = i / 72, k = i % 72;
        float v = (k < 64) ? Ws1[(size_t)k * 64 + n] : 0.f;
        short hi = bf16_rne(v);
        s1hi[i] = hi; s1lo[i] = bf16_rne(v - bf16_to_f(hi));
    }
    if (t < 64){
        float s = bs1[t];
        for (int k = 0; k < 32; ++k) s = fmaf(donor[k], Ws1[(size_t)(64 + k) * 64 + t], s);
        d1p[t] = s;
    }
}

// ---------------- CSR build: two-level counting sort ----------------

__global__ __launch_bounds__(256) void bucket_scan_kernel(
    const int* __restrict__ bucket_cnt, int NB, int ET,
    int* __restrict__ bucket_base, int* __restrict__ bucket_cursor,
    int* __restrict__ rowptr, int N)
{
    __shared__ int ws4[4];
    int tid = threadIdx.x;
    int v = (tid < NB) ? bucket_cnt[tid] : 0;
    int excl = block_excl_scan(v, ws4);
    if (tid <= NB) bucket_base[tid] = excl;
    if (tid < NB)  bucket_cursor[tid] = excl;
    if (tid == 0)  rowptr[N] = ET;
}

__global__ __launch_bounds__(256) void coarse_scatter_kernel(
    const int* __restrict__ ei, int E, int N, int NB,
    int* __restrict__ bucket_cursor, uint2* __restrict__ pairs)
{
    __shared__ int lh[256];
    __shared__ int gb[256];
    int tid = threadIdx.x;
    int ET = E + N;
    int ebase = blockIdx.x * 2048;
    lh[tid] = 0;
    __syncthreads();
    int d[8], s[8], r[8];
    #pragma unroll
    for (int j = 0; j < 8; ++j){
        int e = ebase + j * 256 + tid;
        d[j] = -1;
        if (e < ET){
            if (e < E){ s[j] = ei[e]; d[j] = ei[E + e]; } else { s[j] = d[j] = e - E; }
            r[j] = atomicAdd(&lh[d[j] >> 8], 1);
        }
    }
    __syncthreads();
    if (tid < NB) gb[tid] = atomicAdd(&bucket_cursor[tid], lh[tid]);
    __syncthreads();
    #pragma unroll
    for (int j = 0; j < 8; ++j){
        if (d[j] >= 0)
            pairs[gb[d[j] >> 8] + r[j]] = make_uint2((unsigned)d[j], (unsigned)s[j]);
    }
}

__global__ __launch_bounds__(256) void fine_sort_kernel(
    const uint2* __restrict__ pairs, const int* __restrict__ bucket_base,
    int* __restrict__ colsrc, int* __restrict__ rowptr, int N)
{
    __shared__ int hist[256];
    __shared__ int cur[256];
    __shared__ int ws4[4];
    int tid = threadIdx.x;
    int b = blockIdx.x;
    int base = bucket_base[b], endb = bucket_base[b + 1];
    int cnt = endb - base;
    int d0 = b << 8;
    hist[tid] = 0;
    __syncthreads();
    for (int i = tid; i < cnt; i += 256){
        uint2 p = pairs[base + i];
        atomicAdd(&hist[p.x - d0], 1);
    }
    __syncthreads();
    int v = hist[tid];
    int excl = block_excl_scan(v, ws4);
    cur[tid] = excl;
    if (d0 + tid < N) rowptr[d0 + tid] = base + excl;
    __syncthreads();
    for (int i = tid; i < cnt; i += 256){
        uint2 p = pairs[base + i];
        int r = atomicAdd(&cur[p.x - d0], 1);
        colsrc[base + r] = (int)p.y;
    }
}

// ---------------- MFMA node transform (device body) ----------------

template<int FIN, int KSTEPS, int NT>
__device__ __forceinline__ void transform_body(
    int bx, int by,
    const float* __restrict__ xin, const short* __restrict__ whi, const short* __restrict__ wlo,
    const float* __restrict__ a_src, const float* __restrict__ a_dst,
    __half* __restrict__ h, float* __restrict__ asrc, float* __restrict__ adst, int N)
{
    constexpr int KP = KSTEPS * 32;
    constexpr int XP = KP + 4;
    constexpr int WP = KP + 8;
    constexpr int NCOL = NT * 16;
    __shared__ float xl[64 * XP];
    __shared__ short wt_hi[NCOL * WP];
    __shared__ short wt_lo[NCOL * WP];

    const int tid = threadIdx.x;
    const int n0 = bx * 64;
    const int c0 = by * NCOL;

    if (FIN == 64) {
        for (int t = tid; t < 64 * 16; t += 256) {
            int row = t >> 4, c4 = (t & 15) * 4;
            int n = n0 + row;
            float4 v = make_float4(0.f, 0.f, 0.f, 0.f);
            if (n < N) v = *(const float4*)(xin + (size_t)n * 64 + c4);
            *(float4*)(xl + row * XP + c4) = v;
        }
    } else {
        for (int t = tid; t < 64 * KP; t += 256) {
            int row = t / KP, k = t % KP;
            int n = n0 + row;
            float v = 0.f;
            if (n < N && k < FIN) v = xin[(size_t)n * FIN + k];
            xl[row * XP + k] = v;
        }
    }
    {
        const short8* ghi = (const short8*)(whi + (size_t)c0 * WP);
        const short8* glo = (const short8*)(wlo + (size_t)c0 * WP);
        short8* lhi = (short8*)wt_hi;
        short8* llo = (short8*)wt_lo;
        for (int t = tid; t < NCOL * WP / 8; t += 256){
            lhi[t] = ghi[t];
            llo[t] = glo[t];
        }
    }
    __syncthreads();

    const int wv = tid >> 6, lane = tid & 63;
    const int quad = lane >> 4, ln = lane & 15;
    const int myrow = wv * 16 + ln;

    f32x4 acc[NT];
    #pragma unroll
    for (int i = 0; i < NT; ++i) acc[i] = (f32x4){0.f, 0.f, 0.f, 0.f};

    #pragma unroll
    for (int ks = 0; ks < KSTEPS; ++ks) {
        const int k0 = ks * 32 + quad * 8;
        const float* ap = xl + myrow * XP + k0;
        float4 f0 = *(const float4*)ap;
        float4 f1 = *(const float4*)(ap + 4);
        float fa[8] = {f0.x, f0.y, f0.z, f0.w, f1.x, f1.y, f1.z, f1.w};
        short8 ahi, alo;
        #pragma unroll
        for (int e = 0; e < 8; ++e) {
            short hi = bf16_rne(fa[e]);
            ahi[e] = hi;
            alo[e] = bf16_rne(fa[e] - bf16_to_f(hi));
        }
        #pragma unroll
        for (int nt = 0; nt < NT; ++nt) {
            short8 bhi = *(const short8*)(wt_hi + (nt * 16 + ln) * WP + k0);
            short8 blo = *(const short8*)(wt_lo + (nt * 16 + ln) * WP + k0);
            acc[nt] = __builtin_amdgcn_mfma_f32_16x16x32_bf16(ahi, bhi, acc[nt], 0, 0, 0);
            acc[nt] = __builtin_amdgcn_mfma_f32_16x16x32_bf16(alo, bhi, acc[nt], 0, 0, 0);
            acc[nt] = __builtin_amdgcn_mfma_f32_16x16x32_bf16(ahi, blo, acc[nt], 0, 0, 0);
        }
    }

    #pragma unroll
    for (int r = 0; r < 4; ++r) {
        int n = n0 + wv * 16 + quad * 4 + r;
        if (n < N) {
            if (NT == 16) {
                #pragma unroll
                for (int q = 0; q < 4; ++q) {
                    uint2 u;
                    u.x = packh2(acc[q][r],     acc[q + 4][r]);
                    u.y = packh2(acc[q + 8][r], acc[q + 12][r]);
                    *(uint2*)((char*)h + (size_t)n * 512 + (q * 16 + ln) * 8) = u;
                }
            } else {
                #pragma unroll
                for (int q = 0; q < 4; ++q) {
                    unsigned u = packh2(acc[q][r], acc[q + 4][r]);
                    *(unsigned*)((char*)h + (size_t)n * 512 + (q * 16 + ln) * 8 + ((c0 >> 6) << 1)) = u;
                }
            }
        }
    }

    float aS[NT], aD[NT];
    #pragma unroll
    for (int nt = 0; nt < NT; ++nt) {
        aS[nt] = a_src[c0 + nt * 16 + ln];
        aD[nt] = a_dst[c0 + nt * 16 + ln];
    }
    #pragma unroll
    for (int hl = 0; hl < NT / 4; ++hl) {
        #pragma unroll
        for (int r = 0; r < 4; ++r) {
            float ps = 0.f, pd = 0.f;
            #pragma unroll
            for (int i = 0; i < 4; ++i) {
                ps = fmaf(acc[hl * 4 + i][r], aS[hl * 4 + i], ps);
                pd = fmaf(acc[hl * 4 + i][r], aD[hl * 4 + i], pd);
            }
            #pragma unroll
            for (int off = 1; off < 16; off <<= 1) {
                ps += __shfl_xor(ps, off);
                pd += __shfl_xor(pd, off);
            }
            if (ln == 0) {
                int n = n0 + wv * 16 + quad * 4 + r;
                if (n < N) {
                    int hg = c0 / 64 + hl;
                    asrc[n * 4 + hg] = ps;
                    adst[n * 4 + hg] = pd;
                }
            }
        }
    }
}

__global__ __launch_bounds__(256) void transform1_hist_kernel(
    const float* __restrict__ xin, const short* __restrict__ whi, const short* __restrict__ wlo,
    const float* __restrict__ a_src, const float* __restrict__ a_dst,
    __half* __restrict__ h, float* __restrict__ asrc, float* __restrict__ adst, int N,
    int nblk, const int* __restrict__ ei, int E, int NB, int* __restrict__ bucket_cnt)
{
    if ((int)blockIdx.x < nblk) {
        transform_body<27, 1, 16>(blockIdx.x, 0, xin, whi, wlo, a_src, a_dst, h, asrc, adst, N);
    } else {
        __shared__ int lh[256];
        int tid = threadIdx.x;
        int ET = E + N;
        int ebase = (blockIdx.x - nblk) * 2048;
        lh[tid] = 0;
        __syncthreads();
        #pragma unroll
        for (int j = 0; j < 8; ++j){
            int e = ebase + j * 256 + tid;
            if (e < ET){
                int d = (e < E) ? ei[E + e] : (e - E);
                atomicAdd(&lh[d >> 8], 1);
            }
        }
        __syncthreads();
        if (tid < NB) atomicAdd(&bucket_cnt[tid], lh[tid]);
    }
}

__global__ __launch_bounds__(256) void transform2_kernel(
    const float* __restrict__ xin, const short* __restrict__ whi, const short* __restrict__ wlo,
    const float* __restrict__ a_src, const float* __restrict__ a_dst,
    __half* __restrict__ h, float* __restrict__ asrc, float* __restrict__ adst, int N)
{
    transform_body<64, 2, 8>(blockIdx.x, blockIdx.y, xin, whi, wlo, a_src, a_dst, h, asrc, adst, N);
}

// ---------------- per-dst aggregation: 2 nodes per wave (32 lanes each) ----------------
// lane32 = channel pair (16 B of the 512 B h row). Butterflies are 5-step within
// 32-lane halves (xor masks <32 never cross the half boundary). Fast path deg<=32
// (P(deg>32) ~ 2e-4): one exp per lane per head. Slow path: chunked online softmax.

__global__ __launch_bounds__(256) void aggregate_kernel(
    const int* __restrict__ rowptr, const int* __restrict__ colsrc,
    const __half* __restrict__ h, const float* __restrict__ asrc,
    const float* __restrict__ adst, const float* __restrict__ bias,
    float* __restrict__ hout, int N)
{
    __shared__ int      s_off[8][32];
    __shared__ uint2    s_w[8][32];
    int tid = threadIdx.x;
    int grp = tid >> 5;            // 0..7 half-wave group in block
    int lane32 = tid & 31;
    int n = blockIdx.x * 8 + grp;
    if (n >= N) return;
    int start = rowptr[n], end = rowptr[n + 1];
    int deg = end - start;
    const float4 ad = *(const float4*)(adst + (size_t)n * 4);

    int src0 = 0;
    float e0 = -1e30f, e1 = -1e30f, e2 = -1e30f, e3 = -1e30f;
    bool v0 = lane32 < deg;
    if (v0){
        src0 = colsrc[start + lane32];
        float4 as = *(const float4*)(asrc + (size_t)src0 * 4);
        e0 = leaky(as.x + ad.x); e1 = leaky(as.y + ad.y);
        e2 = leaky(as.z + ad.z); e3 = leaky(as.w + ad.w);
    }

    float m0, m1, m2, m3, i0, i1, i2, i3, p0, p1, p2, p3;
    if (deg <= 32){
        m0 = e0; m1 = e1; m2 = e2; m3 = e3;
        #pragma unroll
        for (int off = 1; off < 32; off <<= 1){
            m0 = fmaxf(m0, __shfl_xor(m0, off));
            m1 = fmaxf(m1, __shfl_xor(m1, off));
            m2 = fmaxf(m2, __shfl_xor(m2, off));
            m3 = fmaxf(m3, __shfl_xor(m3, off));
        }
        p0 = __expf(e0 - m0);   // 0 for invalid lanes (underflow)
        p1 = __expf(e1 - m1);
        p2 = __expf(e2 - m2);
        p3 = __expf(e3 - m3);
        float t0 = p0, t1 = p1, t2 = p2, t3 = p3;
        #pragma unroll
        for (int off = 1; off < 32; off <<= 1){
            t0 += __shfl_xor(t0, off);
            t1 += __shfl_xor(t1, off);
            t2 += __shfl_xor(t2, off);
            t3 += __shfl_xor(t3, off);
        }
        i0 = 1.f / t0; i1 = 1.f / t1; i2 = 1.f / t2; i3 = 1.f / t3;
    } else {
        // slow path (deg>32, ~10 nodes of 50K): per-lane online over chunks, then merge
        m0 = e0; m1 = e1; m2 = e2; m3 = e3;
        float t0 = v0 ? 1.f : 0.f, t1 = t0, t2 = t0, t3 = t0;
        for (int i = start + 32 + lane32; i < end; i += 32){
            int s = colsrc[i];
            float4 as = *(const float4*)(asrc + (size_t)s * 4);
            float e, nm;
            e = leaky(as.x + ad.x); nm = fmaxf(m0, e); t0 = t0 * __expf(m0 - nm) + __expf(e - nm); m0 = nm;
            e = leaky(as.y + ad.y); nm = fmaxf(m1, e); t1 = t1 * __expf(m1 - nm) + __expf(e - nm); m1 = nm;
            e = leaky(as.z + ad.z); nm = fmaxf(m2, e); t2 = t2 * __expf(m2 - nm) + __expf(e - nm); m2 = nm;
            e = leaky(as.w + ad.w); nm = fmaxf(m3, e); t3 = t3 * __expf(m3 - nm) + __expf(e - nm); m3 = nm;
        }
        #pragma unroll
        for (int off = 1; off < 32; off <<= 1){
            float om, os, nm;
            om = __shfl_xor(m0, off); os = __shfl_xor(t0, off);
            nm = fmaxf(m0, om); t0 = t0 * __expf(m0 - nm) + os * __expf(om - nm); m0 = nm;
            om = __shfl_xor(m1, off); os = __shfl_xor(t1, off);
            nm = fmaxf(m1, om); t1 = t1 * __expf(m1 - nm) + os * __expf(om - nm); m1 = nm;
            om = __shfl_xor(m2, off); os = __shfl_xor(t2, off);
            nm = fmaxf(m2, om); t2 = t2 * __expf(m2 - nm) + os * __expf(om - nm); m2 = nm;
            om = __shfl_xor(m3, off); os = __shfl_xor(t3, off);
            nm = fmaxf(m3, om); t3 = t3 * __expf(m3 - nm) + os * __expf(om - nm); m3 = nm;
        }
        i0 = 1.f / t0; i1 = 1.f / t1; i2 = 1.f / t2; i3 = 1.f / t3;
        p0 = __expf(e0 - m0); p1 = __expf(e1 - m1);
        p2 = __expf(e2 - m2); p3 = __expf(e3 - m3);
    }

    // ---- sweep: stage 32 edges' (offset, packed w) then broadcast-read per edge
    float accA = 0.f, accB = 0.f;
    const int boff = lane32 * 16;   // this lane's 16 B (2 channels x 4 heads)
    bool first = true;
    for (int base = start; base < end; base += 32){
        int cnt = end - base; if (cnt > 32) cnt = 32;
        float w0, w1, w2, w3; int off = 0;
        if (first){
            w0 = p0 * i0; w1 = p1 * i1; w2 = p2 * i2; w3 = p3 * i3;
            off = v0 ? src0 * (HC * 2) : 0;
        } else {
            w0 = w1 = w2 = w3 = 0.f;
            if (lane32 < cnt){
                int s = colsrc[base + lane32];
                float4 as = *(const float4*)(asrc + (size_t)s * 4);
                w0 = __expf(leaky(as.x + ad.x) - m0) * i0;
                w1 = __expf(leaky(as.y + ad.y) - m1) * i1;
                w2 = __expf(leaky(as.z + ad.z) - m2) * i2;
                w3 = __expf(leaky(as.w + ad.w) - m3) * i3;
                off = s * (HC * 2);
            }
        }
        first = false;
        s_off[grp][lane32] = off;
        half2_t q01 = __builtin_amdgcn_cvt_pkrtz(w0, w1);
        half2_t q23 = __builtin_amdgcn_cvt_pkrtz(w2, w3);
        s_w[grp][lane32] = (uint2){ __builtin_bit_cast(unsigned, q01),
                                    __builtin_bit_cast(unsigned, q23) };
        // wave-synchronous: same-wave staging, no barrier needed
        for (int j = 0; j < cnt; ++j){
            int o = s_off[grp][j];                // same-address broadcast per half
            uint2 w = s_w[grp][j];
            uint4 hv = *(const uint4*)((const char*)h + o + boff);
            accA = __builtin_amdgcn_fdot2(bc16(hv.x), bc16(w.x), accA, false);
            accA = __builtin_amdgcn_fdot2(bc16(hv.y), bc16(w.y), accA, false);
            accB = __builtin_amdgcn_fdot2(bc16(hv.z), bc16(w.x), accB, false);
            accB = __builtin_amdgcn_fdot2(bc16(hv.w), bc16(w.y), accB, false);
        }
    }

    float2 bv = *(const float2*)(bias + lane32 * 2);
    float oA = accA * 0.25f + bv.x;
    float oB = accB * 0.25f + bv.y;
    oA = (oA > 0.f) ? oA : expm1f(oA);
    oB = (oB > 0.f) ? oB : expm1f(oB);
    *(float2*)(hout + (size_t)n * CH + lane32 * 2) = make_float2(oA, oB);
}

// ---------------- scorer: MFMA (bf16x3) for hmid@Ws1, fp32 epilogue ----------------

__global__ __launch_bounds__(256) void scorer_mfma_kernel(
    const float* __restrict__ h2, const short* __restrict__ s1hi, const short* __restrict__ s1lo,
    const float* __restrict__ d1p, const float* __restrict__ Ws2, const float* __restrict__ bs2,
    float* __restrict__ out, int N)
{
    constexpr int XP = 68, WP = 72;
    __shared__ float xl[64 * XP];
    __shared__ short whi[64 * WP];
    __shared__ short wlo[64 * WP];
    const int tid = threadIdx.x;
    const int n0 = blockIdx.x * 64;

    for (int t = tid; t < 64 * 16; t += 256) {
        int row = t >> 4, c4 = (t & 15) * 4;
        int n = n0 + row;
        float4 v = make_float4(0.f, 0.f, 0.f, 0.f);
        if (n < N) v = *(const float4*)(h2 + (size_t)n * 64 + c4);
        *(float4*)(xl + row * XP + c4) = v;
    }
    {
        const short8* ghi = (const short8*)s1hi;
        const short8* glo = (const short8*)s1lo;
        short8* lhi = (short8*)whi;
        short8* llo = (short8*)wlo;
        for (int t = tid; t < 64 * WP / 8; t += 256){ lhi[t] = ghi[t]; llo[t] = glo[t]; }
    }
    __syncthreads();

    const int wv = tid >> 6, lane = tid & 63;
    const int quad = lane >> 4, ln = lane & 15;
    const int myrow = wv * 16 + ln;

    f32x4 acc[4];
    #pragma unroll
    for (int i = 0; i < 4; ++i) acc[i] = (f32x4){0.f, 0.f, 0.f, 0.f};

    #pragma unroll
    for (int ks = 0; ks < 2; ++ks) {
        const int k0 = ks * 32 + quad * 8;
        const float* ap = xl + myrow * XP + k0;
        float4 f0 = *(const float4*)ap;
        float4 f1 = *(const float4*)(ap + 4);
        float fa[8] = {f0.x, f0.y, f0.z, f0.w, f1.x, f1.y, f1.z, f1.w};
        short8 ahi, alo;
        #pragma unroll
        for (int e = 0; e < 8; ++e) {
            short hi = bf16_rne(fa[e]);
            ahi[e] = hi;
            alo[e] = bf16_rne(fa[e] - bf16_to_f(hi));
        }
        #pragma unroll
        for (int nt = 0; nt < 4; ++nt) {
            short8 bhi = *(const short8*)(whi + (nt * 16 + ln) * WP + k0);
            short8 blo = *(const short8*)(wlo + (nt * 16 + ln) * WP + k0);
            acc[nt] = __builtin_amdgcn_mfma_f32_16x16x32_bf16(ahi, bhi, acc[nt], 0, 0, 0);
            acc[nt] = __builtin_amdgcn_mfma_f32_16x16x32_bf16(alo, bhi, acc[nt], 0, 0, 0);
            acc[nt] = __builtin_amdgcn_mfma_f32_16x16x32_bf16(ahi, blo, acc[nt], 0, 0, 0);
        }
    }

    float d1v[4], w2v[4];
    #pragma unroll
    for (int nt = 0; nt < 4; ++nt){
        d1v[nt] = d1p[nt * 16 + ln];
        w2v[nt] = Ws2[nt * 16 + ln];
    }
    float b2 = bs2[0];
    #pragma unroll
    for (int r = 0; r < 4; ++r){
        float t = 0.f;
        #pragma unroll
        for (int nt = 0; nt < 4; ++nt)
            t = fmaf(fmaxf(acc[nt][r] + d1v[nt], 0.f), w2v[nt], t);
        #pragma unroll
        for (int off = 1; off < 16; off <<= 1) t += __shfl_xor(t, off);
        if (ln == 0){
            int n = n0 + wv * 16 + quad * 4 + r;
            if (n < N) out[n] = t + b2;
        }
    }
}

// ---------------- launch ----------------

extern "C" void kernel_launch(void* const* d_in, const int* in_sizes, int n_in,
                              void* d_out, int out_size, void* d_ws, size_t ws_size,
                              hipStream_t stream)
{
    const float* x    = (const float*)d_in[0];
    const int*   ei   = (const int*)  d_in[1];
    const float* donor= (const float*)d_in[2];
    const float* W1   = (const float*)d_in[3];
    const float* as1  = (const float*)d_in[4];
    const float* ad1  = (const float*)d_in[5];
    const float* b1   = (const float*)d_in[6];
    const float* W2   = (const float*)d_in[7];
    const float* as2  = (const float*)d_in[8];
    const float* ad2  = (const float*)d_in[9];
    const float* b2   = (const float*)d_in[10];
    const float* Ws1  = (const float*)d_in[11];
    const float* bs1  = (const float*)d_in[12];
    const float* Ws2  = (const float*)d_in[13];
    const float* bs2  = (const float*)d_in[14];

    const int N  = in_sizes[0] / 27;
    const int E  = in_sizes[1] / 2;
    const int ET = E + N;
    const int NB = (N + 255) / 256;

    char* ws = (char*)d_ws;
    auto alloc = [&](size_t bytes) -> void* {
        void* p = (void*)ws;
        ws += (bytes + 255) / 256 * 256;
        return p;
    };
    int*    rowptr  = (int*)   alloc((size_t)(N + 1) * 4);
    int*    colsrc  = (int*)   alloc((size_t)ET * 4);
    uint2*  pairs   = (uint2*) alloc((size_t)ET * 8);
    __half* hbig    = (__half*)alloc((size_t)N * HC * 2);
    float*  asrc    = (float*) alloc((size_t)N * 4 * 4);
    float*  adst    = (float*) alloc((size_t)N * 4 * 4);
    float*  hmid    = (float*) alloc((size_t)N * CH * 4);
    int*    bucket_cnt    = (int*) alloc(256 * 4);
    int*    bucket_base   = (int*) alloc(257 * 4);
    int*    bucket_cursor = (int*) alloc(256 * 4);
    short*  w1hi    = (short*) alloc(256 * 40 * 2);
    short*  w1lo    = (short*) alloc(256 * 40 * 2);
    short*  w2hi    = (short*) alloc(256 * 72 * 2);
    short*  w2lo    = (short*) alloc(256 * 72 * 2);
    short*  s1hi    = (short*) alloc(64 * 72 * 2);
    short*  s1lo    = (short*) alloc(64 * 72 * 2);
    float*  d1p     = (float*) alloc(64 * 4);

    const int nblk = (N + 63) / 64;
    const int hblk = (ET + 2047) / 2048;

    prep_kernel<<<256, 256, 0, stream>>>(W1, W2, Ws1, bs1, donor,
        w1hi, w1lo, w2hi, w2lo, s1hi, s1lo, d1p, bucket_cnt);
    transform1_hist_kernel<<<nblk + hblk, 256, 0, stream>>>(
        x, w1hi, w1lo, as1, ad1, hbig, asrc, adst, N, nblk, ei, E, NB, bucket_cnt);
    bucket_scan_kernel<<<1, 256, 0, stream>>>(bucket_cnt, NB, ET, bucket_base, bucket_cursor, rowptr, N);
    coarse_scatter_kernel<<<hblk, 256, 0, stream>>>(ei, E, N, NB, bucket_cursor, pairs);
    fine_sort_kernel<<<NB, 256, 0, stream>>>(pairs, bucket_base, colsrc, rowptr, N);
    aggregate_kernel<<<(N + 7) / 8, 256, 0, stream>>>(
        rowptr, colsrc, hbig, asrc, adst, b1, hmid, N);
    transform2_kernel<<<dim3(nblk, 2), 256, 0, stream>>>(
        hmid, w2hi, w2lo, as2, ad2, hbig, asrc, adst, N);
    aggregate_kernel<<<(N + 7) / 8, 256, 0, stream>>>(
        rowptr, colsrc, hbig, asrc, adst, b2, hmid, N);
    scorer_mfma_kernel<<<nblk, 256, 0, stream>>>(
        hmid, s1hi, s1lo, d1p, Ws2, bs2, (float*)d_out, N);
}

// Round 12
// 299.654 us; speedup vs baseline: 1.2983x; 1.0252x over previous
//
#include <hip/hip_runtime.h>
#include <hip/hip_fp16.h>
#include <cmath>

#define HEADS 4
#define CH 64
#define HC 256
#define NEG 0.2f

typedef __attribute__((ext_vector_type(8))) short short8;
typedef __attribute__((ext_vector_type(4))) float f32x4;
typedef __fp16 half2_t __attribute__((ext_vector_type(2)));

__device__ __forceinline__ float leaky(float v){ return v > 0.f ? v : NEG * v; }

__device__ __forceinline__ short bf16_rne(float f){
    unsigned u = __float_as_uint(f);
    unsigned r = u + 0x7fffu + ((u >> 16) & 1u);
    return (short)(r >> 16);
}
__device__ __forceinline__ float bf16_to_f(short s){
    return __uint_as_float(((unsigned)(unsigned short)s) << 16);
}
__device__ __forceinline__ half2_t bc16(unsigned u){ return __builtin_bit_cast(half2_t, u); }
__device__ __forceinline__ unsigned packh2(float a, float b){
    __half ha = __float2half(a), hb = __float2half(b);   // RNE
    return (unsigned)__builtin_bit_cast(unsigned short, ha)
         | ((unsigned)__builtin_bit_cast(unsigned short, hb) << 16);
}

// block-wide exclusive scan of one int per thread (256 threads)
__device__ __forceinline__ int block_excl_scan(int v, int* ws4){
    int tid = threadIdx.x, lane = tid & 63, wv = tid >> 6;
    int incl = v;
    #pragma unroll
    for (int off = 1; off < 64; off <<= 1){
        int t = __shfl_up(incl, off);
        if (lane >= off) incl += t;
    }
    if (lane == 63) ws4[wv] = incl;
    __syncthreads();
    int add = 0;
    for (int w = 0; w < wv; ++w) add += ws4[w];
    return incl - v + add;
}

// ---------------- prep: weight splits + d1 + zero bucket_cnt ----------------

__global__ __launch_bounds__(256) void prep_kernel(
    const float* __restrict__ W1, const float* __restrict__ W2,
    const float* __restrict__ Ws1, const float* __restrict__ bs1,
    const float* __restrict__ donor,
    short* __restrict__ w1hi, short* __restrict__ w1lo,
    short* __restrict__ w2hi,
    short* __restrict__ s1hi, short* __restrict__ s1lo,
    float* __restrict__ d1p, int* __restrict__ bucket_cnt)
{
    int t = blockIdx.x * 256 + threadIdx.x;
    int T = gridDim.x * 256;
    if (blockIdx.x == 0) bucket_cnt[threadIdx.x] = 0;
    for (int i = t; i < 256 * 40; i += T){
        int n = i / 40, k = i % 40;
        float v = (k < 27) ? W1[(size_t)k * HC + n] : 0.f;
        short hi = bf16_rne(v);
        w1hi[i] = hi; w1lo[i] = bf16_rne(v - bf16_to_f(hi));
    }
    for (int i = t; i < 256 * 72; i += T){
        int n = i / 72, k = i % 72;
        float v = (k < 64) ? W2[(size_t)k * HC + n] : 0.f;
        w2hi[i] = bf16_rne(v);
    }
    for (int i = t; i < 64 * 72; i += T){
        int n = i / 72, k = i % 72;
        float v = (k < 64) ? Ws1[(size_t)k * 64 + n] : 0.f;
        short hi = bf16_rne(v);
        s1hi[i] = hi; s1lo[i] = bf16_rne(v - bf16_to_f(hi));
    }
    if (t < 64){
        float s = bs1[t];
        for (int k = 0; k < 32; ++k) s = fmaf(donor[k], Ws1[(size_t)(64 + k) * 64 + t], s);
        d1p[t] = s;
    }
}

// ---------------- CSR build: two-level counting sort ----------------

__global__ __launch_bounds__(256) void bucket_scan_kernel(
    const int* __restrict__ bucket_cnt, int NB, int ET,
    int* __restrict__ bucket_base, int* __restrict__ bucket_cursor,
    int* __restrict__ rowptr, int N)
{
    __shared__ int ws4[4];
    int tid = threadIdx.x;
    int v = (tid < NB) ? bucket_cnt[tid] : 0;
    int excl = block_excl_scan(v, ws4);
    if (tid <= NB) bucket_base[tid] = excl;
    if (tid < NB)  bucket_cursor[tid] = excl;
    if (tid == 0)  rowptr[N] = ET;
}

__global__ __launch_bounds__(256) void coarse_scatter_kernel(
    const int* __restrict__ ei, int E, int N, int NB,
    int* __restrict__ bucket_cursor, uint2* __restrict__ pairs)
{
    __shared__ int lh[256];
    __shared__ int gb[256];
    int tid = threadIdx.x;
    int ET = E + N;
    int ebase = blockIdx.x * 2048;
    lh[tid] = 0;
    __syncthreads();
    int d[8], s[8], r[8];
    #pragma unroll
    for (int j = 0; j < 8; ++j){
        int e = ebase + j * 256 + tid;
        d[j] = -1;
        if (e < ET){
            if (e < E){ s[j] = ei[e]; d[j] = ei[E + e]; } else { s[j] = d[j] = e - E; }
            r[j] = atomicAdd(&lh[d[j] >> 8], 1);
        }
    }
    __syncthreads();
    if (tid < NB) gb[tid] = atomicAdd(&bucket_cursor[tid], lh[tid]);
    __syncthreads();
    #pragma unroll
    for (int j = 0; j < 8; ++j){
        if (d[j] >= 0)
            pairs[gb[d[j] >> 8] + r[j]] = make_uint2((unsigned)d[j], (unsigned)s[j]);
    }
}

__global__ __launch_bounds__(256) void fine_sort_kernel(
    const uint2* __restrict__ pairs, const int* __restrict__ bucket_base,
    int* __restrict__ colsrc, int* __restrict__ rowptr, int N)
{
    __shared__ int hist[256];
    __shared__ int cur[256];
    __shared__ int ws4[4];
    int tid = threadIdx.x;
    int b = blockIdx.x;
    int base = bucket_base[b], endb = bucket_base[b + 1];
    int cnt = endb - base;
    int d0 = b << 8;
    hist[tid] = 0;
    __syncthreads();
    for (int i = tid; i < cnt; i += 256){
        uint2 p = pairs[base + i];
        atomicAdd(&hist[p.x - d0], 1);
    }
    __syncthreads();
    int v = hist[tid];
    int excl = block_excl_scan(v, ws4);
    cur[tid] = excl;
    if (d0 + tid < N) rowptr[d0 + tid] = base + excl;
    __syncthreads();
    for (int i = tid; i < cnt; i += 256){
        uint2 p = pairs[base + i];
        int r = atomicAdd(&cur[p.x - d0], 1);
        colsrc[base + r] = (int)p.y;
    }
}

// ---------------- MFMA node transform (device body) ----------------
// X3: full bf16x3 split. !X3: drop ahi*blo term (W-lo), wt_lo unused.

template<int FIN, int KSTEPS, int NT, bool X3>
__device__ __forceinline__ void transform_body(
    int bx, int by,
    const float* __restrict__ xin, const short* __restrict__ whi, const short* __restrict__ wlo,
    const float* __restrict__ a_src, const float* __restrict__ a_dst,
    __half* __restrict__ h, float* __restrict__ asrc, float* __restrict__ adst, int N)
{
    constexpr int KP = KSTEPS * 32;
    constexpr int XP = KP + 4;
    constexpr int WP = KP + 8;
    constexpr int NCOL = NT * 16;
    __shared__ float xl[64 * XP];
    __shared__ short wt_hi[NCOL * WP];
    __shared__ short wt_lo[X3 ? NCOL * WP : 8];

    const int tid = threadIdx.x;
    const int n0 = bx * 64;
    const int c0 = by * NCOL;

    if (FIN == 64) {
        for (int t = tid; t < 64 * 16; t += 256) {
            int row = t >> 4, c4 = (t & 15) * 4;
            int n = n0 + row;
            float4 v = make_float4(0.f, 0.f, 0.f, 0.f);
            if (n < N) v = *(const float4*)(xin + (size_t)n * 64 + c4);
            *(float4*)(xl + row * XP + c4) = v;
        }
    } else {
        for (int t = tid; t < 64 * KP; t += 256) {
            int row = t / KP, k = t % KP;
            int n = n0 + row;
            float v = 0.f;
            if (n < N && k < FIN) v = xin[(size_t)n * FIN + k];
            xl[row * XP + k] = v;
        }
    }
    {
        const short8* ghi = (const short8*)(whi + (size_t)c0 * WP);
        short8* lhi = (short8*)wt_hi;
        for (int t = tid; t < NCOL * WP / 8; t += 256) lhi[t] = ghi[t];
        if (X3){
            const short8* glo = (const short8*)(wlo + (size_t)c0 * WP);
            short8* llo = (short8*)wt_lo;
            for (int t = tid; t < NCOL * WP / 8; t += 256) llo[t] = glo[t];
        }
    }
    __syncthreads();

    const int wv = tid >> 6, lane = tid & 63;
    const int quad = lane >> 4, ln = lane & 15;
    const int myrow = wv * 16 + ln;

    f32x4 acc[NT];
    #pragma unroll
    for (int i = 0; i < NT; ++i) acc[i] = (f32x4){0.f, 0.f, 0.f, 0.f};

    #pragma unroll
    for (int ks = 0; ks < KSTEPS; ++ks) {
        const int k0 = ks * 32 + quad * 8;
        const float* ap = xl + myrow * XP + k0;
        float4 f0 = *(const float4*)ap;
        float4 f1 = *(const float4*)(ap + 4);
        float fa[8] = {f0.x, f0.y, f0.z, f0.w, f1.x, f1.y, f1.z, f1.w};
        short8 ahi, alo;
        #pragma unroll
        for (int e = 0; e < 8; ++e) {
            short hi = bf16_rne(fa[e]);
            ahi[e] = hi;
            alo[e] = bf16_rne(fa[e] - bf16_to_f(hi));
        }
        #pragma unroll
        for (int nt = 0; nt < NT; ++nt) {
            short8 bhi = *(const short8*)(wt_hi + (nt * 16 + ln) * WP + k0);
            acc[nt] = __builtin_amdgcn_mfma_f32_16x16x32_bf16(ahi, bhi, acc[nt], 0, 0, 0);
            acc[nt] = __builtin_amdgcn_mfma_f32_16x16x32_bf16(alo, bhi, acc[nt], 0, 0, 0);
            if (X3){
                short8 blo = *(const short8*)(wt_lo + (nt * 16 + ln) * WP + k0);
                acc[nt] = __builtin_amdgcn_mfma_f32_16x16x32_bf16(ahi, blo, acc[nt], 0, 0, 0);
            }
        }
    }

    #pragma unroll
    for (int r = 0; r < 4; ++r) {
        int n = n0 + wv * 16 + quad * 4 + r;
        if (n < N) {
            if (NT == 16) {
                #pragma unroll
                for (int q = 0; q < 4; ++q) {
                    uint2 u;
                    u.x = packh2(acc[q][r],     acc[q + 4][r]);
                    u.y = packh2(acc[q + 8][r], acc[q + 12][r]);
                    *(uint2*)((char*)h + (size_t)n * 512 + (q * 16 + ln) * 8) = u;
                }
            } else {
                #pragma unroll
                for (int q = 0; q < 4; ++q) {
                    unsigned u = packh2(acc[q][r], acc[q + 4][r]);
                    *(unsigned*)((char*)h + (size_t)n * 512 + (q * 16 + ln) * 8 + ((c0 >> 6) << 1)) = u;
                }
            }
        }
    }

    float aS[NT], aD[NT];
    #pragma unroll
    for (int nt = 0; nt < NT; ++nt) {
        aS[nt] = a_src[c0 + nt * 16 + ln];
        aD[nt] = a_dst[c0 + nt * 16 + ln];
    }
    #pragma unroll
    for (int hl = 0; hl < NT / 4; ++hl) {
        #pragma unroll
        for (int r = 0; r < 4; ++r) {
            float ps = 0.f, pd = 0.f;
            #pragma unroll
            for (int i = 0; i < 4; ++i) {
                ps = fmaf(acc[hl * 4 + i][r], aS[hl * 4 + i], ps);
                pd = fmaf(acc[hl * 4 + i][r], aD[hl * 4 + i], pd);
            }
            #pragma unroll
            for (int off = 1; off < 16; off <<= 1) {
                ps += __shfl_xor(ps, off);
                pd += __shfl_xor(pd, off);
            }
            if (ln == 0) {
                int n = n0 + wv * 16 + quad * 4 + r;
                if (n < N) {
                    int hg = c0 / 64 + hl;
                    asrc[n * 4 + hg] = ps;
                    adst[n * 4 + hg] = pd;
                }
            }
        }
    }
}

__global__ __launch_bounds__(256) void transform1_hist_kernel(
    const float* __restrict__ xin, const short* __restrict__ whi, const short* __restrict__ wlo,
    const float* __restrict__ a_src, const float* __restrict__ a_dst,
    __half* __restrict__ h, float* __restrict__ asrc, float* __restrict__ adst, int N,
    int nblk, const int* __restrict__ ei, int E, int NB, int* __restrict__ bucket_cnt)
{
    if ((int)blockIdx.x < nblk) {
        transform_body<27, 1, 16, true>(blockIdx.x, 0, xin, whi, wlo, a_src, a_dst, h, asrc, adst, N);
    } else {
        __shared__ int lh[256];
        int tid = threadIdx.x;
        int ET = E + N;
        int ebase = (blockIdx.x - nblk) * 2048;
        lh[tid] = 0;
        __syncthreads();
        #pragma unroll
        for (int j = 0; j < 8; ++j){
            int e = ebase + j * 256 + tid;
            if (e < ET){
                int d = (e < E) ? ei[E + e] : (e - E);
                atomicAdd(&lh[d >> 8], 1);
            }
        }
        __syncthreads();
        if (tid < NB) atomicAdd(&bucket_cnt[tid], lh[tid]);
    }
}

// transform2: single pass over all 256 cols (NT=16), bf16x2 (W-lo dropped) -> 54 KB LDS
__global__ __launch_bounds__(256) void transform2_kernel(
    const float* __restrict__ xin, const short* __restrict__ whi,
    const float* __restrict__ a_src, const float* __restrict__ a_dst,
    __half* __restrict__ h, float* __restrict__ asrc, float* __restrict__ adst, int N)
{
    transform_body<64, 2, 16, false>(blockIdx.x, 0, xin, whi, nullptr, a_src, a_dst, h, asrc, adst, N);
}

// ---------------- per-dst aggregation: 2 nodes/wave, shfl-broadcast sweep ----------------
// lane32 = channel pair (16 B). Offsets/weights broadcast via __shfl(width 32) —
// no LDS, no lgkmcnt in the gather chain. 2 loads in flight per unrolled step.

__global__ __launch_bounds__(256) void aggregate_kernel(
    const int* __restrict__ rowptr, const int* __restrict__ colsrc,
    const __half* __restrict__ h, const float* __restrict__ asrc,
    const float* __restrict__ adst, const float* __restrict__ bias,
    float* __restrict__ hout, int N)
{
    int tid = threadIdx.x;
    int grp = tid >> 5;
    int lane32 = tid & 31;
    int n = blockIdx.x * 8 + grp;
    if (n >= N) return;
    int start = rowptr[n], end = rowptr[n + 1];
    int deg = end - start;
    const float4 ad = *(const float4*)(adst + (size_t)n * 4);

    int src0 = 0;
    float e0 = -1e30f, e1 = -1e30f, e2 = -1e30f, e3 = -1e30f;
    bool v0 = lane32 < deg;
    if (v0){
        src0 = colsrc[start + lane32];
        float4 as = *(const float4*)(asrc + (size_t)src0 * 4);
        e0 = leaky(as.x + ad.x); e1 = leaky(as.y + ad.y);
        e2 = leaky(as.z + ad.z); e3 = leaky(as.w + ad.w);
    }

    float m0, m1, m2, m3, i0, i1, i2, i3, p0, p1, p2, p3;
    if (deg <= 32){
        m0 = e0; m1 = e1; m2 = e2; m3 = e3;
        #pragma unroll
        for (int off = 1; off < 32; off <<= 1){
            m0 = fmaxf(m0, __shfl_xor(m0, off));
            m1 = fmaxf(m1, __shfl_xor(m1, off));
            m2 = fmaxf(m2, __shfl_xor(m2, off));
            m3 = fmaxf(m3, __shfl_xor(m3, off));
        }
        p0 = __expf(e0 - m0);
        p1 = __expf(e1 - m1);
        p2 = __expf(e2 - m2);
        p3 = __expf(e3 - m3);
        float t0 = p0, t1 = p1, t2 = p2, t3 = p3;
        #pragma unroll
        for (int off = 1; off < 32; off <<= 1){
            t0 += __shfl_xor(t0, off);
            t1 += __shfl_xor(t1, off);
            t2 += __shfl_xor(t2, off);
            t3 += __shfl_xor(t3, off);
        }
        i0 = 1.f / t0; i1 = 1.f / t1; i2 = 1.f / t2; i3 = 1.f / t3;
    } else {
        m0 = e0; m1 = e1; m2 = e2; m3 = e3;
        float t0 = v0 ? 1.f : 0.f, t1 = t0, t2 = t0, t3 = t0;
        for (int i = start + 32 + lane32; i < end; i += 32){
            int s = colsrc[i];
            float4 as = *(const float4*)(asrc + (size_t)s * 4);
            float e, nm;
            e = leaky(as.x + ad.x); nm = fmaxf(m0, e); t0 = t0 * __expf(m0 - nm) + __expf(e - nm); m0 = nm;
            e = leaky(as.y + ad.y); nm = fmaxf(m1, e); t1 = t1 * __expf(m1 - nm) + __expf(e - nm); m1 = nm;
            e = leaky(as.z + ad.z); nm = fmaxf(m2, e); t2 = t2 * __expf(m2 - nm) + __expf(e - nm); m2 = nm;
            e = leaky(as.w + ad.w); nm = fmaxf(m3, e); t3 = t3 * __expf(m3 - nm) + __expf(e - nm); m3 = nm;
        }
        #pragma unroll
        for (int off = 1; off < 32; off <<= 1){
            float om, os, nm;
            om = __shfl_xor(m0, off); os = __shfl_xor(t0, off);
            nm = fmaxf(m0, om); t0 = t0 * __expf(m0 - nm) + os * __expf(om - nm); m0 = nm;
            om = __shfl_xor(m1, off); os = __shfl_xor(t1, off);
            nm = fmaxf(m1, om); t1 = t1 * __expf(m1 - nm) + os * __expf(om - nm); m1 = nm;
            om = __shfl_xor(m2, off); os = __shfl_xor(t2, off);
            nm = fmaxf(m2, om); t2 = t2 * __expf(m2 - nm) + os * __expf(om - nm); m2 = nm;
            om = __shfl_xor(m3, off); os = __shfl_xor(t3, off);
            nm = fmaxf(m3, om); t3 = t3 * __expf(m3 - nm) + os * __expf(om - nm); m3 = nm;
        }
        i0 = 1.f / t0; i1 = 1.f / t1; i2 = 1.f / t2; i3 = 1.f / t3;
        p0 = __expf(e0 - m0); p1 = __expf(e1 - m1);
        p2 = __expf(e2 - m2); p3 = __expf(e3 - m3);
    }

    float accA = 0.f, accB = 0.f;
    const int boff = lane32 * 16;
    bool first = true;
    for (int base = start; base < end; base += 32){
        int cnt = end - base; if (cnt > 32) cnt = 32;
        float w0, w1, w2, w3; int off = 0;
        if (first){
            w0 = p0 * i0; w1 = p1 * i1; w2 = p2 * i2; w3 = p3 * i3;
            off = v0 ? src0 * (HC * 2) : 0;
        } else {
            w0 = w1 = w2 = w3 = 0.f;
            if (lane32 < cnt){
                int s = colsrc[base + lane32];
                float4 as = *(const float4*)(asrc + (size_t)s * 4);
                w0 = __expf(leaky(as.x + ad.x) - m0) * i0;
                w1 = __expf(leaky(as.y + ad.y) - m1) * i1;
                w2 = __expf(leaky(as.z + ad.z) - m2) * i2;
                w3 = __expf(leaky(as.w + ad.w) - m3) * i3;
                off = s * (HC * 2);
            }
        }
        first = false;
        half2_t q01 = __builtin_amdgcn_cvt_pkrtz(w0, w1);
        half2_t q23 = __builtin_amdgcn_cvt_pkrtz(w2, w3);
        unsigned wx = __builtin_bit_cast(unsigned, q01);
        unsigned wy = __builtin_bit_cast(unsigned, q23);

        int j = 0;
        for (; j + 2 <= cnt; j += 2){
            int o0 = __shfl(off, j, 32);
            unsigned a0 = __shfl((int)wx, j, 32), b0 = __shfl((int)wy, j, 32);
            int o1 = __shfl(off, j + 1, 32);
            unsigned a1 = __shfl((int)wx, j + 1, 32), b1 = __shfl((int)wy, j + 1, 32);
            uint4 h0 = *(const uint4*)((const char*)h + o0 + boff);
            uint4 h1 = *(const uint4*)((const char*)h + o1 + boff);
            accA = __builtin_amdgcn_fdot2(bc16(h0.x), bc16(a0), accA, false);
            accA = __builtin_amdgcn_fdot2(bc16(h0.y), bc16(b0), accA, false);
            accB = __builtin_amdgcn_fdot2(bc16(h0.z), bc16(a0), accB, false);
            accB = __builtin_amdgcn_fdot2(bc16(h0.w), bc16(b0), accB, false);
            accA = __builtin_amdgcn_fdot2(bc16(h1.x), bc16(a1), accA, false);
            accA = __builtin_amdgcn_fdot2(bc16(h1.y), bc16(b1), accA, false);
            accB = __builtin_amdgcn_fdot2(bc16(h1.z), bc16(a1), accB, false);
            accB = __builtin_amdgcn_fdot2(bc16(h1.w), bc16(b1), accB, false);
        }
        for (; j < cnt; ++j){
            int o0 = __shfl(off, j, 32);
            unsigned a0 = __shfl((int)wx, j, 32), b0 = __shfl((int)wy, j, 32);
            uint4 h0 = *(const uint4*)((const char*)h + o0 + boff);
            accA = __builtin_amdgcn_fdot2(bc16(h0.x), bc16(a0), accA, false);
            accA = __builtin_amdgcn_fdot2(bc16(h0.y), bc16(b0), accA, false);
            accB = __builtin_amdgcn_fdot2(bc16(h0.z), bc16(a0), accB, false);
            accB = __builtin_amdgcn_fdot2(bc16(h0.w), bc16(b0), accB, false);
        }
    }

    float2 bv = *(const float2*)(bias + lane32 * 2);
    float oA = accA * 0.25f + bv.x;
    float oB = accB * 0.25f + bv.y;
    oA = (oA > 0.f) ? oA : expm1f(oA);
    oB = (oB > 0.f) ? oB : expm1f(oB);
    *(float2*)(hout + (size_t)n * CH + lane32 * 2) = make_float2(oA, oB);
}

// ---------------- scorer: MFMA (bf16x3) for hmid@Ws1, fp32 epilogue ----------------

__global__ __launch_bounds__(256) void scorer_mfma_kernel(
    const float* __restrict__ h2, const short* __restrict__ s1hi, const short* __restrict__ s1lo,
    const float* __restrict__ d1p, const float* __restrict__ Ws2, const float* __restrict__ bs2,
    float* __restrict__ out, int N)
{
    constexpr int XP = 68, WP = 72;
    __shared__ float xl[64 * XP];
    __shared__ short whi[64 * WP];
    __shared__ short wlo[64 * WP];
    const int tid = threadIdx.x;
    const int n0 = blockIdx.x * 64;

    for (int t = tid; t < 64 * 16; t += 256) {
        int row = t >> 4, c4 = (t & 15) * 4;
        int n = n0 + row;
        float4 v = make_float4(0.f, 0.f, 0.f, 0.f);
        if (n < N) v = *(const float4*)(h2 + (size_t)n * 64 + c4);
        *(float4*)(xl + row * XP + c4) = v;
    }
    {
        const short8* ghi = (const short8*)s1hi;
        const short8* glo = (const short8*)s1lo;
        short8* lhi = (short8*)whi;
        short8* llo = (short8*)wlo;
        for (int t = tid; t < 64 * WP / 8; t += 256){ lhi[t] = ghi[t]; llo[t] = glo[t]; }
    }
    __syncthreads();

    const int wv = tid >> 6, lane = tid & 63;
    const int quad = lane >> 4, ln = lane & 15;
    const int myrow = wv * 16 + ln;

    f32x4 acc[4];
    #pragma unroll
    for (int i = 0; i < 4; ++i) acc[i] = (f32x4){0.f, 0.f, 0.f, 0.f};

    #pragma unroll
    for (int ks = 0; ks < 2; ++ks) {
        const int k0 = ks * 32 + quad * 8;
        const float* ap = xl + myrow * XP + k0;
        float4 f0 = *(const float4*)ap;
        float4 f1 = *(const float4*)(ap + 4);
        float fa[8] = {f0.x, f0.y, f0.z, f0.w, f1.x, f1.y, f1.z, f1.w};
        short8 ahi, alo;
        #pragma unroll
        for (int e = 0; e < 8; ++e) {
            short hi = bf16_rne(fa[e]);
            ahi[e] = hi;
            alo[e] = bf16_rne(fa[e] - bf16_to_f(hi));
        }
        #pragma unroll
        for (int nt = 0; nt < 4; ++nt) {
            short8 bhi = *(const short8*)(whi + (nt * 16 + ln) * WP + k0);
            short8 blo = *(const short8*)(wlo + (nt * 16 + ln) * WP + k0);
            acc[nt] = __builtin_amdgcn_mfma_f32_16x16x32_bf16(ahi, bhi, acc[nt], 0, 0, 0);
            acc[nt] = __builtin_amdgcn_mfma_f32_16x16x32_bf16(alo, bhi, acc[nt], 0, 0, 0);
            acc[nt] = __builtin_amdgcn_mfma_f32_16x16x32_bf16(ahi, blo, acc[nt], 0, 0, 0);
        }
    }

    float d1v[4], w2v[4];
    #pragma unroll
    for (int nt = 0; nt < 4; ++nt){
        d1v[nt] = d1p[nt * 16 + ln];
        w2v[nt] = Ws2[nt * 16 + ln];
    }
    float b2 = bs2[0];
    #pragma unroll
    for (int r = 0; r < 4; ++r){
        float t = 0.f;
        #pragma unroll
        for (int nt = 0; nt < 4; ++nt)
            t = fmaf(fmaxf(acc[nt][r] + d1v[nt], 0.f), w2v[nt], t);
        #pragma unroll
        for (int off = 1; off < 16; off <<= 1) t += __shfl_xor(t, off);
        if (ln == 0){
            int n = n0 + wv * 16 + quad * 4 + r;
            if (n < N) out[n] = t + b2;
        }
    }
}

// ---------------- launch ----------------

extern "C" void kernel_launch(void* const* d_in, const int* in_sizes, int n_in,
                              void* d_out, int out_size, void* d_ws, size_t ws_size,
                              hipStream_t stream)
{
    const float* x    = (const float*)d_in[0];
    const int*   ei   = (const int*)  d_in[1];
    const float* donor= (const float*)d_in[2];
    const float* W1   = (const float*)d_in[3];
    const float* as1  = (const float*)d_in[4];
    const float* ad1  = (const float*)d_in[5];
    const float* b1   = (const float*)d_in[6];
    const float* W2   = (const float*)d_in[7];
    const float* as2  = (const float*)d_in[8];
    const float* ad2  = (const float*)d_in[9];
    const float* b2   = (const float*)d_in[10];
    const float* Ws1  = (const float*)d_in[11];
    const float* bs1  = (const float*)d_in[12];
    const float* Ws2  = (const float*)d_in[13];
    const float* bs2  = (const float*)d_in[14];

    const int N  = in_sizes[0] / 27;
    const int E  = in_sizes[1] / 2;
    const int ET = E + N;
    const int NB = (N + 255) / 256;

    char* ws = (char*)d_ws;
    auto alloc = [&](size_t bytes) -> void* {
        void* p = (void*)ws;
        ws += (bytes + 255) / 256 * 256;
        return p;
    };
    int*    rowptr  = (int*)   alloc((size_t)(N + 1) * 4);
    int*    colsrc  = (int*)   alloc((size_t)ET * 4);
    uint2*  pairs   = (uint2*) alloc((size_t)ET * 8);
    __half* hbig    = (__half*)alloc((size_t)N * HC * 2);
    float*  asrc    = (float*) alloc((size_t)N * 4 * 4);
    float*  adst    = (float*) alloc((size_t)N * 4 * 4);
    float*  hmid    = (float*) alloc((size_t)N * CH * 4);
    int*    bucket_cnt    = (int*) alloc(256 * 4);
    int*    bucket_base   = (int*) alloc(257 * 4);
    int*    bucket_cursor = (int*) alloc(256 * 4);
    short*  w1hi    = (short*) alloc(256 * 40 * 2);
    short*  w1lo    = (short*) alloc(256 * 40 * 2);
    short*  w2hi    = (short*) alloc(256 * 72 * 2);
    short*  s1hi    = (short*) alloc(64 * 72 * 2);
    short*  s1lo    = (short*) alloc(64 * 72 * 2);
    float*  d1p     = (float*) alloc(64 * 4);

    const int nblk = (N + 63) / 64;
    const int hblk = (ET + 2047) / 2048;

    prep_kernel<<<256, 256, 0, stream>>>(W1, W2, Ws1, bs1, donor,
        w1hi, w1lo, w2hi, s1hi, s1lo, d1p, bucket_cnt);
    transform1_hist_kernel<<<nblk + hblk, 256, 0, stream>>>(
        x, w1hi, w1lo, as1, ad1, hbig, asrc, adst, N, nblk, ei, E, NB, bucket_cnt);
    bucket_scan_kernel<<<1, 256, 0, stream>>>(bucket_cnt, NB, ET, bucket_base, bucket_cursor, rowptr, N);
    coarse_scatter_kernel<<<hblk, 256, 0, stream>>>(ei, E, N, NB, bucket_cursor, pairs);
    fine_sort_kernel<<<NB, 256, 0, stream>>>(pairs, bucket_base, colsrc, rowptr, N);
    aggregate_kernel<<<(N + 7) / 8, 256, 0, stream>>>(
        rowptr, colsrc, hbig, asrc, adst, b1, hmid, N);
    transform2_kernel<<<nblk, 256, 0, stream>>>(
        hmid, w2hi, as2, ad2, hbig, asrc, adst, N);
    aggregate_kernel<<<(N + 7) / 8, 256, 0, stream>>>(
        rowptr, colsrc, hbig, asrc, adst, b2, hmid, N);
    scorer_mfma_kernel<<<nblk, 256, 0, stream>>>(
        hmid, s1hi, s1lo, d1p, Ws2, bs2, (float*)d_out, N);
}

// Round 13
// 289.354 us; speedup vs baseline: 1.3445x; 1.0356x over previous
//
#include <hip/hip_runtime.h>
#include <hip/hip_fp16.h>
#include <cmath>

#define HEADS 4
#define CH 64
#define HC 256
#define NEG 0.2f

typedef __attribute__((ext_vector_type(8))) short short8;
typedef __attribute__((ext_vector_type(4))) float f32x4;
typedef __fp16 half2_t __attribute__((ext_vector_type(2)));

__device__ __forceinline__ float leaky(float v){ return v > 0.f ? v : NEG * v; }

__device__ __forceinline__ short bf16_rne(float f){
    unsigned u = __float_as_uint(f);
    unsigned r = u + 0x7fffu + ((u >> 16) & 1u);
    return (short)(r >> 16);
}
__device__ __forceinline__ float bf16_to_f(short s){
    return __uint_as_float(((unsigned)(unsigned short)s) << 16);
}
__device__ __forceinline__ half2_t bc16(unsigned u){ return __builtin_bit_cast(half2_t, u); }
__device__ __forceinline__ unsigned packh2(float a, float b){
    __half ha = __float2half(a), hb = __float2half(b);   // RNE
    return (unsigned)__builtin_bit_cast(unsigned short, ha)
         | ((unsigned)__builtin_bit_cast(unsigned short, hb) << 16);
}

// block-wide exclusive scan of one int per thread (256 threads)
__device__ __forceinline__ int block_excl_scan(int v, int* ws4){
    int tid = threadIdx.x, lane = tid & 63, wv = tid >> 6;
    int incl = v;
    #pragma unroll
    for (int off = 1; off < 64; off <<= 1){
        int t = __shfl_up(incl, off);
        if (lane >= off) incl += t;
    }
    if (lane == 63) ws4[wv] = incl;
    __syncthreads();
    int add = 0;
    for (int w = 0; w < wv; ++w) add += ws4[w];
    return incl - v + add;
}

// ---------------- prep (+ edge histogram tail) ----------------
// bucket_cnt/bucket_cursor zeroed by hipMemsetAsync before this kernel.

__global__ __launch_bounds__(256) void prep_hist_kernel(
    const float* __restrict__ W1, const float* __restrict__ W2,
    const float* __restrict__ Ws1, const float* __restrict__ bs1,
    const float* __restrict__ donor,
    short* __restrict__ w1hi, short* __restrict__ w2hi,
    short* __restrict__ s1hi, short* __restrict__ s1lo,
    float* __restrict__ d1p,
    const int* __restrict__ ei, int E, int N, int NB, int* __restrict__ bucket_cnt)
{
    if ((int)blockIdx.x < 256){
        int t = blockIdx.x * 256 + threadIdx.x;
        int T = 256 * 256;
        for (int i = t; i < 256 * 40; i += T){                  // W1 bf16: [n=256][k pitch 40], K=27
            int n = i / 40, k = i % 40;
            w1hi[i] = bf16_rne((k < 27) ? W1[(size_t)k * HC + n] : 0.f);
        }
        for (int i = t; i < 256 * 72; i += T){                  // W2 bf16: [n=256][k pitch 72], K=64
            int n = i / 72, k = i % 72;
            w2hi[i] = bf16_rne((k < 64) ? W2[(size_t)k * HC + n] : 0.f);
        }
        for (int i = t; i < 64 * 72; i += T){                   // Ws1 bf16x2 (scorer keeps x3)
            int n = i / 72, k = i % 72;
            float v = (k < 64) ? Ws1[(size_t)k * 64 + n] : 0.f;
            short hi = bf16_rne(v);
            s1hi[i] = hi; s1lo[i] = bf16_rne(v - bf16_to_f(hi));
        }
        if (t < 64){
            float s = bs1[t];
            for (int k = 0; k < 32; ++k) s = fmaf(donor[k], Ws1[(size_t)(64 + k) * 64 + t], s);
            d1p[t] = s;
        }
    } else {
        __shared__ int lh[256];
        int tid = threadIdx.x;
        int ET = E + N;
        int ebase = ((int)blockIdx.x - 256) * 2048;
        lh[tid] = 0;
        __syncthreads();
        #pragma unroll
        for (int j = 0; j < 8; ++j){
            int e = ebase + j * 256 + tid;
            if (e < ET){
                int d = (e < E) ? ei[E + e] : (e - E);
                atomicAdd(&lh[d >> 8], 1);
            }
        }
        __syncthreads();
        if (tid < NB && lh[tid]) atomicAdd(&bucket_cnt[tid], lh[tid]);
    }
}

// ---------------- coarse scatter (self-scan of bucket counts) ----------------

__global__ __launch_bounds__(256) void coarse_scatter_kernel(
    const int* __restrict__ ei, int E, int N, int NB,
    const int* __restrict__ bucket_cnt, int* __restrict__ bucket_cursor,
    uint2* __restrict__ pairs)
{
    __shared__ int ws4[4];
    __shared__ int gbase[256];
    __shared__ int lh[256];
    __shared__ int gb[256];
    int tid = threadIdx.x;
    int ET = E + N;
    // self-scan: global base of each bucket
    {
        int v = (tid < NB) ? bucket_cnt[tid] : 0;
        gbase[tid] = block_excl_scan(v, ws4);
    }
    lh[tid] = 0;
    __syncthreads();
    int ebase = blockIdx.x * 2048;
    int d[8], s[8], r[8];
    #pragma unroll
    for (int j = 0; j < 8; ++j){
        int e = ebase + j * 256 + tid;
        d[j] = -1;
        if (e < ET){
            if (e < E){ s[j] = ei[e]; d[j] = ei[E + e]; } else { s[j] = d[j] = e - E; }
            r[j] = atomicAdd(&lh[d[j] >> 8], 1);
        }
    }
    __syncthreads();
    if (tid < NB && lh[tid]) gb[tid] = gbase[tid] + atomicAdd(&bucket_cursor[tid], lh[tid]);
    __syncthreads();
    #pragma unroll
    for (int j = 0; j < 8; ++j){
        if (d[j] >= 0)
            pairs[gb[d[j] >> 8] + r[j]] = make_uint2((unsigned)d[j], (unsigned)s[j]);
    }
}

// ---------------- fine sort body (self-scan, block-local writes) ----------------

__device__ __forceinline__ void fine_sort_body(
    int b, const uint2* __restrict__ pairs, const int* __restrict__ bucket_cnt, int NB,
    int* __restrict__ colsrc, int* __restrict__ rowptr, int N, int ET)
{
    __shared__ int ws4f[4];
    __shared__ int sb[257];
    __shared__ int hist[256];
    __shared__ int cur[256];
    int tid = threadIdx.x;
    {
        int v = (tid < NB) ? bucket_cnt[tid] : 0;
        int excl = block_excl_scan(v, ws4f);
        sb[tid] = excl;
        if (tid == 255) sb[256] = excl + v;
    }
    hist[tid] = 0;
    __syncthreads();
    int base = sb[b], endb = sb[b + 1];
    int cnt = endb - base;
    int d0 = b << 8;
    for (int i = tid; i < cnt; i += 256){
        uint2 p = pairs[base + i];
        atomicAdd(&hist[p.x - d0], 1);
    }
    __syncthreads();
    int v = hist[tid];
    int excl = block_excl_scan(v, ws4f);
    cur[tid] = excl;
    if (d0 + tid < N) rowptr[d0 + tid] = base + excl;
    if (b == 0 && tid == 0) rowptr[N] = ET;
    __syncthreads();
    for (int i = tid; i < cnt; i += 256){
        uint2 p = pairs[base + i];
        int r = atomicAdd(&cur[p.x - d0], 1);
        colsrc[base + r] = (int)p.y;
    }
}

// ---------------- MFMA node transform (device body) ----------------
// X3: full bf16x3 split. !X3: drop ahi*blo term (W-lo), wt_lo unused.

template<int FIN, int KSTEPS, int NT, bool X3>
__device__ __forceinline__ void transform_body(
    int bx, int by,
    const float* __restrict__ xin, const short* __restrict__ whi, const short* __restrict__ wlo,
    const float* __restrict__ a_src, const float* __restrict__ a_dst,
    __half* __restrict__ h, float* __restrict__ asrc, float* __restrict__ adst, int N)
{
    constexpr int KP = KSTEPS * 32;
    constexpr int XP = KP + 4;
    constexpr int WP = KP + 8;
    constexpr int NCOL = NT * 16;
    __shared__ float xl[64 * XP];
    __shared__ short wt_hi[NCOL * WP];
    __shared__ short wt_lo[X3 ? NCOL * WP : 8];

    const int tid = threadIdx.x;
    const int n0 = bx * 64;
    const int c0 = by * NCOL;

    if (FIN == 64) {
        for (int t = tid; t < 64 * 16; t += 256) {
            int row = t >> 4, c4 = (t & 15) * 4;
            int n = n0 + row;
            float4 v = make_float4(0.f, 0.f, 0.f, 0.f);
            if (n < N) v = *(const float4*)(xin + (size_t)n * 64 + c4);
            *(float4*)(xl + row * XP + c4) = v;
        }
    } else {
        for (int t = tid; t < 64 * KP; t += 256) {
            int row = t / KP, k = t % KP;
            int n = n0 + row;
            float v = 0.f;
            if (n < N && k < FIN) v = xin[(size_t)n * FIN + k];
            xl[row * XP + k] = v;
        }
    }
    {
        const short8* ghi = (const short8*)(whi + (size_t)c0 * WP);
        short8* lhi = (short8*)wt_hi;
        for (int t = tid; t < NCOL * WP / 8; t += 256) lhi[t] = ghi[t];
        if (X3){
            const short8* glo = (const short8*)(wlo + (size_t)c0 * WP);
            short8* llo = (short8*)wt_lo;
            for (int t = tid; t < NCOL * WP / 8; t += 256) llo[t] = glo[t];
        }
    }
    __syncthreads();

    const int wv = tid >> 6, lane = tid & 63;
    const int quad = lane >> 4, ln = lane & 15;
    const int myrow = wv * 16 + ln;

    f32x4 acc[NT];
    #pragma unroll
    for (int i = 0; i < NT; ++i) acc[i] = (f32x4){0.f, 0.f, 0.f, 0.f};

    #pragma unroll
    for (int ks = 0; ks < KSTEPS; ++ks) {
        const int k0 = ks * 32 + quad * 8;
        const float* ap = xl + myrow * XP + k0;
        float4 f0 = *(const float4*)ap;
        float4 f1 = *(const float4*)(ap + 4);
        float fa[8] = {f0.x, f0.y, f0.z, f0.w, f1.x, f1.y, f1.z, f1.w};
        short8 ahi, alo;
        #pragma unroll
        for (int e = 0; e < 8; ++e) {
            short hi = bf16_rne(fa[e]);
            ahi[e] = hi;
            alo[e] = bf16_rne(fa[e] - bf16_to_f(hi));
        }
        #pragma unroll
        for (int nt = 0; nt < NT; ++nt) {
            short8 bhi = *(const short8*)(wt_hi + (nt * 16 + ln) * WP + k0);
            acc[nt] = __builtin_amdgcn_mfma_f32_16x16x32_bf16(ahi, bhi, acc[nt], 0, 0, 0);
            acc[nt] = __builtin_amdgcn_mfma_f32_16x16x32_bf16(alo, bhi, acc[nt], 0, 0, 0);
            if (X3){
                short8 blo = *(const short8*)(wt_lo + (nt * 16 + ln) * WP + k0);
                acc[nt] = __builtin_amdgcn_mfma_f32_16x16x32_bf16(ahi, blo, acc[nt], 0, 0, 0);
            }
        }
    }

    #pragma unroll
    for (int r = 0; r < 4; ++r) {
        int n = n0 + wv * 16 + quad * 4 + r;
        if (n < N) {
            if (NT == 16) {
                #pragma unroll
                for (int q = 0; q < 4; ++q) {
                    uint2 u;
                    u.x = packh2(acc[q][r],     acc[q + 4][r]);
                    u.y = packh2(acc[q + 8][r], acc[q + 12][r]);
                    *(uint2*)((char*)h + (size_t)n * 512 + (q * 16 + ln) * 8) = u;
                }
            } else {
                #pragma unroll
                for (int q = 0; q < 4; ++q) {
                    unsigned u = packh2(acc[q][r], acc[q + 4][r]);
                    *(unsigned*)((char*)h + (size_t)n * 512 + (q * 16 + ln) * 8 + ((c0 >> 6) << 1)) = u;
                }
            }
        }
    }

    float aS[NT], aD[NT];
    #pragma unroll
    for (int nt = 0; nt < NT; ++nt) {
        aS[nt] = a_src[c0 + nt * 16 + ln];
        aD[nt] = a_dst[c0 + nt * 16 + ln];
    }
    #pragma unroll
    for (int hl = 0; hl < NT / 4; ++hl) {
        #pragma unroll
        for (int r = 0; r < 4; ++r) {
            float ps = 0.f, pd = 0.f;
            #pragma unroll
            for (int i = 0; i < 4; ++i) {
                ps = fmaf(acc[hl * 4 + i][r], aS[hl * 4 + i], ps);
                pd = fmaf(acc[hl * 4 + i][r], aD[hl * 4 + i], pd);
            }
            #pragma unroll
            for (int off = 1; off < 16; off <<= 1) {
                ps += __shfl_xor(ps, off);
                pd += __shfl_xor(pd, off);
            }
            if (ln == 0) {
                int n = n0 + wv * 16 + quad * 4 + r;
                if (n < N) {
                    int hg = c0 / 64 + hl;
                    asrc[n * 4 + hg] = ps;
                    adst[n * 4 + hg] = pd;
                }
            }
        }
    }
}

// transform1 (bf16x2, 30 KB LDS) fused with fine-sort tail blocks
__global__ __launch_bounds__(256) void transform1_fine_kernel(
    const float* __restrict__ xin, const short* __restrict__ whi,
    const float* __restrict__ a_src, const float* __restrict__ a_dst,
    __half* __restrict__ h, float* __restrict__ asrc, float* __restrict__ adst, int N,
    int nblk, const uint2* __restrict__ pairs, const int* __restrict__ bucket_cnt, int NB,
    int* __restrict__ colsrc, int* __restrict__ rowptr, int ET)
{
    if ((int)blockIdx.x < nblk) {
        transform_body<27, 1, 16, false>(blockIdx.x, 0, xin, whi, nullptr,
                                         a_src, a_dst, h, asrc, adst, N);
    } else {
        fine_sort_body(blockIdx.x - nblk, pairs, bucket_cnt, NB, colsrc, rowptr, N, ET);
    }
}

// transform2: single pass over all 256 cols (NT=16), bf16x2
__global__ __launch_bounds__(256) void transform2_kernel(
    const float* __restrict__ xin, const short* __restrict__ whi,
    const float* __restrict__ a_src, const float* __restrict__ a_dst,
    __half* __restrict__ h, float* __restrict__ asrc, float* __restrict__ adst, int N)
{
    transform_body<64, 2, 16, false>(blockIdx.x, 0, xin, whi, nullptr, a_src, a_dst, h, asrc, adst, N);
}

// ---------------- per-dst aggregation: 2 nodes/wave, shfl-broadcast sweep ----------------

__global__ __launch_bounds__(256) void aggregate_kernel(
    const int* __restrict__ rowptr, const int* __restrict__ colsrc,
    const __half* __restrict__ h, const float* __restrict__ asrc,
    const float* __restrict__ adst, const float* __restrict__ bias,
    float* __restrict__ hout, int N)
{
    int tid = threadIdx.x;
    int grp = tid >> 5;
    int lane32 = tid & 31;
    int n = blockIdx.x * 8 + grp;
    if (n >= N) return;
    int start = rowptr[n], end = rowptr[n + 1];
    int deg = end - start;
    const float4 ad = *(const float4*)(adst + (size_t)n * 4);

    int src0 = 0;
    float e0 = -1e30f, e1 = -1e30f, e2 = -1e30f, e3 = -1e30f;
    bool v0 = lane32 < deg;
    if (v0){
        src0 = colsrc[start + lane32];
        float4 as = *(const float4*)(asrc + (size_t)src0 * 4);
        e0 = leaky(as.x + ad.x); e1 = leaky(as.y + ad.y);
        e2 = leaky(as.z + ad.z); e3 = leaky(as.w + ad.w);
    }

    float m0, m1, m2, m3, i0, i1, i2, i3, p0, p1, p2, p3;
    if (deg <= 32){
        m0 = e0; m1 = e1; m2 = e2; m3 = e3;
        #pragma unroll
        for (int off = 1; off < 32; off <<= 1){
            m0 = fmaxf(m0, __shfl_xor(m0, off));
            m1 = fmaxf(m1, __shfl_xor(m1, off));
            m2 = fmaxf(m2, __shfl_xor(m2, off));
            m3 = fmaxf(m3, __shfl_xor(m3, off));
        }
        p0 = __expf(e0 - m0);
        p1 = __expf(e1 - m1);
        p2 = __expf(e2 - m2);
        p3 = __expf(e3 - m3);
        float t0 = p0, t1 = p1, t2 = p2, t3 = p3;
        #pragma unroll
        for (int off = 1; off < 32; off <<= 1){
            t0 += __shfl_xor(t0, off);
            t1 += __shfl_xor(t1, off);
            t2 += __shfl_xor(t2, off);
            t3 += __shfl_xor(t3, off);
        }
        i0 = 1.f / t0; i1 = 1.f / t1; i2 = 1.f / t2; i3 = 1.f / t3;
    } else {
        m0 = e0; m1 = e1; m2 = e2; m3 = e3;
        float t0 = v0 ? 1.f : 0.f, t1 = t0, t2 = t0, t3 = t0;
        for (int i = start + 32 + lane32; i < end; i += 32){
            int s = colsrc[i];
            float4 as = *(const float4*)(asrc + (size_t)s * 4);
            float e, nm;
            e = leaky(as.x + ad.x); nm = fmaxf(m0, e); t0 = t0 * __expf(m0 - nm) + __expf(e - nm); m0 = nm;
            e = leaky(as.y + ad.y); nm = fmaxf(m1, e); t1 = t1 * __expf(m1 - nm) + __expf(e - nm); m1 = nm;
            e = leaky(as.z + ad.z); nm = fmaxf(m2, e); t2 = t2 * __expf(m2 - nm) + __expf(e - nm); m2 = nm;
            e = leaky(as.w + ad.w); nm = fmaxf(m3, e); t3 = t3 * __expf(m3 - nm) + __expf(e - nm); m3 = nm;
        }
        #pragma unroll
        for (int off = 1; off < 32; off <<= 1){
            float om, os, nm;
            om = __shfl_xor(m0, off); os = __shfl_xor(t0, off);
            nm = fmaxf(m0, om); t0 = t0 * __expf(m0 - nm) + os * __expf(om - nm); m0 = nm;
            om = __shfl_xor(m1, off); os = __shfl_xor(t1, off);
            nm = fmaxf(m1, om); t1 = t1 * __expf(m1 - nm) + os * __expf(om - nm); m1 = nm;
            om = __shfl_xor(m2, off); os = __shfl_xor(t2, off);
            nm = fmaxf(m2, om); t2 = t2 * __expf(m2 - nm) + os * __expf(om - nm); m2 = nm;
            om = __shfl_xor(m3, off); os = __shfl_xor(t3, off);
            nm = fmaxf(m3, om); t3 = t3 * __expf(m3 - nm) + os * __expf(om - nm); m3 = nm;
        }
        i0 = 1.f / t0; i1 = 1.f / t1; i2 = 1.f / t2; i3 = 1.f / t3;
        p0 = __expf(e0 - m0); p1 = __expf(e1 - m1);
        p2 = __expf(e2 - m2); p3 = __expf(e3 - m3);
    }

    float accA = 0.f, accB = 0.f;
    const int boff = lane32 * 16;
    bool first = true;
    for (int base = start; base < end; base += 32){
        int cnt = end - base; if (cnt > 32) cnt = 32;
        float w0, w1, w2, w3; int off = 0;
        if (first){
            w0 = p0 * i0; w1 = p1 * i1; w2 = p2 * i2; w3 = p3 * i3;
            off = v0 ? src0 * (HC * 2) : 0;
        } else {
            w0 = w1 = w2 = w3 = 0.f;
            if (lane32 < cnt){
                int s = colsrc[base + lane32];
                float4 as = *(const float4*)(asrc + (size_t)s * 4);
                w0 = __expf(leaky(as.x + ad.x) - m0) * i0;
                w1 = __expf(leaky(as.y + ad.y) - m1) * i1;
                w2 = __expf(leaky(as.z + ad.z) - m2) * i2;
                w3 = __expf(leaky(as.w + ad.w) - m3) * i3;
                off = s * (HC * 2);
            }
        }
        first = false;
        half2_t q01 = __builtin_amdgcn_cvt_pkrtz(w0, w1);
        half2_t q23 = __builtin_amdgcn_cvt_pkrtz(w2, w3);
        unsigned wx = __builtin_bit_cast(unsigned, q01);
        unsigned wy = __builtin_bit_cast(unsigned, q23);

        int j = 0;
        for (; j + 2 <= cnt; j += 2){
            int o0 = __shfl(off, j, 32);
            unsigned a0 = __shfl((int)wx, j, 32), b0 = __shfl((int)wy, j, 32);
            int o1 = __shfl(off, j + 1, 32);
            unsigned a1 = __shfl((int)wx, j + 1, 32), b1 = __shfl((int)wy, j + 1, 32);
            uint4 h0 = *(const uint4*)((const char*)h + o0 + boff);
            uint4 h1 = *(const uint4*)((const char*)h + o1 + boff);
            accA = __builtin_amdgcn_fdot2(bc16(h0.x), bc16(a0), accA, false);
            accA = __builtin_amdgcn_fdot2(bc16(h0.y), bc16(b0), accA, false);
            accB = __builtin_amdgcn_fdot2(bc16(h0.z), bc16(a0), accB, false);
            accB = __builtin_amdgcn_fdot2(bc16(h0.w), bc16(b0), accB, false);
            accA = __builtin_amdgcn_fdot2(bc16(h1.x), bc16(a1), accA, false);
            accA = __builtin_amdgcn_fdot2(bc16(h1.y), bc16(b1), accA, false);
            accB = __builtin_amdgcn_fdot2(bc16(h1.z), bc16(a1), accB, false);
            accB = __builtin_amdgcn_fdot2(bc16(h1.w), bc16(b1), accB, false);
        }
        for (; j < cnt; ++j){
            int o0 = __shfl(off, j, 32);
            unsigned a0 = __shfl((int)wx, j, 32), b0 = __shfl((int)wy, j, 32);
            uint4 h0 = *(const uint4*)((const char*)h + o0 + boff);
            accA = __builtin_amdgcn_fdot2(bc16(h0.x), bc16(a0), accA, false);
            accA = __builtin_amdgcn_fdot2(bc16(h0.y), bc16(b0), accA, false);
            accB = __builtin_amdgcn_fdot2(bc16(h0.z), bc16(a0), accB, false);
            accB = __builtin_amdgcn_fdot2(bc16(h0.w), bc16(b0), accB, false);
        }
    }

    float2 bv = *(const float2*)(bias + lane32 * 2);
    float oA = accA * 0.25f + bv.x;
    float oB = accB * 0.25f + bv.y;
    oA = (oA > 0.f) ? oA : expm1f(oA);
    oB = (oB > 0.f) ? oB : expm1f(oB);
    *(float2*)(hout + (size_t)n * CH + lane32 * 2) = make_float2(oA, oB);
}

// ---------------- scorer: MFMA (bf16x3) for hmid@Ws1, fp32 epilogue ----------------

__global__ __launch_bounds__(256) void scorer_mfma_kernel(
    const float* __restrict__ h2, const short* __restrict__ s1hi, const short* __restrict__ s1lo,
    const float* __restrict__ d1p, const float* __restrict__ Ws2, const float* __restrict__ bs2,
    float* __restrict__ out, int N)
{
    constexpr int XP = 68, WP = 72;
    __shared__ float xl[64 * XP];
    __shared__ short whi[64 * WP];
    __shared__ short wlo[64 * WP];
    const int tid = threadIdx.x;
    const int n0 = blockIdx.x * 64;

    for (int t = tid; t < 64 * 16; t += 256) {
        int row = t >> 4, c4 = (t & 15) * 4;
        int n = n0 + row;
        float4 v = make_float4(0.f, 0.f, 0.f, 0.f);
        if (n < N) v = *(const float4*)(h2 + (size_t)n * 64 + c4);
        *(float4*)(xl + row * XP + c4) = v;
    }
    {
        const short8* ghi = (const short8*)s1hi;
        const short8* glo = (const short8*)s1lo;
        short8* lhi = (short8*)whi;
        short8* llo = (short8*)wlo;
        for (int t = tid; t < 64 * WP / 8; t += 256){ lhi[t] = ghi[t]; llo[t] = glo[t]; }
    }
    __syncthreads();

    const int wv = tid >> 6, lane = tid & 63;
    const int quad = lane >> 4, ln = lane & 15;
    const int myrow = wv * 16 + ln;

    f32x4 acc[4];
    #pragma unroll
    for (int i = 0; i < 4; ++i) acc[i] = (f32x4){0.f, 0.f, 0.f, 0.f};

    #pragma unroll
    for (int ks = 0; ks < 2; ++ks) {
        const int k0 = ks * 32 + quad * 8;
        const float* ap = xl + myrow * XP + k0;
        float4 f0 = *(const float4*)ap;
        float4 f1 = *(const float4*)(ap + 4);
        float fa[8] = {f0.x, f0.y, f0.z, f0.w, f1.x, f1.y, f1.z, f1.w};
        short8 ahi, alo;
        #pragma unroll
        for (int e = 0; e < 8; ++e) {
            short hi = bf16_rne(fa[e]);
            ahi[e] = hi;
            alo[e] = bf16_rne(fa[e] - bf16_to_f(hi));
        }
        #pragma unroll
        for (int nt = 0; nt < 4; ++nt) {
            short8 bhi = *(const short8*)(whi + (nt * 16 + ln) * WP + k0);
            short8 blo = *(const short8*)(wlo + (nt * 16 + ln) * WP + k0);
            acc[nt] = __builtin_amdgcn_mfma_f32_16x16x32_bf16(ahi, bhi, acc[nt], 0, 0, 0);
            acc[nt] = __builtin_amdgcn_mfma_f32_16x16x32_bf16(alo, bhi, acc[nt], 0, 0, 0);
            acc[nt] = __builtin_amdgcn_mfma_f32_16x16x32_bf16(ahi, blo, acc[nt], 0, 0, 0);
        }
    }

    float d1v[4], w2v[4];
    #pragma unroll
    for (int nt = 0; nt < 4; ++nt){
        d1v[nt] = d1p[nt * 16 + ln];
        w2v[nt] = Ws2[nt * 16 + ln];
    }
    float b2 = bs2[0];
    #pragma unroll
    for (int r = 0; r < 4; ++r){
        float t = 0.f;
        #pragma unroll
        for (int nt = 0; nt < 4; ++nt)
            t = fmaf(fmaxf(acc[nt][r] + d1v[nt], 0.f), w2v[nt], t);
        #pragma unroll
        for (int off = 1; off < 16; off <<= 1) t += __shfl_xor(t, off);
        if (ln == 0){
            int n = n0 + wv * 16 + quad * 4 + r;
            if (n < N) out[n] = t + b2;
        }
    }
}

// ---------------- launch ----------------

extern "C" void kernel_launch(void* const* d_in, const int* in_sizes, int n_in,
                              void* d_out, int out_size, void* d_ws, size_t ws_size,
                              hipStream_t stream)
{
    const float* x    = (const float*)d_in[0];
    const int*   ei   = (const int*)  d_in[1];
    const float* donor= (const float*)d_in[2];
    const float* W1   = (const float*)d_in[3];
    const float* as1  = (const float*)d_in[4];
    const float* ad1  = (const float*)d_in[5];
    const float* b1   = (const float*)d_in[6];
    const float* W2   = (const float*)d_in[7];
    const float* as2  = (const float*)d_in[8];
    const float* ad2  = (const float*)d_in[9];
    const float* b2   = (const float*)d_in[10];
    const float* Ws1  = (const float*)d_in[11];
    const float* bs1  = (const float*)d_in[12];
    const float* Ws2  = (const float*)d_in[13];
    const float* bs2  = (const float*)d_in[14];

    const int N  = in_sizes[0] / 27;
    const int E  = in_sizes[1] / 2;
    const int ET = E + N;
    const int NB = (N + 255) / 256;

    char* ws = (char*)d_ws;
    auto alloc = [&](size_t bytes) -> void* {
        void* p = (void*)ws;
        ws += (bytes + 255) / 256 * 256;
        return p;
    };
    int*    rowptr  = (int*)   alloc((size_t)(N + 1) * 4);
    int*    colsrc  = (int*)   alloc((size_t)ET * 4);
    uint2*  pairs   = (uint2*) alloc((size_t)ET * 8);
    __half* hbig    = (__half*)alloc((size_t)N * HC * 2);
    float*  asrc    = (float*) alloc((size_t)N * 4 * 4);
    float*  adst    = (float*) alloc((size_t)N * 4 * 4);
    float*  hmid    = (float*) alloc((size_t)N * CH * 4);
    int*    bucket_cnt    = (int*) alloc(256 * 4);
    int*    bucket_cursor = (int*) alloc(256 * 4);   // contiguous with bucket_cnt
    short*  w1hi    = (short*) alloc(256 * 40 * 2);
    short*  w2hi    = (short*) alloc(256 * 72 * 2);
    short*  s1hi    = (short*) alloc(64 * 72 * 2);
    short*  s1lo    = (short*) alloc(64 * 72 * 2);
    float*  d1p     = (float*) alloc(64 * 4);

    const int nblk = (N + 63) / 64;
    const int hblk = (ET + 2047) / 2048;

    // 1. zero bucket counts + relative cursors (contiguous 512 ints)
    (void)hipMemsetAsync(bucket_cnt, 0, 512 * 4, stream);
    // 2. prep (weights, d1) + edge histogram
    prep_hist_kernel<<<256 + hblk, 256, 0, stream>>>(W1, W2, Ws1, bs1, donor,
        w1hi, w2hi, s1hi, s1lo, d1p, ei, E, N, NB, bucket_cnt);
    // 3. coarse scatter (self-scan)
    coarse_scatter_kernel<<<hblk, 256, 0, stream>>>(ei, E, N, NB, bucket_cnt, bucket_cursor, pairs);
    // 4. layer1 transform + fine sort
    transform1_fine_kernel<<<nblk + NB, 256, 0, stream>>>(
        x, w1hi, as1, ad1, hbig, asrc, adst, N,
        nblk, pairs, bucket_cnt, NB, colsrc, rowptr, ET);
    // 5. aggregate layer1
    aggregate_kernel<<<(N + 7) / 8, 256, 0, stream>>>(
        rowptr, colsrc, hbig, asrc, adst, b1, hmid, N);
    // 6. layer2 transform
    transform2_kernel<<<nblk, 256, 0, stream>>>(
        hmid, w2hi, as2, ad2, hbig, asrc, adst, N);
    // 7. aggregate layer2
    aggregate_kernel<<<(N + 7) / 8, 256, 0, stream>>>(
        rowptr, colsrc, hbig, asrc, adst, b2, hmid, N);
    // 8. scorer
    scorer_mfma_kernel<<<nblk, 256, 0, stream>>>(
        hmid, s1hi, s1lo, d1p, Ws2, bs2, (float*)d_out, N);
}

// Round 14
// 287.817 us; speedup vs baseline: 1.3517x; 1.0053x over previous
//
#include <hip/hip_runtime.h>
#include <hip/hip_fp16.h>
#include <cmath>

#define HEADS 4
#define CH 64
#define HC 256
#define NEG 0.2f

typedef __attribute__((ext_vector_type(8))) short short8;
typedef __attribute__((ext_vector_type(4))) float f32x4;
typedef __fp16 half2_t __attribute__((ext_vector_type(2)));

__device__ __forceinline__ float leaky(float v){ return v > 0.f ? v : NEG * v; }

__device__ __forceinline__ short bf16_rne(float f){
    unsigned u = __float_as_uint(f);
    unsigned r = u + 0x7fffu + ((u >> 16) & 1u);
    return (short)(r >> 16);
}
__device__ __forceinline__ float bf16_to_f(short s){
    return __uint_as_float(((unsigned)(unsigned short)s) << 16);
}
__device__ __forceinline__ half2_t bc16(unsigned u){ return __builtin_bit_cast(half2_t, u); }
__device__ __forceinline__ unsigned packh2(float a, float b){
    __half ha = __float2half(a), hb = __float2half(b);   // RNE
    return (unsigned)__builtin_bit_cast(unsigned short, ha)
         | ((unsigned)__builtin_bit_cast(unsigned short, hb) << 16);
}

// block-wide exclusive scan of one int per thread (256 threads)
__device__ __forceinline__ int block_excl_scan(int v, int* ws4){
    int tid = threadIdx.x, lane = tid & 63, wv = tid >> 6;
    int incl = v;
    #pragma unroll
    for (int off = 1; off < 64; off <<= 1){
        int t = __shfl_up(incl, off);
        if (lane >= off) incl += t;
    }
    if (lane == 63) ws4[wv] = incl;
    __syncthreads();
    int add = 0;
    for (int w = 0; w < wv; ++w) add += ws4[w];
    return incl - v + add;
}

// ---------------- prep (+ edge histogram tail) ----------------

__global__ __launch_bounds__(256) void prep_hist_kernel(
    const float* __restrict__ W1, const float* __restrict__ W2,
    const float* __restrict__ Ws1, const float* __restrict__ bs1,
    const float* __restrict__ donor,
    short* __restrict__ w1hi, short* __restrict__ w2hi,
    short* __restrict__ s1hi, short* __restrict__ s1lo,
    float* __restrict__ d1p,
    const int* __restrict__ ei, int E, int N, int NB, int* __restrict__ bucket_cnt)
{
    if ((int)blockIdx.x < 256){
        int t = blockIdx.x * 256 + threadIdx.x;
        int T = 256 * 256;
        for (int i = t; i < 256 * 40; i += T){                  // W1 bf16: [n=256][k pitch 40], K=27
            int n = i / 40, k = i % 40;
            w1hi[i] = bf16_rne((k < 27) ? W1[(size_t)k * HC + n] : 0.f);
        }
        for (int i = t; i < 256 * 72; i += T){                  // W2 bf16: [n=256][k pitch 72], K=64
            int n = i / 72, k = i % 72;
            w2hi[i] = bf16_rne((k < 64) ? W2[(size_t)k * HC + n] : 0.f);
        }
        for (int i = t; i < 64 * 72; i += T){                   // Ws1 bf16x3 (scorer)
            int n = i / 72, k = i % 72;
            float v = (k < 64) ? Ws1[(size_t)k * 64 + n] : 0.f;
            short hi = bf16_rne(v);
            s1hi[i] = hi; s1lo[i] = bf16_rne(v - bf16_to_f(hi));
        }
        if (t < 64){
            float s = bs1[t];
            for (int k = 0; k < 32; ++k) s = fmaf(donor[k], Ws1[(size_t)(64 + k) * 64 + t], s);
            d1p[t] = s;
        }
    } else {
        __shared__ int lh[256];
        int tid = threadIdx.x;
        int ET = E + N;
        int ebase = ((int)blockIdx.x - 256) * 2048;
        lh[tid] = 0;
        __syncthreads();
        #pragma unroll
        for (int j = 0; j < 8; ++j){
            int e = ebase + j * 256 + tid;
            if (e < ET){
                int d = (e < E) ? ei[E + e] : (e - E);
                atomicAdd(&lh[d >> 8], 1);
            }
        }
        __syncthreads();
        if (tid < NB && lh[tid]) atomicAdd(&bucket_cnt[tid], lh[tid]);
    }
}

// ---------------- coarse scatter (self-scan, packed uint32 pairs) ----------------

__global__ __launch_bounds__(256) void coarse_scatter_kernel(
    const int* __restrict__ ei, int E, int N, int NB,
    const int* __restrict__ bucket_cnt, int* __restrict__ bucket_cursor,
    unsigned* __restrict__ pairs)
{
    __shared__ int ws4[4];
    __shared__ int gbase[256];
    __shared__ int lh[256];
    __shared__ int gb[256];
    int tid = threadIdx.x;
    int ET = E + N;
    {
        int v = (tid < NB) ? bucket_cnt[tid] : 0;
        gbase[tid] = block_excl_scan(v, ws4);
    }
    lh[tid] = 0;
    __syncthreads();
    int ebase = blockIdx.x * 2048;
    int d[8], s[8], r[8];
    #pragma unroll
    for (int j = 0; j < 8; ++j){
        int e = ebase + j * 256 + tid;
        d[j] = -1;
        if (e < ET){
            if (e < E){ s[j] = ei[e]; d[j] = ei[E + e]; } else { s[j] = d[j] = e - E; }
            r[j] = atomicAdd(&lh[d[j] >> 8], 1);
        }
    }
    __syncthreads();
    if (tid < NB && lh[tid]) gb[tid] = gbase[tid] + atomicAdd(&bucket_cursor[tid], lh[tid]);
    __syncthreads();
    #pragma unroll
    for (int j = 0; j < 8; ++j){
        if (d[j] >= 0)
            pairs[gb[d[j] >> 8] + r[j]] = ((unsigned)d[j] << 16) | (unsigned)s[j];
    }
}

// ---------------- fine sort body (self-scan, block-local writes) ----------------

__device__ __forceinline__ void fine_sort_body(
    int b, const unsigned* __restrict__ pairs, const int* __restrict__ bucket_cnt, int NB,
    int* __restrict__ colsrc, int* __restrict__ rowptr, int N, int ET)
{
    __shared__ int ws4f[4];
    __shared__ int sb[257];
    __shared__ int hist[256];
    __shared__ int cur[256];
    int tid = threadIdx.x;
    {
        int v = (tid < NB) ? bucket_cnt[tid] : 0;
        int excl = block_excl_scan(v, ws4f);
        sb[tid] = excl;
        if (tid == 255) sb[256] = excl + v;
    }
    hist[tid] = 0;
    __syncthreads();
    int base = sb[b], endb = sb[b + 1];
    int cnt = endb - base;
    int d0 = b << 8;
    for (int i = tid; i < cnt; i += 256){
        unsigned p = pairs[base + i];
        atomicAdd(&hist[(int)(p >> 16) - d0], 1);
    }
    __syncthreads();
    int v = hist[tid];
    int excl = block_excl_scan(v, ws4f);
    cur[tid] = excl;
    if (d0 + tid < N) rowptr[d0 + tid] = base + excl;
    if (b == 0 && tid == 0) rowptr[N] = ET;
    __syncthreads();
    for (int i = tid; i < cnt; i += 256){
        unsigned p = pairs[base + i];
        int r = atomicAdd(&cur[(int)(p >> 16) - d0], 1);
        colsrc[base + r] = (int)(p & 0xFFFFu);
    }
}

// ---------------- MFMA node transform (device body) ----------------
// X3: bf16x3 A*B split. DIRECT: FIN==64, read A-fragments straight from global
// (contiguous 32B/lane, wave covers 16 consecutive rows) — no xl staging.

template<int FIN, int KSTEPS, int NT, bool X3, bool DIRECT>
__device__ __forceinline__ void transform_body(
    int bx, int by,
    const float* __restrict__ xin, const short* __restrict__ whi, const short* __restrict__ wlo,
    const float* __restrict__ a_src, const float* __restrict__ a_dst,
    __half* __restrict__ h, float* __restrict__ asrc, float* __restrict__ adst, int N)
{
    constexpr int KP = KSTEPS * 32;
    constexpr int XP = KP + 4;
    constexpr int WP = KP + 8;
    constexpr int NCOL = NT * 16;
    __shared__ float xl[DIRECT ? 8 : 64 * XP];
    __shared__ short wt_hi[NCOL * WP];
    __shared__ short wt_lo[X3 ? NCOL * WP : 8];

    const int tid = threadIdx.x;
    const int n0 = bx * 64;
    const int c0 = by * NCOL;

    const int wv = tid >> 6, lane = tid & 63;
    const int quad = lane >> 4, ln = lane & 15;
    const int myrow = wv * 16 + ln;

    float fdir[DIRECT ? KSTEPS * 8 : 1];
    if (DIRECT){
        int n = n0 + myrow;
        #pragma unroll
        for (int ks = 0; ks < KSTEPS; ++ks){
            float4 f0 = make_float4(0.f, 0.f, 0.f, 0.f), f1 = f0;
            if (n < N){
                const float* ap = xin + (size_t)n * FIN + ks * 32 + quad * 8;
                f0 = *(const float4*)ap;
                f1 = *(const float4*)(ap + 4);
            }
            fdir[ks*8+0]=f0.x; fdir[ks*8+1]=f0.y; fdir[ks*8+2]=f0.z; fdir[ks*8+3]=f0.w;
            fdir[ks*8+4]=f1.x; fdir[ks*8+5]=f1.y; fdir[ks*8+6]=f1.z; fdir[ks*8+7]=f1.w;
        }
    } else {
        for (int t = tid; t < 64 * KP; t += 256) {
            int row = t / KP, k = t % KP;
            int n = n0 + row;
            float v = 0.f;
            if (n < N && k < FIN) v = xin[(size_t)n * FIN + k];
            xl[row * XP + k] = v;
        }
    }
    {
        const short8* ghi = (const short8*)(whi + (size_t)c0 * WP);
        short8* lhi = (short8*)wt_hi;
        for (int t = tid; t < NCOL * WP / 8; t += 256) lhi[t] = ghi[t];
        if (X3){
            const short8* glo = (const short8*)(wlo + (size_t)c0 * WP);
            short8* llo = (short8*)wt_lo;
            for (int t = tid; t < NCOL * WP / 8; t += 256) llo[t] = glo[t];
        }
    }
    __syncthreads();

    f32x4 acc[NT];
    #pragma unroll
    for (int i = 0; i < NT; ++i) acc[i] = (f32x4){0.f, 0.f, 0.f, 0.f};

    #pragma unroll
    for (int ks = 0; ks < KSTEPS; ++ks) {
        const int k0 = ks * 32 + quad * 8;
        float fa[8];
        if (DIRECT){
            #pragma unroll
            for (int e = 0; e < 8; ++e) fa[e] = fdir[ks * 8 + e];
        } else {
            const float* ap = xl + myrow * XP + k0;
            float4 f0 = *(const float4*)ap;
            float4 f1 = *(const float4*)(ap + 4);
            fa[0]=f0.x; fa[1]=f0.y; fa[2]=f0.z; fa[3]=f0.w;
            fa[4]=f1.x; fa[5]=f1.y; fa[6]=f1.z; fa[7]=f1.w;
        }
        short8 ahi, alo;
        #pragma unroll
        for (int e = 0; e < 8; ++e) {
            short hi = bf16_rne(fa[e]);
            ahi[e] = hi;
            alo[e] = bf16_rne(fa[e] - bf16_to_f(hi));
        }
        #pragma unroll
        for (int nt = 0; nt < NT; ++nt) {
            short8 bhi = *(const short8*)(wt_hi + (nt * 16 + ln) * WP + k0);
            acc[nt] = __builtin_amdgcn_mfma_f32_16x16x32_bf16(ahi, bhi, acc[nt], 0, 0, 0);
            acc[nt] = __builtin_amdgcn_mfma_f32_16x16x32_bf16(alo, bhi, acc[nt], 0, 0, 0);
            if (X3){
                short8 blo = *(const short8*)(wt_lo + (nt * 16 + ln) * WP + k0);
                acc[nt] = __builtin_amdgcn_mfma_f32_16x16x32_bf16(ahi, blo, acc[nt], 0, 0, 0);
            }
        }
    }

    #pragma unroll
    for (int r = 0; r < 4; ++r) {
        int n = n0 + wv * 16 + quad * 4 + r;
        if (n < N) {
            if (NT == 16) {
                #pragma unroll
                for (int q = 0; q < 4; ++q) {
                    uint2 u;
                    u.x = packh2(acc[q][r],     acc[q + 4][r]);
                    u.y = packh2(acc[q + 8][r], acc[q + 12][r]);
                    *(uint2*)((char*)h + (size_t)n * 512 + (q * 16 + ln) * 8) = u;
                }
            } else {
                #pragma unroll
                for (int q = 0; q < 4; ++q) {
                    unsigned u = packh2(acc[q][r], acc[q + 4][r]);
                    *(unsigned*)((char*)h + (size_t)n * 512 + (q * 16 + ln) * 8 + ((c0 >> 6) << 1)) = u;
                }
            }
        }
    }

    float aS[NT], aD[NT];
    #pragma unroll
    for (int nt = 0; nt < NT; ++nt) {
        aS[nt] = a_src[c0 + nt * 16 + ln];
        aD[nt] = a_dst[c0 + nt * 16 + ln];
    }
    #pragma unroll
    for (int hl = 0; hl < NT / 4; ++hl) {
        #pragma unroll
        for (int r = 0; r < 4; ++r) {
            float ps = 0.f, pd = 0.f;
            #pragma unroll
            for (int i = 0; i < 4; ++i) {
                ps = fmaf(acc[hl * 4 + i][r], aS[hl * 4 + i], ps);
                pd = fmaf(acc[hl * 4 + i][r], aD[hl * 4 + i], pd);
            }
            #pragma unroll
            for (int off = 1; off < 16; off <<= 1) {
                ps += __shfl_xor(ps, off);
                pd += __shfl_xor(pd, off);
            }
            if (ln == 0) {
                int n = n0 + wv * 16 + quad * 4 + r;
                if (n < N) {
                    int hg = c0 / 64 + hl;
                    asrc[n * 4 + hg] = ps;
                    adst[n * 4 + hg] = pd;
                }
            }
        }
    }
}

// transform1 (bf16x2, LDS-staged x: FIN=27) fused with fine-sort tail blocks
__global__ __launch_bounds__(256) void transform1_fine_kernel(
    const float* __restrict__ xin, const short* __restrict__ whi,
    const float* __restrict__ a_src, const float* __restrict__ a_dst,
    __half* __restrict__ h, float* __restrict__ asrc, float* __restrict__ adst, int N,
    int nblk, const unsigned* __restrict__ pairs, const int* __restrict__ bucket_cnt, int NB,
    int* __restrict__ colsrc, int* __restrict__ rowptr, int ET)
{
    if ((int)blockIdx.x < nblk) {
        transform_body<27, 1, 16, false, false>(blockIdx.x, 0, xin, whi, nullptr,
                                                a_src, a_dst, h, asrc, adst, N);
    } else {
        fine_sort_body(blockIdx.x - nblk, pairs, bucket_cnt, NB, colsrc, rowptr, N, ET);
    }
}

// transform2: NT=16 single pass, bf16x2, DIRECT global A reads (36.9 KB LDS)
__global__ __launch_bounds__(256) void transform2_kernel(
    const float* __restrict__ xin, const short* __restrict__ whi,
    const float* __restrict__ a_src, const float* __restrict__ a_dst,
    __half* __restrict__ h, float* __restrict__ asrc, float* __restrict__ adst, int N)
{
    transform_body<64, 2, 16, false, true>(blockIdx.x, 0, xin, whi, nullptr,
                                           a_src, a_dst, h, asrc, adst, N);
}

// ---------------- per-dst aggregation: 2 nodes/wave, shfl-broadcast sweep ----------------

__global__ __launch_bounds__(256) void aggregate_kernel(
    const int* __restrict__ rowptr, const int* __restrict__ colsrc,
    const __half* __restrict__ h, const float* __restrict__ asrc,
    const float* __restrict__ adst, const float* __restrict__ bias,
    float* __restrict__ hout, int N)
{
    int tid = threadIdx.x;
    int grp = tid >> 5;
    int lane32 = tid & 31;
    int n = blockIdx.x * 8 + grp;
    if (n >= N) return;
    int start = rowptr[n], end = rowptr[n + 1];
    int deg = end - start;
    const float4 ad = *(const float4*)(adst + (size_t)n * 4);

    int src0 = 0;
    float e0 = -1e30f, e1 = -1e30f, e2 = -1e30f, e3 = -1e30f;
    bool v0 = lane32 < deg;
    if (v0){
        src0 = colsrc[start + lane32];
        float4 as = *(const float4*)(asrc + (size_t)src0 * 4);
        e0 = leaky(as.x + ad.x); e1 = leaky(as.y + ad.y);
        e2 = leaky(as.z + ad.z); e3 = leaky(as.w + ad.w);
    }

    float m0, m1, m2, m3, i0, i1, i2, i3, p0, p1, p2, p3;
    if (deg <= 32){
        m0 = e0; m1 = e1; m2 = e2; m3 = e3;
        #pragma unroll
        for (int off = 1; off < 32; off <<= 1){
            m0 = fmaxf(m0, __shfl_xor(m0, off));
            m1 = fmaxf(m1, __shfl_xor(m1, off));
            m2 = fmaxf(m2, __shfl_xor(m2, off));
            m3 = fmaxf(m3, __shfl_xor(m3, off));
        }
        p0 = __expf(e0 - m0);
        p1 = __expf(e1 - m1);
        p2 = __expf(e2 - m2);
        p3 = __expf(e3 - m3);
        float t0 = p0, t1 = p1, t2 = p2, t3 = p3;
        #pragma unroll
        for (int off = 1; off < 32; off <<= 1){
            t0 += __shfl_xor(t0, off);
            t1 += __shfl_xor(t1, off);
            t2 += __shfl_xor(t2, off);
            t3 += __shfl_xor(t3, off);
        }
        i0 = 1.f / t0; i1 = 1.f / t1; i2 = 1.f / t2; i3 = 1.f / t3;
    } else {
        m0 = e0; m1 = e1; m2 = e2; m3 = e3;
        float t0 = v0 ? 1.f : 0.f, t1 = t0, t2 = t0, t3 = t0;
        for (int i = start + 32 + lane32; i < end; i += 32){
            int s = colsrc[i];
            float4 as = *(const float4*)(asrc + (size_t)s * 4);
            float e, nm;
            e = leaky(as.x + ad.x); nm = fmaxf(m0, e); t0 = t0 * __expf(m0 - nm) + __expf(e - nm); m0 = nm;
            e = leaky(as.y + ad.y); nm = fmaxf(m1, e); t1 = t1 * __expf(m1 - nm) + __expf(e - nm); m1 = nm;
            e = leaky(as.z + ad.z); nm = fmaxf(m2, e); t2 = t2 * __expf(m2 - nm) + __expf(e - nm); m2 = nm;
            e = leaky(as.w + ad.w); nm = fmaxf(m3, e); t3 = t3 * __expf(m3 - nm) + __expf(e - nm); m3 = nm;
        }
        #pragma unroll
        for (int off = 1; off < 32; off <<= 1){
            float om, os, nm;
            om = __shfl_xor(m0, off); os = __shfl_xor(t0, off);
            nm = fmaxf(m0, om); t0 = t0 * __expf(m0 - nm) + os * __expf(om - nm); m0 = nm;
            om = __shfl_xor(m1, off); os = __shfl_xor(t1, off);
            nm = fmaxf(m1, om); t1 = t1 * __expf(m1 - nm) + os * __expf(om - nm); m1 = nm;
            om = __shfl_xor(m2, off); os = __shfl_xor(t2, off);
            nm = fmaxf(m2, om); t2 = t2 * __expf(m2 - nm) + os * __expf(om - nm); m2 = nm;
            om = __shfl_xor(m3, off); os = __shfl_xor(t3, off);
            nm = fmaxf(m3, om); t3 = t3 * __expf(m3 - nm) + os * __expf(om - nm); m3 = nm;
        }
        i0 = 1.f / t0; i1 = 1.f / t1; i2 = 1.f / t2; i3 = 1.f / t3;
        p0 = __expf(e0 - m0); p1 = __expf(e1 - m1);
        p2 = __expf(e2 - m2); p3 = __expf(e3 - m3);
    }

    float accA = 0.f, accB = 0.f;
    const int boff = lane32 * 16;
    bool first = true;
    for (int base = start; base < end; base += 32){
        int cnt = end - base; if (cnt > 32) cnt = 32;
        float w0, w1, w2, w3; int off = 0;
        if (first){
            w0 = p0 * i0; w1 = p1 * i1; w2 = p2 * i2; w3 = p3 * i3;
            off = v0 ? src0 * (HC * 2) : 0;
        } else {
            w0 = w1 = w2 = w3 = 0.f;
            if (lane32 < cnt){
                int s = colsrc[base + lane32];
                float4 as = *(const float4*)(asrc + (size_t)s * 4);
                w0 = __expf(leaky(as.x + ad.x) - m0) * i0;
                w1 = __expf(leaky(as.y + ad.y) - m1) * i1;
                w2 = __expf(leaky(as.z + ad.z) - m2) * i2;
                w3 = __expf(leaky(as.w + ad.w) - m3) * i3;
                off = s * (HC * 2);
            }
        }
        first = false;
        half2_t q01 = __builtin_amdgcn_cvt_pkrtz(w0, w1);
        half2_t q23 = __builtin_amdgcn_cvt_pkrtz(w2, w3);
        unsigned wx = __builtin_bit_cast(unsigned, q01);
        unsigned wy = __builtin_bit_cast(unsigned, q23);

        int j = 0;
        for (; j + 2 <= cnt; j += 2){
            int o0 = __shfl(off, j, 32);
            unsigned a0 = __shfl((int)wx, j, 32), b0 = __shfl((int)wy, j, 32);
            int o1 = __shfl(off, j + 1, 32);
            unsigned a1 = __shfl((int)wx, j + 1, 32), b1 = __shfl((int)wy, j + 1, 32);
            uint4 h0 = *(const uint4*)((const char*)h + o0 + boff);
            uint4 h1 = *(const uint4*)((const char*)h + o1 + boff);
            accA = __builtin_amdgcn_fdot2(bc16(h0.x), bc16(a0), accA, false);
            accA = __builtin_amdgcn_fdot2(bc16(h0.y), bc16(b0), accA, false);
            accB = __builtin_amdgcn_fdot2(bc16(h0.z), bc16(a0), accB, false);
            accB = __builtin_amdgcn_fdot2(bc16(h0.w), bc16(b0), accB, false);
            accA = __builtin_amdgcn_fdot2(bc16(h1.x), bc16(a1), accA, false);
            accA = __builtin_amdgcn_fdot2(bc16(h1.y), bc16(b1), accA, false);
            accB = __builtin_amdgcn_fdot2(bc16(h1.z), bc16(a1), accB, false);
            accB = __builtin_amdgcn_fdot2(bc16(h1.w), bc16(b1), accB, false);
        }
        for (; j < cnt; ++j){
            int o0 = __shfl(off, j, 32);
            unsigned a0 = __shfl((int)wx, j, 32), b0 = __shfl((int)wy, j, 32);
            uint4 h0 = *(const uint4*)((const char*)h + o0 + boff);
            accA = __builtin_amdgcn_fdot2(bc16(h0.x), bc16(a0), accA, false);
            accA = __builtin_amdgcn_fdot2(bc16(h0.y), bc16(b0), accA, false);
            accB = __builtin_amdgcn_fdot2(bc16(h0.z), bc16(a0), accB, false);
            accB = __builtin_amdgcn_fdot2(bc16(h0.w), bc16(b0), accB, false);
        }
    }

    float2 bv = *(const float2*)(bias + lane32 * 2);
    float oA = accA * 0.25f + bv.x;
    float oB = accB * 0.25f + bv.y;
    oA = (oA > 0.f) ? oA : expm1f(oA);
    oB = (oB > 0.f) ? oB : expm1f(oB);
    *(float2*)(hout + (size_t)n * CH + lane32 * 2) = make_float2(oA, oB);
}

// ---------------- scorer: MFMA (bf16x3), DIRECT global A reads ----------------

__global__ __launch_bounds__(256) void scorer_mfma_kernel(
    const float* __restrict__ h2, const short* __restrict__ s1hi, const short* __restrict__ s1lo,
    const float* __restrict__ d1p, const float* __restrict__ Ws2, const float* __restrict__ bs2,
    float* __restrict__ out, int N)
{
    constexpr int WP = 72;
    __shared__ short whi[64 * WP];
    __shared__ short wlo[64 * WP];
    const int tid = threadIdx.x;
    const int n0 = blockIdx.x * 64;

    const int wv = tid >> 6, lane = tid & 63;
    const int quad = lane >> 4, ln = lane & 15;
    const int myrow = wv * 16 + ln;
    const int nme = n0 + myrow;

    float fdir[16];
    #pragma unroll
    for (int ks = 0; ks < 2; ++ks){
        float4 f0 = make_float4(0.f, 0.f, 0.f, 0.f), f1 = f0;
        if (nme < N){
            const float* ap = h2 + (size_t)nme * 64 + ks * 32 + quad * 8;
            f0 = *(const float4*)ap;
            f1 = *(const float4*)(ap + 4);
        }
        fdir[ks*8+0]=f0.x; fdir[ks*8+1]=f0.y; fdir[ks*8+2]=f0.z; fdir[ks*8+3]=f0.w;
        fdir[ks*8+4]=f1.x; fdir[ks*8+5]=f1.y; fdir[ks*8+6]=f1.z; fdir[ks*8+7]=f1.w;
    }
    {
        const short8* ghi = (const short8*)s1hi;
        const short8* glo = (const short8*)s1lo;
        short8* lhi = (short8*)whi;
        short8* llo = (short8*)wlo;
        for (int t = tid; t < 64 * WP / 8; t += 256){ lhi[t] = ghi[t]; llo[t] = glo[t]; }
    }
    __syncthreads();

    f32x4 acc[4];
    #pragma unroll
    for (int i = 0; i < 4; ++i) acc[i] = (f32x4){0.f, 0.f, 0.f, 0.f};

    #pragma unroll
    for (int ks = 0; ks < 2; ++ks) {
        const int k0 = ks * 32 + quad * 8;
        short8 ahi, alo;
        #pragma unroll
        for (int e = 0; e < 8; ++e) {
            float v = fdir[ks * 8 + e];
            short hi = bf16_rne(v);
            ahi[e] = hi;
            alo[e] = bf16_rne(v - bf16_to_f(hi));
        }
        #pragma unroll
        for (int nt = 0; nt < 4; ++nt) {
            short8 bhi = *(const short8*)(whi + (nt * 16 + ln) * WP + k0);
            short8 blo = *(const short8*)(wlo + (nt * 16 + ln) * WP + k0);
            acc[nt] = __builtin_amdgcn_mfma_f32_16x16x32_bf16(ahi, bhi, acc[nt], 0, 0, 0);
            acc[nt] = __builtin_amdgcn_mfma_f32_16x16x32_bf16(alo, bhi, acc[nt], 0, 0, 0);
            acc[nt] = __builtin_amdgcn_mfma_f32_16x16x32_bf16(ahi, blo, acc[nt], 0, 0, 0);
        }
    }

    float d1v[4], w2v[4];
    #pragma unroll
    for (int nt = 0; nt < 4; ++nt){
        d1v[nt] = d1p[nt * 16 + ln];
        w2v[nt] = Ws2[nt * 16 + ln];
    }
    float b2 = bs2[0];
    #pragma unroll
    for (int r = 0; r < 4; ++r){
        float t = 0.f;
        #pragma unroll
        for (int nt = 0; nt < 4; ++nt)
            t = fmaf(fmaxf(acc[nt][r] + d1v[nt], 0.f), w2v[nt], t);
        #pragma unroll
        for (int off = 1; off < 16; off <<= 1) t += __shfl_xor(t, off);
        if (ln == 0){
            int n = n0 + wv * 16 + quad * 4 + r;
            if (n < N) out[n] = t + b2;
        }
    }
}

// ---------------- launch ----------------

extern "C" void kernel_launch(void* const* d_in, const int* in_sizes, int n_in,
                              void* d_out, int out_size, void* d_ws, size_t ws_size,
                              hipStream_t stream)
{
    const float* x    = (const float*)d_in[0];
    const int*   ei   = (const int*)  d_in[1];
    const float* donor= (const float*)d_in[2];
    const float* W1   = (const float*)d_in[3];
    const float* as1  = (const float*)d_in[4];
    const float* ad1  = (const float*)d_in[5];
    const float* b1   = (const float*)d_in[6];
    const float* W2   = (const float*)d_in[7];
    const float* as2  = (const float*)d_in[8];
    const float* ad2  = (const float*)d_in[9];
    const float* b2   = (const float*)d_in[10];
    const float* Ws1  = (const float*)d_in[11];
    const float* bs1  = (const float*)d_in[12];
    const float* Ws2  = (const float*)d_in[13];
    const float* bs2  = (const float*)d_in[14];

    const int N  = in_sizes[0] / 27;
    const int E  = in_sizes[1] / 2;
    const int ET = E + N;
    const int NB = (N + 255) / 256;

    char* ws = (char*)d_ws;
    auto alloc = [&](size_t bytes) -> void* {
        void* p = (void*)ws;
        ws += (bytes + 255) / 256 * 256;
        return p;
    };
    int*      rowptr  = (int*)     alloc((size_t)(N + 1) * 4);
    int*      colsrc  = (int*)     alloc((size_t)ET * 4);
    unsigned* pairs   = (unsigned*)alloc((size_t)ET * 4);
    __half*   hbig    = (__half*)  alloc((size_t)N * HC * 2);
    float*    asrc    = (float*)   alloc((size_t)N * 4 * 4);
    float*    adst    = (float*)   alloc((size_t)N * 4 * 4);
    float*    hmid    = (float*)   alloc((size_t)N * CH * 4);
    int*      bucket_cnt    = (int*) alloc(256 * 4);
    int*      bucket_cursor = (int*) alloc(256 * 4);   // contiguous with bucket_cnt
    short*    w1hi    = (short*)   alloc(256 * 40 * 2);
    short*    w2hi    = (short*)   alloc(256 * 72 * 2);
    short*    s1hi    = (short*)   alloc(64 * 72 * 2);
    short*    s1lo    = (short*)   alloc(64 * 72 * 2);
    float*    d1p     = (float*)   alloc(64 * 4);

    const int nblk = (N + 63) / 64;
    const int hblk = (ET + 2047) / 2048;

    (void)hipMemsetAsync(bucket_cnt, 0, 512 * 4, stream);
    prep_hist_kernel<<<256 + hblk, 256, 0, stream>>>(W1, W2, Ws1, bs1, donor,
        w1hi, w2hi, s1hi, s1lo, d1p, ei, E, N, NB, bucket_cnt);
    coarse_scatter_kernel<<<hblk, 256, 0, stream>>>(ei, E, N, NB, bucket_cnt, bucket_cursor, pairs);
    transform1_fine_kernel<<<nblk + NB, 256, 0, stream>>>(
        x, w1hi, as1, ad1, hbig, asrc, adst, N,
        nblk, pairs, bucket_cnt, NB, colsrc, rowptr, ET);
    aggregate_kernel<<<(N + 7) / 8, 256, 0, stream>>>(
        rowptr, colsrc, hbig, asrc, adst, b1, hmid, N);
    transform2_kernel<<<nblk, 256, 0, stream>>>(
        hmid, w2hi, as2, ad2, hbig, asrc, adst, N);
    aggregate_kernel<<<(N + 7) / 8, 256, 0, stream>>>(
        rowptr, colsrc, hbig, asrc, adst, b2, hmid, N);
    scorer_mfma_kernel<<<nblk, 256, 0, stream>>>(
        hmid, s1hi, s1lo, d1p, Ws2, bs2, (float*)d_out, N);
}